// Round 6
// baseline (712.630 us; speedup 1.0000x reference)
//
#include <hip/hip_runtime.h>

// Problem constants
#define BN    65536    // B*N rows
#define DD    256      // D
#define KCB   512      // codebook entries
#define MT    256      // rows per block (main kernel)
#define NBLK  256      // BN/MT -> exactly 1 block per CU (proven best)
#define NST   8        // codebook stages of 64 codes (hi-only staging)

typedef __attribute__((ext_vector_type(8))) short bf16x8;
typedef __attribute__((ext_vector_type(4))) float f32x4;

static __device__ __forceinline__ float bf2f(unsigned short u) {
  return __uint_as_float(((unsigned int)u) << 16);
}
static __device__ __forceinline__ unsigned short f2bf(float f) {
  unsigned int u = __float_as_uint(f);
  return (unsigned short)((u + 0x7fffu + ((u >> 16) & 1u)) >> 16);  // RNE
}
static __device__ __forceinline__ void gll16(const void* g, void* l) {
  __builtin_amdgcn_global_load_lds(
      (const __attribute__((address_space(1))) unsigned int*)g,
      (__attribute__((address_space(3))) unsigned int*)l, 16, 0, 0);
}

__global__ void vq_zero_ws(float* ws) { ws[0] = 0.f; }   // fallback path only

// ---- one-shot prep: codebook fp32 -> bf16 HI ONLY, stage-major layout with
// XOR bank-swizzle pre-applied in GLOBAL memory (linear global_load_lds dest
// + inverse-swz source + swz read). Stage s (64 codes, 32 KB) at s*32768;
// code lc (0..63) byte b at (lc*512 + b) ^ ((lc&7)<<4).
// Also fp64-exact e_sq of the ORIGINAL fp32 codebook, and wsum/dcnt zeroing.
// Numerics note: 2-pass MFMA (z_hi+z_lo)*e_hi computes z.e_hi exactly; the
// dropped z.e_lo term has distance-error std ~0.036 -> covered by the 0.30
// rescan threshold (6-sigma on the gap test).
__global__ void vq_prep(const float* __restrict__ cbg,
                        char* __restrict__ cbt,
                        float* __restrict__ esq,
                        float* __restrict__ wsum,
                        unsigned int* __restrict__ dcnt) {
  if (blockIdx.x == 0 && threadIdx.x == 0) { wsum[0] = 0.f; dcnt[0] = 0u; }
  const int tid = threadIdx.x, lane = tid & 63, wave = tid >> 6;
  const int code = blockIdx.x * 4 + wave;
  float4 v = ((const float4*)cbg)[(size_t)code * 64 + lane];
  ushort4 h;
  h.x = f2bf(v.x); h.y = f2bf(v.y); h.z = f2bf(v.z); h.w = f2bf(v.w);
  const int s  = code >> 6;
  const int lc = code & 63;
  unsigned raw = (unsigned)(lc * 512 + lane * 8);     // 8 bytes per lane
  unsigned off = (unsigned)(s * 32768) + (raw ^ ((unsigned)(lc & 7) << 4));
  *(ushort4*)(cbt + off) = h;
  double sq = (double)v.x * v.x + (double)v.y * v.y +
              (double)v.z * v.z + (double)v.w * v.w;
#pragma unroll
  for (int m = 1; m < 64; m <<= 1) sq += __shfl_xor(sq, m, 64);
  if (lane == 0) esq[code] = (float)sq;
}

// issue stage S (32 KB) into LDS buffer BSEL: 4 x global_load_lds(16B) per
// thread (512 threads); dest = wave-uniform base + lane*16 (HW requirement).
#define ISSUE(S, BSEL)                                                       \
  do {                                                                       \
    const char* _src = cbt + (size_t)(S) * 32768 + (size_t)tid * 16;         \
    char* _dst = &bufB[BSEL][tid * 16];                                      \
    _Pragma("unroll")                                                        \
    for (int _r = 0; _r < 4; ++_r)                                           \
      gll16(_src + _r * 8192, _dst + _r * 8192);                             \
  } while (0)

#define VMCNT4 asm volatile("s_waitcnt vmcnt(4)" ::: "memory")
#define VMCNT0 asm volatile("s_waitcnt vmcnt(0)" ::: "memory")
#define SBAR   asm volatile("s_barrier" ::: "memory")

__global__ __launch_bounds__(512, 2) void vq_main(
    const float* __restrict__ zg,    // (BN, D) float32
    const int* __restrict__ maskg,   // (BN) mask, dtype probed
    const float* __restrict__ cbg,   // (K, D) float32 (rescan + gather)
    const char* __restrict__ cbt,    // stage-major swizzled bf16 hi
    const float* __restrict__ esqg,  // (K) fp64-acc esq
    float* __restrict__ outq,        // (BN, D) float32
    float* __restrict__ outidx,      // (BN) float32 (-1 pad)
    float* __restrict__ outls,       // loss scalar
    float* __restrict__ wsum,        // d_ws fp32 accumulator
    unsigned int* __restrict__ dcnt) // done counter (loss fusion)
{
  // ~74 KB LDS; 8 waves (2/SIMD). A (z) lives in registers, not LDS.
  __shared__ __align__(16) char bufB[2][32768];   // B dbuf: 64 codes hi
  __shared__ float esqs[KCB];
  __shared__ float zsqs[MT];
  __shared__ float v1s[MT], v2s[MT];
  __shared__ int   i1s[MT];
  __shared__ float carr[MT];
  __shared__ int   fidxs[MT], maskb[MT], flaglist[MT];
  __shared__ int   flagcnt, mflags;

  const int tid   = threadIdx.x;
  const int lane  = tid & 63;
  const int wave  = tid >> 6;
  const int q     = lane >> 4;
  const int l15   = lane & 15;
  const int m0    = blockIdx.x * MT;
  const int rbase = wave * 32;           // wave's 32 local rows

  if (tid == 0) { flagcnt = 0; mflags = 0; }

  // ---- mask dtype probe on first 512 bytes (in-bounds under every layout) --
  int wm = 0;
  if (tid < 128) {
    unsigned int W = ((const unsigned int*)maskg)[tid];
    if (W > 1u) wm |= 1;
    if (W != 0u && W != 0x3f800000u) wm |= 2;
    unsigned int lo = W & 0xffffu, hi = W >> 16;
    if ((lo != 0u && lo != 0x3f80u) || (hi != 0u && hi != 0x3f80u)) wm |= 4;
  }
  if (wm) atomicOr(&mflags, wm);

  // ---- esq into LDS (512 threads, 512 entries) ----
  esqs[tid] = esqg[tid];

  // ---- prefetch stage 0 before the z prologue (overlaps with z loads) ----
  ISSUE(0, 0);

  // ---- z -> A registers: 32 rows/wave, bf16 hi/lo; fused exact-fp32 z_sq --
  bf16x8 ah[2][8], al[2][8];
  float zacc0 = 0.f, zacc1 = 0.f;
#pragma unroll
  for (int i = 0; i < 2; ++i) {
    const int grow = m0 + rbase + i * 16 + l15;
#pragma unroll
    for (int kk = 0; kk < 8; ++kk) {
      const float* src = &zg[(size_t)grow * DD + kk * 32 + q * 8];
      float4 v0 = *(const float4*)src;
      float4 v1 = *(const float4*)(src + 4);
      float f[8] = {v0.x, v0.y, v0.z, v0.w, v1.x, v1.y, v1.z, v1.w};
      union { ushort us[8]; bf16x8 v; } H, L;
#pragma unroll
      for (int e = 0; e < 8; ++e) {
        unsigned short hh = f2bf(f[e]);
        H.us[e] = hh;
        L.us[e] = f2bf(f[e] - bf2f(hh));
      }
      ah[i][kk] = H.v;
      al[i][kk] = L.v;
      float s = 0.f;
#pragma unroll
      for (int e = 0; e < 8; ++e) s = fmaf(f[e], f[e], s);
      if (i == 0) zacc0 += s; else zacc1 += s;
    }
  }
  {
    float s0 = zacc0, s1 = zacc1;
    s0 += __shfl_xor(s0, 16, 64); s0 += __shfl_xor(s0, 32, 64);
    s1 += __shfl_xor(s1, 16, 64); s1 += __shfl_xor(s1, 32, 64);
    if (q == 0) {
      zsqs[rbase + l15]      = s0;
      zsqs[rbase + 16 + l15] = s1;
    }
  }
  __syncthreads();   // drains z loads + stage 0; esqs/zsqs/mflags visible
  const int mmode = mflags;

  // ---- per-thread running top-2 over all 512 codes ----
  float t1[2][4], t2[2][4];
  int   ti[2][4];
#pragma unroll
  for (int i = 0; i < 2; ++i)
#pragma unroll
    for (int rr = 0; rr < 4; ++rr) { t1[i][rr] = 3.0e38f; t2[i][rr] = 3.0e38f; ti[i][rr] = 0; }

  // ---- 8-stage pipeline over codes; all waves consume the same B tile ----
  // 2-pass MFMA per code-tile: (ah + al) x bh  == exact z.e_hi in fp32.
#pragma unroll 1
  for (int s = 0; s < NST; ++s) {
    if (s < NST - 1) { ISSUE(s + 1, (s + 1) & 1); VMCNT4; }
    else             { VMCNT0; }
    SBAR;
    __builtin_amdgcn_s_setprio(1);
    const char* bb = &bufB[s & 1][0];
#pragma unroll
    for (int tt = 0; tt < 4; ++tt) {
      const int lc = tt * 16 + l15;
      const unsigned sw = ((unsigned)(l15 & 7)) << 4;
      f32x4 a0 = (f32x4){0.f, 0.f, 0.f, 0.f};
      f32x4 a1 = (f32x4){0.f, 0.f, 0.f, 0.f};
#pragma unroll
      for (int kk = 0; kk < 8; ++kk) {
        const unsigned off = ((unsigned)(lc * 512 + kk * 64 + q * 16)) ^ sw;
        bf16x8 bh = *(const bf16x8*)(bb + off);
        a0 = __builtin_amdgcn_mfma_f32_16x16x32_bf16(ah[0][kk], bh, a0, 0, 0, 0);
        a1 = __builtin_amdgcn_mfma_f32_16x16x32_bf16(ah[1][kk], bh, a1, 0, 0, 0);
        a0 = __builtin_amdgcn_mfma_f32_16x16x32_bf16(al[0][kk], bh, a0, 0, 0, 0);
        a1 = __builtin_amdgcn_mfma_f32_16x16x32_bf16(al[1][kk], bh, a1, 0, 0, 0);
      }
      // fold: half-score v = esq/2 - dot; strict < keeps lowest idx
      const int code = s * 64 + lc;
      const float eh = 0.5f * esqs[code];
#pragma unroll
      for (int rr = 0; rr < 4; ++rr) {
        {
          float v = eh - a0[rr];
          bool  tk = v < t1[0][rr];
          float m2 = fminf(t2[0][rr], v);
          t2[0][rr] = tk ? t1[0][rr] : m2;
          ti[0][rr] = tk ? code : ti[0][rr];
          t1[0][rr] = tk ? v : t1[0][rr];
        }
        {
          float v = eh - a1[rr];
          bool  tk = v < t1[1][rr];
          float m2 = fminf(t2[1][rr], v);
          t2[1][rr] = tk ? t1[1][rr] : m2;
          ti[1][rr] = tk ? code : ti[1][rr];
          t1[1][rr] = tk ? v : t1[1][rr];
        }
      }
    }
    __builtin_amdgcn_s_setprio(0);
    SBAR;            // all waves done reading this buffer -> safe to refill
  }

  // ---- reduce across the 16 lanes (l15) sharing the same rows; store ------
#pragma unroll
  for (int i = 0; i < 2; ++i)
#pragma unroll
    for (int rr = 0; rr < 4; ++rr) {
      float a1 = t1[i][rr], a2 = t2[i][rr];
      int   ai = ti[i][rr];
#pragma unroll
      for (int m = 1; m < 16; m <<= 1) {
        float o1 = __shfl_xor(a1, m, 64);
        float o2 = __shfl_xor(a2, m, 64);
        int   oi = __shfl_xor(ai, m, 64);
        bool  tk = (o1 < a1) || (o1 == a1 && oi < ai);
        float losr = tk ? a1 : o1;
        a2 = fminf(fminf(a2, o2), losr);
        a1 = tk ? o1 : a1;
        ai = tk ? oi : ai;
      }
      if (l15 == 0) {
        int row = rbase + i * 16 + q * 4 + rr;   // unique owner per row
        v1s[row] = a1; v2s[row] = a2; i1s[row] = ai;
      }
    }
  __syncthreads();

  // ---- per-row finalize (rows disjoint across waves) ----------------------
  if (tid < MT) {
    float bv1 = v1s[tid], bv2 = v2s[tid];
    int   bi = i1s[tid];
    fidxs[tid] = bi;
    carr[tid]  = zsqs[tid] + 2.f * bv1;   // min ||z-e||^2
    if (2.f * (bv2 - bv1) < 0.30f) {      // near-tie -> exact fp64 rescan
      int pos = atomicAdd(&flagcnt, 1);   // (0.30 = 6-sigma of 2-pass error)
      flaglist[pos] = tid;
    }
    int mk;
    if (!(mmode & 1))      mk = maskg[m0 + tid] ? 1 : 0;                          // int32
    else if (!(mmode & 2)) mk = ((const float*)maskg)[m0 + tid] != 0.f ? 1 : 0;   // fp32
    else if (!(mmode & 4)) mk = ((const unsigned short*)maskg)[m0 + tid] ? 1 : 0; // bf16
    else                   mk = ((const unsigned char*)maskg)[m0 + tid] ? 1 : 0;  // bool
    maskb[tid] = mk;
  }
  __syncthreads();

  // ---- exact fp64 rescan: WAVE-PARALLEL (8 rows/batch, no inner barriers).
  //      Per lane: 8 codes (lane*8..+7), 8 independent fp64 fma chains.
  int nflag = flagcnt;
  for (int f0 = 0; f0 < nflag; f0 += 8) {
    const int fi = f0 + wave;
    if (fi < nflag) {
      const int row = flaglist[fi];
      const float* zr = &zg[(size_t)(m0 + row) * DD];
      const float* cb = &cbg[(size_t)(lane * 8) * DD];
      double d2[8] = {0., 0., 0., 0., 0., 0., 0., 0.};
      for (int d = 0; d < DD; ++d) {
        double zd = (double)zr[d];
#pragma unroll
        for (int c = 0; c < 8; ++c) {
          double df = zd - (double)cb[(size_t)c * DD + d];
          d2[c] = fma(df, df, d2[c]);
        }
      }
      double bd = d2[0];
      int    bk = lane * 8;
#pragma unroll
      for (int c = 1; c < 8; ++c)
        if (d2[c] < bd) { bd = d2[c]; bk = lane * 8 + c; }
      for (int m = 1; m < 64; m <<= 1) {
        double od = __shfl_xor(bd, m, 64);
        int    ok = __shfl_xor(bk, m, 64);
        if (od < bd || (od == bd && ok < bk)) { bd = od; bk = ok; }
      }
      if (lane == 0) { fidxs[row] = bk; carr[row] = (float)bd; }
    }
  }
  __syncthreads();

  // ---- index output: float32 values, -1.0 pad ----
  if (tid < MT)
    outidx[m0 + tid] = maskb[tid] ? (float)(fidxs[tid] & (KCB - 1)) : -1.0f;

  // ---- commit partial -> device atomicAdd (waves 0-3, 64 rows each) -------
  if (tid < MT) {
    float c = carr[tid];
    for (int m = 1; m < 64; m <<= 1) c += __shfl_xor(c, m, 64);
    if (lane == 0) atomicAdd(wsum, c);
  }

  // ---- quantized output: float32 codebook gather, masked ----
#pragma unroll
  for (int it = 0; it < 32; ++it) {
    int idx = it * 512 + tid;             // float4 index: 256 rows x 64
    int row = idx >> 6;
    int f4  = idx & 63;
    int k   = fidxs[row] & (KCB - 1);
    float4 val = {0.f, 0.f, 0.f, 0.f};
    if (maskb[row]) val = ((const float4*)cbg)[(size_t)k * 64 + f4];
    ((float4*)outq)[(size_t)(m0 + row) * 64 + f4] = val;
  }

  // ---- fused loss finalize: last block computes outls ----
  __syncthreads();   // block's wsum atomics drained before counting
  if (tid == 0) {
    __threadfence();
    unsigned prev = atomicAdd(dcnt, 1u);
    if (prev == (unsigned)(NBLK - 1)) {
      float s = atomicAdd(wsum, 0.f);     // device-coherent read
      outls[0] = 0.25f * (s / 16777216.0f);   // mean over B*N*D
    }
  }
}

// ================= fallback (no workspace): in-register B conversion =======
__global__ __launch_bounds__(256, 3) void vq_main_fb(
    const float* __restrict__ zg, const int* __restrict__ maskg,
    const float* __restrict__ cbg, float* __restrict__ outq,
    float* __restrict__ outidx, float* __restrict__ wsum)
{
  __shared__ unsigned short zs_hi[8 * 32 * 32];
  __shared__ unsigned short zs_lo[8 * 32 * 32];
  __shared__ float esqs[KCB];
  __shared__ float zsq[32];
  __shared__ float wv1[4][32], wv2[4][32];
  __shared__ int   wi1[4][32];
  __shared__ float carr[32];
  __shared__ int   fidxs[32], maskb[32], flaglist[32];
  __shared__ int   flagcnt, mflags;
  __shared__ double rbd[4];
  __shared__ int    rbi[4];

  const int tid  = threadIdx.x;
  const int lane = tid & 63;
  const int wave = tid >> 6;
  const int q    = lane >> 4;
  const int l15  = lane & 15;
  const int m0   = blockIdx.x * 32;

  if (tid == 0) { flagcnt = 0; mflags = 0; }
  int wm = 0;
  if (tid < 128) {
    unsigned int W = ((const unsigned int*)maskg)[tid];
    if (W > 1u) wm |= 1;
    if (W != 0u && W != 0x3f800000u) wm |= 2;
    unsigned int lo = W & 0xffffu, hi = W >> 16;
    if ((lo != 0u && lo != 0x3f80u) || (hi != 0u && hi != 0x3f80u)) wm |= 4;
  }
  if (wm) atomicOr(&mflags, wm);

#pragma unroll
  for (int i = 0; i < 8; ++i) {
    int idx = i * 256 + tid;
    int row = idx >> 6;
    int f4  = idx & 63;
    float4 v = ((const float4*)zg)[(size_t)(m0 + row) * 64 + f4];
    int ch  = f4 >> 3;
    int col = (f4 & 7) * 4;
    int base = (ch * 32 + row) * 32 + col;
    ushort4 h, l;
    h.x = f2bf(v.x); l.x = f2bf(v.x - bf2f(h.x));
    h.y = f2bf(v.y); l.y = f2bf(v.y - bf2f(h.y));
    h.z = f2bf(v.z); l.z = f2bf(v.z - bf2f(h.z));
    h.w = f2bf(v.w); l.w = f2bf(v.w - bf2f(h.w));
    *(ushort4*)&zs_hi[base] = h;
    *(ushort4*)&zs_lo[base] = l;
    float s = v.x * v.x + v.y * v.y + v.z * v.z + v.w * v.w;
#pragma unroll
    for (int m = 1; m < 64; m <<= 1) s += __shfl_xor(s, m, 64);
    if (lane == 0) zsq[row] = s;
  }
  for (int c = tid; c < KCB; c += 256) {
    float s = 0.f;
    for (int f4i = 0; f4i < 64; ++f4i) {
      float4 v = ((const float4*)cbg)[(size_t)c * 64 + f4i];
      s = fmaf(v.x, v.x, s); s = fmaf(v.y, v.y, s);
      s = fmaf(v.z, v.z, s); s = fmaf(v.w, v.w, s);
    }
    esqs[c] = s;
  }
  __syncthreads();
  const int mmode = mflags;

  f32x4 acc[8][2];
#pragma unroll
  for (int t = 0; t < 8; ++t) {
    acc[t][0] = (f32x4){0.f, 0.f, 0.f, 0.f};
    acc[t][1] = (f32x4){0.f, 0.f, 0.f, 0.f};
  }
  const unsigned short* Abh = &zs_hi[l15 * 32 + q * 8];
  const unsigned short* Abl = &zs_lo[l15 * 32 + q * 8];

  for (int kk = 0; kk < 8; ++kk) {
    bf16x8 ah0 = *(const bf16x8*)(Abh + kk * 1024);
    bf16x8 ah1 = *(const bf16x8*)(Abh + kk * 1024 + 512);
    bf16x8 al0 = *(const bf16x8*)(Abl + kk * 1024);
    bf16x8 al1 = *(const bf16x8*)(Abl + kk * 1024 + 512);
#pragma unroll
    for (int t = 0; t < 8; ++t) {
      const int code_row = (wave * 8 + t) * 16 + l15;
      const float* src = &cbg[(size_t)code_row * 256 + kk * 32 + q * 8];
      float4 v0 = *(const float4*)src;
      float4 v1 = *(const float4*)(src + 4);
      float f[8] = {v0.x, v0.y, v0.z, v0.w, v1.x, v1.y, v1.z, v1.w};
      union { ushort us[8]; bf16x8 v; } H, L;
#pragma unroll
      for (int e = 0; e < 8; ++e) {
        unsigned short hh = f2bf(f[e]);
        H.us[e] = hh;
        L.us[e] = f2bf(f[e] - bf2f(hh));
      }
      bf16x8 bh = H.v, bl = L.v;
      acc[t][0] = __builtin_amdgcn_mfma_f32_16x16x32_bf16(ah0, bh, acc[t][0], 0, 0, 0);
      acc[t][1] = __builtin_amdgcn_mfma_f32_16x16x32_bf16(ah1, bh, acc[t][1], 0, 0, 0);
      acc[t][0] = __builtin_amdgcn_mfma_f32_16x16x32_bf16(al0, bh, acc[t][0], 0, 0, 0);
      acc[t][1] = __builtin_amdgcn_mfma_f32_16x16x32_bf16(al1, bh, acc[t][1], 0, 0, 0);
      acc[t][0] = __builtin_amdgcn_mfma_f32_16x16x32_bf16(ah0, bl, acc[t][0], 0, 0, 0);
      acc[t][1] = __builtin_amdgcn_mfma_f32_16x16x32_bf16(ah1, bl, acc[t][1], 0, 0, 0);
    }
  }

  float t1[2][4], t2[2][4];
  int   ti[2][4];
#pragma unroll
  for (int i = 0; i < 2; ++i)
#pragma unroll
    for (int rr = 0; rr < 4; ++rr) { t1[i][rr] = 3.0e38f; t2[i][rr] = 3.0e38f; ti[i][rr] = 0; }
#pragma unroll
  for (int t = 0; t < 8; ++t) {
    const int code = (wave * 8 + t) * 16 + l15;
    const float eh = 0.5f * esqs[code];
#pragma unroll
    for (int i = 0; i < 2; ++i)
#pragma unroll
      for (int rr = 0; rr < 4; ++rr) {
        float v = eh - acc[t][i][rr];
        bool  tk = v < t1[i][rr];
        float m2 = fminf(t2[i][rr], v);
        t2[i][rr] = tk ? t1[i][rr] : m2;
        ti[i][rr] = tk ? code : ti[i][rr];
        t1[i][rr] = tk ? v : t1[i][rr];
      }
  }
#pragma unroll
  for (int i = 0; i < 2; ++i)
#pragma unroll
    for (int rr = 0; rr < 4; ++rr) {
      float a1 = t1[i][rr], a2 = t2[i][rr];
      int   ai = ti[i][rr];
#pragma unroll
      for (int m = 1; m < 16; m <<= 1) {
        float o1 = __shfl_xor(a1, m, 64);
        float o2 = __shfl_xor(a2, m, 64);
        int   oi = __shfl_xor(ai, m, 64);
        bool  tk = (o1 < a1) || (o1 == a1 && oi < ai);
        float losr = tk ? a1 : o1;
        a2 = fminf(fminf(a2, o2), losr);
        a1 = tk ? o1 : a1;
        ai = tk ? oi : ai;
      }
      if (l15 == 0) {
        int row = i * 16 + q * 4 + rr;
        wv1[wave][row] = a1; wv2[wave][row] = a2; wi1[wave][row] = ai;
      }
    }
  __syncthreads();

  if (tid < 32) {
    float bv1 = 3.0e38f, bv2 = 3.0e38f;
    int   bi = 0x7fffffff;
#pragma unroll
    for (int w = 0; w < 4; ++w) {
      float a1 = wv1[w][tid], a2 = wv2[w][tid];
      int   ai = wi1[w][tid];
      bool  tk = (a1 < bv1) || (a1 == bv1 && ai < bi);
      if (tk) { bv2 = fminf(bv1, a2); bv1 = a1; bi = ai; }
      else    { bv2 = fminf(bv2, a1); }
    }
    fidxs[tid] = bi;
    carr[tid]  = zsq[tid] + 2.f * bv1;
    if (2.f * (bv2 - bv1) < 0.02f) {
      int pos = atomicAdd(&flagcnt, 1);
      flaglist[pos] = tid;
    }
    int mk;
    if (!(mmode & 1))      mk = maskg[m0 + tid] ? 1 : 0;
    else if (!(mmode & 2)) mk = ((const float*)maskg)[m0 + tid] != 0.f ? 1 : 0;
    else if (!(mmode & 4)) mk = ((const unsigned short*)maskg)[m0 + tid] ? 1 : 0;
    else                   mk = ((const unsigned char*)maskg)[m0 + tid] ? 1 : 0;
    maskb[tid] = mk;
  }
  __syncthreads();

  int nflag = flagcnt;
  for (int f = 0; f < nflag; ++f) {
    int row = flaglist[f];
    double bd = 1e300;
    int    bk = 0;
    for (int k = tid; k < KCB; k += 256) {
      double d2 = 0.0;
      for (int d = 0; d < DD; ++d) {
        double df = (double)zg[(size_t)(m0 + row) * DD + d] - (double)cbg[(size_t)k * DD + d];
        d2 = fma(df, df, d2);
      }
      if (d2 < bd) { bd = d2; bk = k; }
    }
    for (int m = 1; m < 64; m <<= 1) {
      double od = __shfl_xor(bd, m, 64);
      int    ok = __shfl_xor(bk, m, 64);
      if (od < bd || (od == bd && ok < bk)) { bd = od; bk = ok; }
    }
    if (lane == 0) { rbd[wave] = bd; rbi[wave] = bk; }
    __syncthreads();
    if (tid == 0) {
      double xd = rbd[0]; int xk = rbi[0];
      for (int w = 1; w < 4; ++w)
        if (rbd[w] < xd || (rbd[w] == xd && rbi[w] < xk)) { xd = rbd[w]; xk = rbi[w]; }
      fidxs[row] = xk;
      carr[row]  = (float)xd;
    }
    __syncthreads();
  }
  __syncthreads();

  if (tid < 32)
    outidx[m0 + tid] = maskb[tid] ? (float)(fidxs[tid] & (KCB - 1)) : -1.0f;

  if (wave == 0) {
    float c = (lane < 32) ? carr[lane] : 0.f;
    for (int m = 1; m < 64; m <<= 1) c += __shfl_xor(c, m, 64);
    if (lane == 0) atomicAdd(wsum, c);
  }

#pragma unroll
  for (int i = 0; i < 8; ++i) {
    int idx = i * 256 + tid;
    int row = idx >> 6;
    int f4  = idx & 63;
    int k   = fidxs[row] & (KCB - 1);
    float4 val = {0.f, 0.f, 0.f, 0.f};
    if (maskb[row]) val = ((const float4*)cbg)[(size_t)k * 64 + f4];
    ((float4*)outq)[(size_t)(m0 + row) * 64 + f4] = val;
  }
}

__global__ void vq_final(const float* __restrict__ wsum,
                         float* __restrict__ outloss) {
  if (threadIdx.x == 0)
    outloss[0] = 0.25f * (wsum[0] / 16777216.0f);   // mean over B*N*D
}

extern "C" void kernel_launch(void* const* d_in, const int* in_sizes, int n_in,
                              void* d_out, int out_size, void* d_ws, size_t ws_size,
                              hipStream_t stream) {
  // Inputs identified by element count. z/codebook FLOAT32, mask probed.
  const void* pz = d_in[0];
  const void* pm = (n_in > 1) ? d_in[1] : d_in[0];
  const void* pc = (n_in > 2) ? d_in[2] : d_in[0];
  for (int i = 0; i < n_in; ++i) {
    if      (in_sizes[i] == BN * DD)  pz = d_in[i];
    else if (in_sizes[i] == BN)       pm = d_in[i];
    else if (in_sizes[i] == KCB * DD) pc = d_in[i];
  }
  const float* zg  = (const float*)pz;
  const int*   mk  = (const int*)pm;
  const float* cbg = (const float*)pc;

  float* outq   = (float*)d_out;
  float* outidx = outq + (size_t)BN * DD;
  float* outls  = outidx + BN;
  float* wsum   = (float*)d_ws;

  // ws layout: [0] wsum | +512 dcnt | +1024 esq (2KB) | +4096 cbt (256KB hi)
  unsigned int* dcnt = (unsigned int*)((char*)d_ws + 512);
  const size_t ESQ_OFF = 1024;
  const size_t CBT_OFF = 4096;
  const size_t WS_NEED = CBT_OFF + (size_t)KCB * DD * 2;   // 260 KB

  if (ws_size >= WS_NEED) {
    char*  cbt = (char*)d_ws + CBT_OFF;
    float* esw = (float*)((char*)d_ws + ESQ_OFF);
    vq_prep<<<128, 256, 0, stream>>>(cbg, cbt, esw, wsum, dcnt);
    vq_main<<<NBLK, 512, 0, stream>>>(zg, mk, cbg, cbt, esw,
                                      outq, outidx, outls, wsum, dcnt);
  } else {
    vq_zero_ws<<<1, 1, 0, stream>>>(wsum);
    vq_main_fb<<<2048, 256, 0, stream>>>(zg, mk, cbg, outq, outidx, wsum);
    vq_final<<<1, 64, 0, stream>>>(wsum, outls);
  }
}

// Round 7
// 252.177 us; speedup vs baseline: 2.8259x; 2.8259x over previous
//
#include <hip/hip_runtime.h>

// Problem constants
#define BN    65536    // B*N rows
#define DD    256      // D
#define KCB   512      // codebook entries
#define MT    256      // rows per block (main kernel)
#define NBLK  256      // BN/MT -> exactly 1 block per CU (proven best)
#define NST   8        // codebook stages of 64 codes (hi-only staging)

typedef __attribute__((ext_vector_type(8))) short bf16x8;
typedef __attribute__((ext_vector_type(4))) float f32x4;

static __device__ __forceinline__ float bf2f(unsigned short u) {
  return __uint_as_float(((unsigned int)u) << 16);
}
static __device__ __forceinline__ unsigned short f2bf(float f) {
  unsigned int u = __float_as_uint(f);
  return (unsigned short)((u + 0x7fffu + ((u >> 16) & 1u)) >> 16);  // RNE
}
static __device__ __forceinline__ void gll16(const void* g, void* l) {
  __builtin_amdgcn_global_load_lds(
      (const __attribute__((address_space(1))) unsigned int*)g,
      (__attribute__((address_space(3))) unsigned int*)l, 16, 0, 0);
}

__global__ void vq_zero_ws(float* ws) { ws[0] = 0.f; }   // fallback path only

// ---- one-shot prep: codebook fp32 -> bf16 HI ONLY (stage-major, XOR
// bank-swizzle pre-applied in GLOBAL memory: linear global_load_lds dest +
// inverse-swz source + swz read), PLUS a TRANSPOSED fp32 copy cbT[d][k] for
// the coalesced exact rescan, PLUS fp64-exact e_sq, PLUS wsum/dcnt zeroing.
// Stage s (64 codes, 32 KB) at s*32768; code lc byte b at
// (lc*512 + b) ^ ((lc&7)<<4).
__global__ void vq_prep(const float* __restrict__ cbg,
                        char* __restrict__ cbt,
                        float* __restrict__ cbf,   // (D, K) transposed fp32
                        float* __restrict__ esq,
                        float* __restrict__ wsum,
                        unsigned int* __restrict__ dcnt) {
  if (blockIdx.x == 0 && threadIdx.x == 0) { wsum[0] = 0.f; dcnt[0] = 0u; }
  const int tid = threadIdx.x, lane = tid & 63, wave = tid >> 6;
  const int code = blockIdx.x * 4 + wave;
  float4 v = ((const float4*)cbg)[(size_t)code * 64 + lane];
  ushort4 h;
  h.x = f2bf(v.x); h.y = f2bf(v.y); h.z = f2bf(v.z); h.w = f2bf(v.w);
  const int s  = code >> 6;
  const int lc = code & 63;
  unsigned raw = (unsigned)(lc * 512 + lane * 8);     // 8 bytes per lane
  unsigned off = (unsigned)(s * 32768) + (raw ^ ((unsigned)(lc & 7) << 4));
  *(ushort4*)(cbt + off) = h;
  // transposed fp32 copy: cbT[d][k] (scattered one-shot stores, ~512 KB)
  cbf[(size_t)(lane * 4 + 0) * KCB + code] = v.x;
  cbf[(size_t)(lane * 4 + 1) * KCB + code] = v.y;
  cbf[(size_t)(lane * 4 + 2) * KCB + code] = v.z;
  cbf[(size_t)(lane * 4 + 3) * KCB + code] = v.w;
  double sq = (double)v.x * v.x + (double)v.y * v.y +
              (double)v.z * v.z + (double)v.w * v.w;
#pragma unroll
  for (int m = 1; m < 64; m <<= 1) sq += __shfl_xor(sq, m, 64);
  if (lane == 0) esq[code] = (float)sq;
}

// issue stage S (32 KB) into LDS buffer BSEL: 4 x global_load_lds(16B) per
// thread (512 threads); dest = wave-uniform base + lane*16 (HW requirement).
#define ISSUE(S, BSEL)                                                       \
  do {                                                                       \
    const char* _src = cbt + (size_t)(S) * 32768 + (size_t)tid * 16;         \
    char* _dst = &bufB[BSEL][tid * 16];                                      \
    _Pragma("unroll")                                                        \
    for (int _r = 0; _r < 4; ++_r)                                           \
      gll16(_src + _r * 8192, _dst + _r * 8192);                             \
  } while (0)

#define VMCNT4 asm volatile("s_waitcnt vmcnt(4)" ::: "memory")
#define VMCNT0 asm volatile("s_waitcnt vmcnt(0)" ::: "memory")
#define SBAR   asm volatile("s_barrier" ::: "memory")

__global__ __launch_bounds__(512, 2) void vq_main(
    const float* __restrict__ zg,    // (BN, D) float32
    const int* __restrict__ maskg,   // (BN) mask, dtype probed
    const float* __restrict__ cbg,   // (K, D) float32 (gather)
    const char* __restrict__ cbt,    // stage-major swizzled bf16 hi
    const float* __restrict__ cbf,   // (D, K) transposed fp32 (rescan)
    const float* __restrict__ esqg,  // (K) fp64-acc esq
    float* __restrict__ outq,        // (BN, D) float32
    float* __restrict__ outidx,      // (BN) float32 (-1 pad)
    float* __restrict__ outls,       // loss scalar
    float* __restrict__ wsum,        // d_ws fp32 accumulator
    unsigned int* __restrict__ dcnt) // done counter (loss fusion)
{
  // ~74 KB LDS; 8 waves (2/SIMD). A (z) lives in registers, not LDS.
  __shared__ __align__(16) char bufB[2][32768];   // B dbuf: 64 codes hi
  __shared__ float esqs[KCB];
  __shared__ float zsqs[MT];
  __shared__ float v1s[MT], v2s[MT];
  __shared__ int   i1s[MT];
  __shared__ float carr[MT];
  __shared__ int   fidxs[MT], maskb[MT], flaglist[MT];
  __shared__ int   flagcnt, mflags;

  const int tid   = threadIdx.x;
  const int lane  = tid & 63;
  const int wave  = tid >> 6;
  const int q     = lane >> 4;
  const int l15   = lane & 15;
  const int m0    = blockIdx.x * MT;
  const int rbase = wave * 32;           // wave's 32 local rows

  if (tid == 0) { flagcnt = 0; mflags = 0; }

  // ---- mask dtype probe on first 512 bytes (in-bounds under every layout) --
  int wm = 0;
  if (tid < 128) {
    unsigned int W = ((const unsigned int*)maskg)[tid];
    if (W > 1u) wm |= 1;
    if (W != 0u && W != 0x3f800000u) wm |= 2;
    unsigned int lo = W & 0xffffu, hi = W >> 16;
    if ((lo != 0u && lo != 0x3f80u) || (hi != 0u && hi != 0x3f80u)) wm |= 4;
  }
  if (wm) atomicOr(&mflags, wm);

  // ---- esq into LDS (512 threads, 512 entries) ----
  esqs[tid] = esqg[tid];

  // ---- prefetch stage 0 before the z prologue (overlaps with z loads) ----
  ISSUE(0, 0);

  // ---- z -> A registers: 32 rows/wave, bf16 hi/lo; fused exact-fp32 z_sq --
  bf16x8 ah[2][8], al[2][8];
  float zacc0 = 0.f, zacc1 = 0.f;
#pragma unroll
  for (int i = 0; i < 2; ++i) {
    const int grow = m0 + rbase + i * 16 + l15;
#pragma unroll
    for (int kk = 0; kk < 8; ++kk) {
      const float* src = &zg[(size_t)grow * DD + kk * 32 + q * 8];
      float4 v0 = *(const float4*)src;
      float4 v1 = *(const float4*)(src + 4);
      float f[8] = {v0.x, v0.y, v0.z, v0.w, v1.x, v1.y, v1.z, v1.w};
      union { ushort us[8]; bf16x8 v; } H, L;
#pragma unroll
      for (int e = 0; e < 8; ++e) {
        unsigned short hh = f2bf(f[e]);
        H.us[e] = hh;
        L.us[e] = f2bf(f[e] - bf2f(hh));
      }
      ah[i][kk] = H.v;
      al[i][kk] = L.v;
      float s = 0.f;
#pragma unroll
      for (int e = 0; e < 8; ++e) s = fmaf(f[e], f[e], s);
      if (i == 0) zacc0 += s; else zacc1 += s;
    }
  }
  {
    float s0 = zacc0, s1 = zacc1;
    s0 += __shfl_xor(s0, 16, 64); s0 += __shfl_xor(s0, 32, 64);
    s1 += __shfl_xor(s1, 16, 64); s1 += __shfl_xor(s1, 32, 64);
    if (q == 0) {
      zsqs[rbase + l15]      = s0;
      zsqs[rbase + 16 + l15] = s1;
    }
  }
  __syncthreads();   // drains z loads + stage 0; esqs/zsqs/mflags visible
  const int mmode = mflags;

  // ---- per-thread running top-2 over all 512 codes ----
  float t1[2][4], t2[2][4];
  int   ti[2][4];
#pragma unroll
  for (int i = 0; i < 2; ++i)
#pragma unroll
    for (int rr = 0; rr < 4; ++rr) { t1[i][rr] = 3.0e38f; t2[i][rr] = 3.0e38f; ti[i][rr] = 0; }

  // ---- 8-stage pipeline over codes; all waves consume the same B tile ----
  // 2-pass MFMA per code-tile: (ah + al) x bh  == exact z.e_hi in fp32.
#pragma unroll 1
  for (int s = 0; s < NST; ++s) {
    if (s < NST - 1) { ISSUE(s + 1, (s + 1) & 1); VMCNT4; }
    else             { VMCNT0; }
    SBAR;
    __builtin_amdgcn_s_setprio(1);
    const char* bb = &bufB[s & 1][0];
#pragma unroll
    for (int tt = 0; tt < 4; ++tt) {
      const int lc = tt * 16 + l15;
      const unsigned sw = ((unsigned)(l15 & 7)) << 4;
      f32x4 a0 = (f32x4){0.f, 0.f, 0.f, 0.f};
      f32x4 a1 = (f32x4){0.f, 0.f, 0.f, 0.f};
#pragma unroll
      for (int kk = 0; kk < 8; ++kk) {
        const unsigned off = ((unsigned)(lc * 512 + kk * 64 + q * 16)) ^ sw;
        bf16x8 bh = *(const bf16x8*)(bb + off);
        a0 = __builtin_amdgcn_mfma_f32_16x16x32_bf16(ah[0][kk], bh, a0, 0, 0, 0);
        a1 = __builtin_amdgcn_mfma_f32_16x16x32_bf16(ah[1][kk], bh, a1, 0, 0, 0);
        a0 = __builtin_amdgcn_mfma_f32_16x16x32_bf16(al[0][kk], bh, a0, 0, 0, 0);
        a1 = __builtin_amdgcn_mfma_f32_16x16x32_bf16(al[1][kk], bh, a1, 0, 0, 0);
      }
      // fold: half-score v = esq/2 - dot; strict < keeps lowest idx
      const int code = s * 64 + lc;
      const float eh = 0.5f * esqs[code];
#pragma unroll
      for (int rr = 0; rr < 4; ++rr) {
        {
          float v = eh - a0[rr];
          bool  tk = v < t1[0][rr];
          float m2 = fminf(t2[0][rr], v);
          t2[0][rr] = tk ? t1[0][rr] : m2;
          ti[0][rr] = tk ? code : ti[0][rr];
          t1[0][rr] = tk ? v : t1[0][rr];
        }
        {
          float v = eh - a1[rr];
          bool  tk = v < t1[1][rr];
          float m2 = fminf(t2[1][rr], v);
          t2[1][rr] = tk ? t1[1][rr] : m2;
          ti[1][rr] = tk ? code : ti[1][rr];
          t1[1][rr] = tk ? v : t1[1][rr];
        }
      }
    }
    __builtin_amdgcn_s_setprio(0);
    SBAR;            // all waves done reading this buffer -> safe to refill
  }

  // ---- reduce across the 16 lanes (l15) sharing the same rows; store ------
#pragma unroll
  for (int i = 0; i < 2; ++i)
#pragma unroll
    for (int rr = 0; rr < 4; ++rr) {
      float a1 = t1[i][rr], a2 = t2[i][rr];
      int   ai = ti[i][rr];
#pragma unroll
      for (int m = 1; m < 16; m <<= 1) {
        float o1 = __shfl_xor(a1, m, 64);
        float o2 = __shfl_xor(a2, m, 64);
        int   oi = __shfl_xor(ai, m, 64);
        bool  tk = (o1 < a1) || (o1 == a1 && oi < ai);
        float losr = tk ? a1 : o1;
        a2 = fminf(fminf(a2, o2), losr);
        a1 = tk ? o1 : a1;
        ai = tk ? oi : ai;
      }
      if (l15 == 0) {
        int row = rbase + i * 16 + q * 4 + rr;   // unique owner per row
        v1s[row] = a1; v2s[row] = a2; i1s[row] = ai;
      }
    }
  __syncthreads();

  // ---- per-row finalize (rows disjoint across waves) ----------------------
  if (tid < MT) {
    float bv1 = v1s[tid], bv2 = v2s[tid];
    int   bi = i1s[tid];
    fidxs[tid] = bi;
    carr[tid]  = zsqs[tid] + 2.f * bv1;   // min ||z-e||^2
    if (2.f * (bv2 - bv1) < 0.30f) {      // near-tie -> exact fp64 rescan
      int pos = atomicAdd(&flagcnt, 1);   // (0.30 = 6-sigma of 2-pass error)
      flaglist[pos] = tid;
    }
    int mk;
    if (!(mmode & 1))      mk = maskg[m0 + tid] ? 1 : 0;                          // int32
    else if (!(mmode & 2)) mk = ((const float*)maskg)[m0 + tid] != 0.f ? 1 : 0;   // fp32
    else if (!(mmode & 4)) mk = ((const unsigned short*)maskg)[m0 + tid] ? 1 : 0; // bf16
    else                   mk = ((const unsigned char*)maskg)[m0 + tid] ? 1 : 0;  // bool
    maskb[tid] = mk;
  }
  __syncthreads();

  // ---- exact fp64 rescan: WAVE-PARALLEL (8 rows/batch, no inner barriers),
  //      COALESCED via transposed codebook: lane handles codes lane+c*64,
  //      reads cbf[d*512 + lane + c*64] -> lane-stride 4B (4 lines/wave).
  int nflag = flagcnt;
  for (int f0 = 0; f0 < nflag; f0 += 8) {
    const int fi = f0 + wave;
    if (fi < nflag) {
      const int row = flaglist[fi];
      const float* zr = &zg[(size_t)(m0 + row) * DD];
      double d2[8] = {0., 0., 0., 0., 0., 0., 0., 0.};
      for (int d = 0; d < DD; ++d) {
        double zd = (double)zr[d];
        const float* cr = &cbf[(size_t)d * KCB + lane];
#pragma unroll
        for (int c = 0; c < 8; ++c) {
          double df = zd - (double)cr[c * 64];
          d2[c] = fma(df, df, d2[c]);
        }
      }
      double bd = d2[0];
      int    bk = lane;
#pragma unroll
      for (int c = 1; c < 8; ++c)           // ascending code order: strict <
        if (d2[c] < bd) { bd = d2[c]; bk = lane + c * 64; }
      for (int m = 1; m < 64; m <<= 1) {
        double od = __shfl_xor(bd, m, 64);
        int    ok = __shfl_xor(bk, m, 64);
        if (od < bd || (od == bd && ok < bk)) { bd = od; bk = ok; }
      }
      if (lane == 0) { fidxs[row] = bk; carr[row] = (float)bd; }
    }
  }
  __syncthreads();

  // ---- index output: float32 values, -1.0 pad ----
  if (tid < MT)
    outidx[m0 + tid] = maskb[tid] ? (float)(fidxs[tid] & (KCB - 1)) : -1.0f;

  // ---- commit partial -> device atomicAdd (waves 0-3, 64 rows each) -------
  if (tid < MT) {
    float c = carr[tid];
    for (int m = 1; m < 64; m <<= 1) c += __shfl_xor(c, m, 64);
    if (lane == 0) atomicAdd(wsum, c);
  }

  // ---- quantized output: float32 codebook gather, masked ----
#pragma unroll
  for (int it = 0; it < 32; ++it) {
    int idx = it * 512 + tid;             // float4 index: 256 rows x 64
    int row = idx >> 6;
    int f4  = idx & 63;
    int k   = fidxs[row] & (KCB - 1);
    float4 val = {0.f, 0.f, 0.f, 0.f};
    if (maskb[row]) val = ((const float4*)cbg)[(size_t)k * 64 + f4];
    ((float4*)outq)[(size_t)(m0 + row) * 64 + f4] = val;
  }

  // ---- fused loss finalize: last block computes outls ----
  __syncthreads();   // block's wsum atomics drained before counting
  if (tid == 0) {
    __threadfence();
    unsigned prev = atomicAdd(dcnt, 1u);
    if (prev == (unsigned)(NBLK - 1)) {
      float s = atomicAdd(wsum, 0.f);     // device-coherent read
      outls[0] = 0.25f * (s / 16777216.0f);   // mean over B*N*D
    }
  }
}

// ================= fallback (no workspace): in-register B conversion =======
__global__ __launch_bounds__(256, 3) void vq_main_fb(
    const float* __restrict__ zg, const int* __restrict__ maskg,
    const float* __restrict__ cbg, float* __restrict__ outq,
    float* __restrict__ outidx, float* __restrict__ wsum)
{
  __shared__ unsigned short zs_hi[8 * 32 * 32];
  __shared__ unsigned short zs_lo[8 * 32 * 32];
  __shared__ float esqs[KCB];
  __shared__ float zsq[32];
  __shared__ float wv1[4][32], wv2[4][32];
  __shared__ int   wi1[4][32];
  __shared__ float carr[32];
  __shared__ int   fidxs[32], maskb[32], flaglist[32];
  __shared__ int   flagcnt, mflags;
  __shared__ double rbd[4];
  __shared__ int    rbi[4];

  const int tid  = threadIdx.x;
  const int lane = tid & 63;
  const int wave = tid >> 6;
  const int q    = lane >> 4;
  const int l15  = lane & 15;
  const int m0   = blockIdx.x * 32;

  if (tid == 0) { flagcnt = 0; mflags = 0; }
  int wm = 0;
  if (tid < 128) {
    unsigned int W = ((const unsigned int*)maskg)[tid];
    if (W > 1u) wm |= 1;
    if (W != 0u && W != 0x3f800000u) wm |= 2;
    unsigned int lo = W & 0xffffu, hi = W >> 16;
    if ((lo != 0u && lo != 0x3f80u) || (hi != 0u && hi != 0x3f80u)) wm |= 4;
  }
  if (wm) atomicOr(&mflags, wm);

#pragma unroll
  for (int i = 0; i < 8; ++i) {
    int idx = i * 256 + tid;
    int row = idx >> 6;
    int f4  = idx & 63;
    float4 v = ((const float4*)zg)[(size_t)(m0 + row) * 64 + f4];
    int ch  = f4 >> 3;
    int col = (f4 & 7) * 4;
    int base = (ch * 32 + row) * 32 + col;
    ushort4 h, l;
    h.x = f2bf(v.x); l.x = f2bf(v.x - bf2f(h.x));
    h.y = f2bf(v.y); l.y = f2bf(v.y - bf2f(h.y));
    h.z = f2bf(v.z); l.z = f2bf(v.z - bf2f(h.z));
    h.w = f2bf(v.w); l.w = f2bf(v.w - bf2f(h.w));
    *(ushort4*)&zs_hi[base] = h;
    *(ushort4*)&zs_lo[base] = l;
    float s = v.x * v.x + v.y * v.y + v.z * v.z + v.w * v.w;
#pragma unroll
    for (int m = 1; m < 64; m <<= 1) s += __shfl_xor(s, m, 64);
    if (lane == 0) zsq[row] = s;
  }
  for (int c = tid; c < KCB; c += 256) {
    float s = 0.f;
    for (int f4i = 0; f4i < 64; ++f4i) {
      float4 v = ((const float4*)cbg)[(size_t)c * 64 + f4i];
      s = fmaf(v.x, v.x, s); s = fmaf(v.y, v.y, s);
      s = fmaf(v.z, v.z, s); s = fmaf(v.w, v.w, s);
    }
    esqs[c] = s;
  }
  __syncthreads();
  const int mmode = mflags;

  f32x4 acc[8][2];
#pragma unroll
  for (int t = 0; t < 8; ++t) {
    acc[t][0] = (f32x4){0.f, 0.f, 0.f, 0.f};
    acc[t][1] = (f32x4){0.f, 0.f, 0.f, 0.f};
  }
  const unsigned short* Abh = &zs_hi[l15 * 32 + q * 8];
  const unsigned short* Abl = &zs_lo[l15 * 32 + q * 8];

  for (int kk = 0; kk < 8; ++kk) {
    bf16x8 ah0 = *(const bf16x8*)(Abh + kk * 1024);
    bf16x8 ah1 = *(const bf16x8*)(Abh + kk * 1024 + 512);
    bf16x8 al0 = *(const bf16x8*)(Abl + kk * 1024);
    bf16x8 al1 = *(const bf16x8*)(Abl + kk * 1024 + 512);
#pragma unroll
    for (int t = 0; t < 8; ++t) {
      const int code_row = (wave * 8 + t) * 16 + l15;
      const float* src = &cbg[(size_t)code_row * 256 + kk * 32 + q * 8];
      float4 v0 = *(const float4*)src;
      float4 v1 = *(const float4*)(src + 4);
      float f[8] = {v0.x, v0.y, v0.z, v0.w, v1.x, v1.y, v1.z, v1.w};
      union { ushort us[8]; bf16x8 v; } H, L;
#pragma unroll
      for (int e = 0; e < 8; ++e) {
        unsigned short hh = f2bf(f[e]);
        H.us[e] = hh;
        L.us[e] = f2bf(f[e] - bf2f(hh));
      }
      bf16x8 bh = H.v, bl = L.v;
      acc[t][0] = __builtin_amdgcn_mfma_f32_16x16x32_bf16(ah0, bh, acc[t][0], 0, 0, 0);
      acc[t][1] = __builtin_amdgcn_mfma_f32_16x16x32_bf16(ah1, bh, acc[t][1], 0, 0, 0);
      acc[t][0] = __builtin_amdgcn_mfma_f32_16x16x32_bf16(al0, bh, acc[t][0], 0, 0, 0);
      acc[t][1] = __builtin_amdgcn_mfma_f32_16x16x32_bf16(al1, bh, acc[t][1], 0, 0, 0);
      acc[t][0] = __builtin_amdgcn_mfma_f32_16x16x32_bf16(ah0, bl, acc[t][0], 0, 0, 0);
      acc[t][1] = __builtin_amdgcn_mfma_f32_16x16x32_bf16(ah1, bl, acc[t][1], 0, 0, 0);
    }
  }

  float t1[2][4], t2[2][4];
  int   ti[2][4];
#pragma unroll
  for (int i = 0; i < 2; ++i)
#pragma unroll
    for (int rr = 0; rr < 4; ++rr) { t1[i][rr] = 3.0e38f; t2[i][rr] = 3.0e38f; ti[i][rr] = 0; }
#pragma unroll
  for (int t = 0; t < 8; ++t) {
    const int code = (wave * 8 + t) * 16 + l15;
    const float eh = 0.5f * esqs[code];
#pragma unroll
    for (int i = 0; i < 2; ++i)
#pragma unroll
      for (int rr = 0; rr < 4; ++rr) {
        float v = eh - acc[t][i][rr];
        bool  tk = v < t1[i][rr];
        float m2 = fminf(t2[i][rr], v);
        t2[i][rr] = tk ? t1[i][rr] : m2;
        ti[i][rr] = tk ? code : ti[i][rr];
        t1[i][rr] = tk ? v : t1[i][rr];
      }
  }
#pragma unroll
  for (int i = 0; i < 2; ++i)
#pragma unroll
    for (int rr = 0; rr < 4; ++rr) {
      float a1 = t1[i][rr], a2 = t2[i][rr];
      int   ai = ti[i][rr];
#pragma unroll
      for (int m = 1; m < 16; m <<= 1) {
        float o1 = __shfl_xor(a1, m, 64);
        float o2 = __shfl_xor(a2, m, 64);
        int   oi = __shfl_xor(ai, m, 64);
        bool  tk = (o1 < a1) || (o1 == a1 && oi < ai);
        float losr = tk ? a1 : o1;
        a2 = fminf(fminf(a2, o2), losr);
        a1 = tk ? o1 : a1;
        ai = tk ? oi : ai;
      }
      if (l15 == 0) {
        int row = i * 16 + q * 4 + rr;
        wv1[wave][row] = a1; wv2[wave][row] = a2; wi1[wave][row] = ai;
      }
    }
  __syncthreads();

  if (tid < 32) {
    float bv1 = 3.0e38f, bv2 = 3.0e38f;
    int   bi = 0x7fffffff;
#pragma unroll
    for (int w = 0; w < 4; ++w) {
      float a1 = wv1[w][tid], a2 = wv2[w][tid];
      int   ai = wi1[w][tid];
      bool  tk = (a1 < bv1) || (a1 == bv1 && ai < bi);
      if (tk) { bv2 = fminf(bv1, a2); bv1 = a1; bi = ai; }
      else    { bv2 = fminf(bv2, a1); }
    }
    fidxs[tid] = bi;
    carr[tid]  = zsq[tid] + 2.f * bv1;
    if (2.f * (bv2 - bv1) < 0.02f) {
      int pos = atomicAdd(&flagcnt, 1);
      flaglist[pos] = tid;
    }
    int mk;
    if (!(mmode & 1))      mk = maskg[m0 + tid] ? 1 : 0;
    else if (!(mmode & 2)) mk = ((const float*)maskg)[m0 + tid] != 0.f ? 1 : 0;
    else if (!(mmode & 4)) mk = ((const unsigned short*)maskg)[m0 + tid] ? 1 : 0;
    else                   mk = ((const unsigned char*)maskg)[m0 + tid] ? 1 : 0;
    maskb[tid] = mk;
  }
  __syncthreads();

  int nflag = flagcnt;
  for (int f = 0; f < nflag; ++f) {
    int row = flaglist[f];
    double bd = 1e300;
    int    bk = 0;
    for (int k = tid; k < KCB; k += 256) {
      double d2 = 0.0;
      for (int d = 0; d < DD; ++d) {
        double df = (double)zg[(size_t)(m0 + row) * DD + d] - (double)cbg[(size_t)k * DD + d];
        d2 = fma(df, df, d2);
      }
      if (d2 < bd) { bd = d2; bk = k; }
    }
    for (int m = 1; m < 64; m <<= 1) {
      double od = __shfl_xor(bd, m, 64);
      int    ok = __shfl_xor(bk, m, 64);
      if (od < bd || (od == bd && ok < bk)) { bd = od; bk = ok; }
    }
    if (lane == 0) { rbd[wave] = bd; rbi[wave] = bk; }
    __syncthreads();
    if (tid == 0) {
      double xd = rbd[0]; int xk = rbi[0];
      for (int w = 1; w < 4; ++w)
        if (rbd[w] < xd || (rbd[w] == xd && rbi[w] < xk)) { xd = rbd[w]; xk = rbi[w]; }
      fidxs[row] = xk;
      carr[row]  = (float)xd;
    }
    __syncthreads();
  }
  __syncthreads();

  if (tid < 32)
    outidx[m0 + tid] = maskb[tid] ? (float)(fidxs[tid] & (KCB - 1)) : -1.0f;

  if (wave == 0) {
    float c = (lane < 32) ? carr[lane] : 0.f;
    for (int m = 1; m < 64; m <<= 1) c += __shfl_xor(c, m, 64);
    if (lane == 0) atomicAdd(wsum, c);
  }

#pragma unroll
  for (int i = 0; i < 8; ++i) {
    int idx = i * 256 + tid;
    int row = idx >> 6;
    int f4  = idx & 63;
    int k   = fidxs[row] & (KCB - 1);
    float4 val = {0.f, 0.f, 0.f, 0.f};
    if (maskb[row]) val = ((const float4*)cbg)[(size_t)k * 64 + f4];
    ((float4*)outq)[(size_t)(m0 + row) * 64 + f4] = val;
  }
}

__global__ void vq_final(const float* __restrict__ wsum,
                         float* __restrict__ outloss) {
  if (threadIdx.x == 0)
    outloss[0] = 0.25f * (wsum[0] / 16777216.0f);   // mean over B*N*D
}

extern "C" void kernel_launch(void* const* d_in, const int* in_sizes, int n_in,
                              void* d_out, int out_size, void* d_ws, size_t ws_size,
                              hipStream_t stream) {
  // Inputs identified by element count. z/codebook FLOAT32, mask probed.
  const void* pz = d_in[0];
  const void* pm = (n_in > 1) ? d_in[1] : d_in[0];
  const void* pc = (n_in > 2) ? d_in[2] : d_in[0];
  for (int i = 0; i < n_in; ++i) {
    if      (in_sizes[i] == BN * DD)  pz = d_in[i];
    else if (in_sizes[i] == BN)       pm = d_in[i];
    else if (in_sizes[i] == KCB * DD) pc = d_in[i];
  }
  const float* zg  = (const float*)pz;
  const int*   mk  = (const int*)pm;
  const float* cbg = (const float*)pc;

  float* outq   = (float*)d_out;
  float* outidx = outq + (size_t)BN * DD;
  float* outls  = outidx + BN;
  float* wsum   = (float*)d_ws;

  // ws layout: [0] wsum | +512 dcnt | +1024 esq (2KB) | +4096 cbt (256KB hi)
  //            | +266240 cbT fp32 transposed (512KB)  => total ~772 KB
  unsigned int* dcnt = (unsigned int*)((char*)d_ws + 512);
  const size_t ESQ_OFF = 1024;
  const size_t CBT_OFF = 4096;
  const size_t CBF_OFF = CBT_OFF + (size_t)KCB * DD * 2;           // 266240
  const size_t WS_NEED = CBF_OFF + (size_t)KCB * DD * 4;           // ~772 KB

  if (ws_size >= WS_NEED) {
    char*  cbt = (char*)d_ws + CBT_OFF;
    float* cbf = (float*)((char*)d_ws + CBF_OFF);
    float* esw = (float*)((char*)d_ws + ESQ_OFF);
    vq_prep<<<128, 256, 0, stream>>>(cbg, cbt, cbf, esw, wsum, dcnt);
    vq_main<<<NBLK, 512, 0, stream>>>(zg, mk, cbg, cbt, cbf, esw,
                                      outq, outidx, outls, wsum, dcnt);
  } else {
    vq_zero_ws<<<1, 1, 0, stream>>>(wsum);
    vq_main_fb<<<2048, 256, 0, stream>>>(zg, mk, cbg, outq, outidx, wsum);
    vq_final<<<1, 64, 0, stream>>>(wsum, outls);
  }
}

// Round 8
// 229.420 us; speedup vs baseline: 3.1062x; 1.0992x over previous
//
#include <hip/hip_runtime.h>

// Problem constants
#define BN    65536    // B*N rows
#define DD    256      // D
#define KCB   512      // codebook entries
#define MT    256      // rows per block (main kernel)
#define NBLK  256      // BN/MT -> exactly 1 block per CU (proven best)
#define NST   8        // codebook stages of 64 codes (hi+lo staging)

typedef __attribute__((ext_vector_type(8))) short bf16x8;
typedef __attribute__((ext_vector_type(4))) float f32x4;

static __device__ __forceinline__ float bf2f(unsigned short u) {
  return __uint_as_float(((unsigned int)u) << 16);
}
static __device__ __forceinline__ unsigned short f2bf(float f) {
  unsigned int u = __float_as_uint(f);
  return (unsigned short)((u + 0x7fffu + ((u >> 16) & 1u)) >> 16);  // RNE
}
static __device__ __forceinline__ void gll16(const void* g, void* l) {
  __builtin_amdgcn_global_load_lds(
      (const __attribute__((address_space(1))) unsigned int*)g,
      (__attribute__((address_space(3))) unsigned int*)l, 16, 0, 0);
}

__global__ void vq_zero_ws(float* ws) { ws[0] = 0.f; }   // fallback path only

// ---- one-shot prep: codebook fp32 -> bf16 hi/lo, 64-code-stage layout with
// XOR bank-swizzle pre-applied in GLOBAL memory (linear global_load_lds dest
// + inverse-swz source + swz read). Stage s (64 codes, 64 KB) at s*65536:
// [32 KB hi][32 KB lo]; code lc (0..63) byte b at (lc*512+b) ^ ((lc&7)<<4).
// Plus TRANSPOSED fp32 copy cbT[d][k] for the coalesced exact rescan,
// fp64-exact e_sq, and wsum/dcnt zeroing.
// Numerics: 3-pass MFMA (zh+zl)*(eh) + zh*el leaves only |z_lo.e_lo| ~3e-4
// -> 0.02 rescan threshold gives ~0.4% flag rate (round-3-verified).
__global__ void vq_prep(const float* __restrict__ cbg,
                        char* __restrict__ cbt,
                        float* __restrict__ cbf,   // (D, K) transposed fp32
                        float* __restrict__ esq,
                        float* __restrict__ wsum,
                        unsigned int* __restrict__ dcnt) {
  if (blockIdx.x == 0 && threadIdx.x == 0) { wsum[0] = 0.f; dcnt[0] = 0u; }
  const int tid = threadIdx.x, lane = tid & 63, wave = tid >> 6;
  const int code = blockIdx.x * 4 + wave;
  float4 v = ((const float4*)cbg)[(size_t)code * 64 + lane];
  ushort4 h, l;
  h.x = f2bf(v.x); l.x = f2bf(v.x - bf2f(h.x));
  h.y = f2bf(v.y); l.y = f2bf(v.y - bf2f(h.y));
  h.z = f2bf(v.z); l.z = f2bf(v.z - bf2f(h.z));
  h.w = f2bf(v.w); l.w = f2bf(v.w - bf2f(h.w));
  const int s  = code >> 6;
  const int lc = code & 63;
  unsigned raw = (unsigned)(lc * 512 + lane * 8);     // 8 bytes per lane
  unsigned off = (unsigned)(s * 65536) + (raw ^ ((unsigned)(lc & 7) << 4));
  *(ushort4*)(cbt + off)         = h;
  *(ushort4*)(cbt + off + 32768) = l;
  // transposed fp32 copy: cbT[d][k] (scattered one-shot stores, ~512 KB)
  cbf[(size_t)(lane * 4 + 0) * KCB + code] = v.x;
  cbf[(size_t)(lane * 4 + 1) * KCB + code] = v.y;
  cbf[(size_t)(lane * 4 + 2) * KCB + code] = v.z;
  cbf[(size_t)(lane * 4 + 3) * KCB + code] = v.w;
  double sq = (double)v.x * v.x + (double)v.y * v.y +
              (double)v.z * v.z + (double)v.w * v.w;
#pragma unroll
  for (int m = 1; m < 64; m <<= 1) sq += __shfl_xor(sq, m, 64);
  if (lane == 0) esq[code] = (float)sq;
}

// issue stage S (64 KB) into LDS buffer BSEL: 8 x global_load_lds(16B) per
// thread (512 threads); dest = wave-uniform base + lane*16 (HW requirement).
#define ISSUE(S, BSEL)                                                       \
  do {                                                                       \
    const char* _src = cbt + (size_t)(S) * 65536 + (size_t)tid * 16;         \
    char* _dst = &bufB[BSEL][tid * 16];                                      \
    _Pragma("unroll")                                                        \
    for (int _r = 0; _r < 8; ++_r)                                           \
      gll16(_src + _r * 8192, _dst + _r * 8192);                             \
  } while (0)

#define VMCNT8 asm volatile("s_waitcnt vmcnt(8)" ::: "memory")
#define VMCNT0 asm volatile("s_waitcnt vmcnt(0)" ::: "memory")
#define SBAR   asm volatile("s_barrier" ::: "memory")

__global__ __launch_bounds__(512, 2) void vq_main(
    const float* __restrict__ zg,    // (BN, D) float32
    const int* __restrict__ maskg,   // (BN) mask, dtype probed
    const float* __restrict__ cbg,   // (K, D) float32 (gather)
    const char* __restrict__ cbt,    // stage-major swizzled bf16 hi/lo
    const float* __restrict__ cbf,   // (D, K) transposed fp32 (rescan)
    const float* __restrict__ esqg,  // (K) fp64-acc esq
    float* __restrict__ outq,        // (BN, D) float32
    float* __restrict__ outidx,      // (BN) float32 (-1 pad)
    float* __restrict__ outls,       // loss scalar
    float* __restrict__ wsum,        // d_ws fp32 accumulator
    unsigned int* __restrict__ dcnt) // done counter (loss fusion)
{
  // ~141 KB LDS; 8 waves (2/SIMD), 1 block/CU. A (z) lives in registers.
  __shared__ __align__(16) char bufB[2][65536];   // B dbuf: 32K hi | 32K lo
  __shared__ float esqs[KCB];
  __shared__ float zsqs[MT];
  __shared__ float v1s[MT], v2s[MT];
  __shared__ int   i1s[MT];
  __shared__ float carr[MT];
  __shared__ int   fidxs[MT], maskb[MT], flaglist[MT];
  __shared__ int   flagcnt, mflags;

  const int tid   = threadIdx.x;
  const int lane  = tid & 63;
  const int wave  = tid >> 6;
  const int q     = lane >> 4;
  const int l15   = lane & 15;
  const int m0    = blockIdx.x * MT;
  const int rbase = wave * 32;           // wave's 32 local rows

  if (tid == 0) { flagcnt = 0; mflags = 0; }

  // ---- mask dtype probe on first 512 bytes (in-bounds under every layout) --
  int wm = 0;
  if (tid < 128) {
    unsigned int W = ((const unsigned int*)maskg)[tid];
    if (W > 1u) wm |= 1;
    if (W != 0u && W != 0x3f800000u) wm |= 2;
    unsigned int lo = W & 0xffffu, hi = W >> 16;
    if ((lo != 0u && lo != 0x3f80u) || (hi != 0u && hi != 0x3f80u)) wm |= 4;
  }
  if (wm) atomicOr(&mflags, wm);

  // ---- esq into LDS (512 threads, 512 entries) ----
  esqs[tid] = esqg[tid];

  // ---- prefetch stage 0 before the z prologue (overlaps with z loads) ----
  ISSUE(0, 0);

  // ---- z -> A registers: 32 rows/wave, bf16 hi/lo; fused exact-fp32 z_sq --
  bf16x8 ah[2][8], al[2][8];
  float zacc0 = 0.f, zacc1 = 0.f;
#pragma unroll
  for (int i = 0; i < 2; ++i) {
    const int grow = m0 + rbase + i * 16 + l15;
#pragma unroll
    for (int kk = 0; kk < 8; ++kk) {
      const float* src = &zg[(size_t)grow * DD + kk * 32 + q * 8];
      float4 v0 = *(const float4*)src;
      float4 v1 = *(const float4*)(src + 4);
      float f[8] = {v0.x, v0.y, v0.z, v0.w, v1.x, v1.y, v1.z, v1.w};
      union { ushort us[8]; bf16x8 v; } H, L;
#pragma unroll
      for (int e = 0; e < 8; ++e) {
        unsigned short hh = f2bf(f[e]);
        H.us[e] = hh;
        L.us[e] = f2bf(f[e] - bf2f(hh));
      }
      ah[i][kk] = H.v;
      al[i][kk] = L.v;
      float s = 0.f;
#pragma unroll
      for (int e = 0; e < 8; ++e) s = fmaf(f[e], f[e], s);
      if (i == 0) zacc0 += s; else zacc1 += s;
    }
  }
  {
    float s0 = zacc0, s1 = zacc1;
    s0 += __shfl_xor(s0, 16, 64); s0 += __shfl_xor(s0, 32, 64);
    s1 += __shfl_xor(s1, 16, 64); s1 += __shfl_xor(s1, 32, 64);
    if (q == 0) {
      zsqs[rbase + l15]      = s0;
      zsqs[rbase + 16 + l15] = s1;
    }
  }
  __syncthreads();   // drains z loads + stage 0; esqs/zsqs/mflags visible
  const int mmode = mflags;

  // ---- per-thread running top-2 over all 512 codes ----
  float t1[2][4], t2[2][4];
  int   ti[2][4];
#pragma unroll
  for (int i = 0; i < 2; ++i)
#pragma unroll
    for (int rr = 0; rr < 4; ++rr) { t1[i][rr] = 3.0e38f; t2[i][rr] = 3.0e38f; ti[i][rr] = 0; }

  // ---- 8-stage pipeline over codes; all waves consume the same B tile ----
  // 3-pass MFMA per code-tile: (ah+al)xbh + ahxbl (z_lo.e_lo dropped, ~3e-4,
  // covered by the 0.02 rescan threshold — round-3-verified numerics).
#pragma unroll 1
  for (int s = 0; s < NST; ++s) {
    if (s < NST - 1) { ISSUE(s + 1, (s + 1) & 1); VMCNT8; }
    else             { VMCNT0; }
    SBAR;
    const char* bb = &bufB[s & 1][0];
#pragma unroll
    for (int tt = 0; tt < 4; ++tt) {
      const int lc = tt * 16 + l15;
      const unsigned sw = ((unsigned)(l15 & 7)) << 4;
      f32x4 a0 = (f32x4){0.f, 0.f, 0.f, 0.f};
      f32x4 a1 = (f32x4){0.f, 0.f, 0.f, 0.f};
#pragma unroll
      for (int kk = 0; kk < 8; ++kk) {
        const unsigned off = ((unsigned)(lc * 512 + kk * 64 + q * 16)) ^ sw;
        bf16x8 bh = *(const bf16x8*)(bb + off);
        bf16x8 bl = *(const bf16x8*)(bb + 32768 + off);
        a0 = __builtin_amdgcn_mfma_f32_16x16x32_bf16(ah[0][kk], bh, a0, 0, 0, 0);
        a1 = __builtin_amdgcn_mfma_f32_16x16x32_bf16(ah[1][kk], bh, a1, 0, 0, 0);
        a0 = __builtin_amdgcn_mfma_f32_16x16x32_bf16(al[0][kk], bh, a0, 0, 0, 0);
        a1 = __builtin_amdgcn_mfma_f32_16x16x32_bf16(al[1][kk], bh, a1, 0, 0, 0);
        a0 = __builtin_amdgcn_mfma_f32_16x16x32_bf16(ah[0][kk], bl, a0, 0, 0, 0);
        a1 = __builtin_amdgcn_mfma_f32_16x16x32_bf16(ah[1][kk], bl, a1, 0, 0, 0);
      }
      // fold: half-score v = esq/2 - dot; strict < keeps lowest idx
      const int code = s * 64 + lc;
      const float eh = 0.5f * esqs[code];
#pragma unroll
      for (int rr = 0; rr < 4; ++rr) {
        {
          float v = eh - a0[rr];
          bool  tk = v < t1[0][rr];
          float m2 = fminf(t2[0][rr], v);
          t2[0][rr] = tk ? t1[0][rr] : m2;
          ti[0][rr] = tk ? code : ti[0][rr];
          t1[0][rr] = tk ? v : t1[0][rr];
        }
        {
          float v = eh - a1[rr];
          bool  tk = v < t1[1][rr];
          float m2 = fminf(t2[1][rr], v);
          t2[1][rr] = tk ? t1[1][rr] : m2;
          ti[1][rr] = tk ? code : ti[1][rr];
          t1[1][rr] = tk ? v : t1[1][rr];
        }
      }
    }
    SBAR;            // all waves done reading this buffer -> safe to refill
  }

  // ---- reduce across the 16 lanes (l15) sharing the same rows; store ------
#pragma unroll
  for (int i = 0; i < 2; ++i)
#pragma unroll
    for (int rr = 0; rr < 4; ++rr) {
      float a1 = t1[i][rr], a2 = t2[i][rr];
      int   ai = ti[i][rr];
#pragma unroll
      for (int m = 1; m < 16; m <<= 1) {
        float o1 = __shfl_xor(a1, m, 64);
        float o2 = __shfl_xor(a2, m, 64);
        int   oi = __shfl_xor(ai, m, 64);
        bool  tk = (o1 < a1) || (o1 == a1 && oi < ai);
        float losr = tk ? a1 : o1;
        a2 = fminf(fminf(a2, o2), losr);
        a1 = tk ? o1 : a1;
        ai = tk ? oi : ai;
      }
      if (l15 == 0) {
        int row = rbase + i * 16 + q * 4 + rr;   // unique owner per row
        v1s[row] = a1; v2s[row] = a2; i1s[row] = ai;
      }
    }
  __syncthreads();

  // ---- per-row finalize (rows disjoint across waves) ----------------------
  if (tid < MT) {
    float bv1 = v1s[tid], bv2 = v2s[tid];
    int   bi = i1s[tid];
    fidxs[tid] = bi;
    carr[tid]  = zsqs[tid] + 2.f * bv1;   // min ||z-e||^2
    if (2.f * (bv2 - bv1) < 0.02f) {      // near-tie -> exact fp64 rescan
      int pos = atomicAdd(&flagcnt, 1);   // (3-pass err ~3e-4 << 0.02)
      flaglist[pos] = tid;
    }
    int mk;
    if (!(mmode & 1))      mk = maskg[m0 + tid] ? 1 : 0;                          // int32
    else if (!(mmode & 2)) mk = ((const float*)maskg)[m0 + tid] != 0.f ? 1 : 0;   // fp32
    else if (!(mmode & 4)) mk = ((const unsigned short*)maskg)[m0 + tid] ? 1 : 0; // bf16
    else                   mk = ((const unsigned char*)maskg)[m0 + tid] ? 1 : 0;  // bool
    maskb[tid] = mk;
  }
  __syncthreads();

  // ---- exact fp64 rescan: WAVE-PARALLEL (8 rows/batch, no inner barriers),
  //      COALESCED via transposed codebook: lane handles codes lane+c*64,
  //      reads cbf[d*512 + lane + c*64] -> lane-stride 4B (4 lines/wave).
  //      Rare at 0.02 threshold (~0.4% of rows).
  int nflag = flagcnt;
  for (int f0 = 0; f0 < nflag; f0 += 8) {
    const int fi = f0 + wave;
    if (fi < nflag) {
      const int row = flaglist[fi];
      const float* zr = &zg[(size_t)(m0 + row) * DD];
      double d2[8] = {0., 0., 0., 0., 0., 0., 0., 0.};
      for (int d = 0; d < DD; ++d) {
        double zd = (double)zr[d];
        const float* cr = &cbf[(size_t)d * KCB + lane];
#pragma unroll
        for (int c = 0; c < 8; ++c) {
          double df = zd - (double)cr[c * 64];
          d2[c] = fma(df, df, d2[c]);
        }
      }
      double bd = d2[0];
      int    bk = lane;
#pragma unroll
      for (int c = 1; c < 8; ++c)           // ascending code order: strict <
        if (d2[c] < bd) { bd = d2[c]; bk = lane + c * 64; }
      for (int m = 1; m < 64; m <<= 1) {
        double od = __shfl_xor(bd, m, 64);
        int    ok = __shfl_xor(bk, m, 64);
        if (od < bd || (od == bd && ok < bk)) { bd = od; bk = ok; }
      }
      if (lane == 0) { fidxs[row] = bk; carr[row] = (float)bd; }
    }
  }
  __syncthreads();

  // ---- index output: float32 values, -1.0 pad ----
  if (tid < MT)
    outidx[m0 + tid] = maskb[tid] ? (float)(fidxs[tid] & (KCB - 1)) : -1.0f;

  // ---- commit partial -> device atomicAdd (waves 0-3, 64 rows each) -------
  if (tid < MT) {
    float c = carr[tid];
    for (int m = 1; m < 64; m <<= 1) c += __shfl_xor(c, m, 64);
    if (lane == 0) atomicAdd(wsum, c);
  }

  // ---- quantized output: float32 codebook gather, masked ----
#pragma unroll
  for (int it = 0; it < 32; ++it) {
    int idx = it * 512 + tid;             // float4 index: 256 rows x 64
    int row = idx >> 6;
    int f4  = idx & 63;
    int k   = fidxs[row] & (KCB - 1);
    float4 val = {0.f, 0.f, 0.f, 0.f};
    if (maskb[row]) val = ((const float4*)cbg)[(size_t)k * 64 + f4];
    ((float4*)outq)[(size_t)(m0 + row) * 64 + f4] = val;
  }

  // ---- fused loss finalize: last block computes outls ----
  __syncthreads();   // block's wsum atomics drained before counting
  if (tid == 0) {
    __threadfence();
    unsigned prev = atomicAdd(dcnt, 1u);
    if (prev == (unsigned)(NBLK - 1)) {
      float s = atomicAdd(wsum, 0.f);     // device-coherent read
      outls[0] = 0.25f * (s / 16777216.0f);   // mean over B*N*D
    }
  }
}

// ================= fallback (no workspace): in-register B conversion =======
__global__ __launch_bounds__(256, 3) void vq_main_fb(
    const float* __restrict__ zg, const int* __restrict__ maskg,
    const float* __restrict__ cbg, float* __restrict__ outq,
    float* __restrict__ outidx, float* __restrict__ wsum)
{
  __shared__ unsigned short zs_hi[8 * 32 * 32];
  __shared__ unsigned short zs_lo[8 * 32 * 32];
  __shared__ float esqs[KCB];
  __shared__ float zsq[32];
  __shared__ float wv1[4][32], wv2[4][32];
  __shared__ int   wi1[4][32];
  __shared__ float carr[32];
  __shared__ int   fidxs[32], maskb[32], flaglist[32];
  __shared__ int   flagcnt, mflags;
  __shared__ double rbd[4];
  __shared__ int    rbi[4];

  const int tid  = threadIdx.x;
  const int lane = tid & 63;
  const int wave = tid >> 6;
  const int q    = lane >> 4;
  const int l15  = lane & 15;
  const int m0   = blockIdx.x * 32;

  if (tid == 0) { flagcnt = 0; mflags = 0; }
  int wm = 0;
  if (tid < 128) {
    unsigned int W = ((const unsigned int*)maskg)[tid];
    if (W > 1u) wm |= 1;
    if (W != 0u && W != 0x3f800000u) wm |= 2;
    unsigned int lo = W & 0xffffu, hi = W >> 16;
    if ((lo != 0u && lo != 0x3f80u) || (hi != 0u && hi != 0x3f80u)) wm |= 4;
  }
  if (wm) atomicOr(&mflags, wm);

#pragma unroll
  for (int i = 0; i < 8; ++i) {
    int idx = i * 256 + tid;
    int row = idx >> 6;
    int f4  = idx & 63;
    float4 v = ((const float4*)zg)[(size_t)(m0 + row) * 64 + f4];
    int ch  = f4 >> 3;
    int col = (f4 & 7) * 4;
    int base = (ch * 32 + row) * 32 + col;
    ushort4 h, l;
    h.x = f2bf(v.x); l.x = f2bf(v.x - bf2f(h.x));
    h.y = f2bf(v.y); l.y = f2bf(v.y - bf2f(h.y));
    h.z = f2bf(v.z); l.z = f2bf(v.z - bf2f(h.z));
    h.w = f2bf(v.w); l.w = f2bf(v.w - bf2f(h.w));
    *(ushort4*)&zs_hi[base] = h;
    *(ushort4*)&zs_lo[base] = l;
    float s = v.x * v.x + v.y * v.y + v.z * v.z + v.w * v.w;
#pragma unroll
    for (int m = 1; m < 64; m <<= 1) s += __shfl_xor(s, m, 64);
    if (lane == 0) zsq[row] = s;
  }
  for (int c = tid; c < KCB; c += 256) {
    float s = 0.f;
    for (int f4i = 0; f4i < 64; ++f4i) {
      float4 v = ((const float4*)cbg)[(size_t)c * 64 + f4i];
      s = fmaf(v.x, v.x, s); s = fmaf(v.y, v.y, s);
      s = fmaf(v.z, v.z, s); s = fmaf(v.w, v.w, s);
    }
    esqs[c] = s;
  }
  __syncthreads();
  const int mmode = mflags;

  f32x4 acc[8][2];
#pragma unroll
  for (int t = 0; t < 8; ++t) {
    acc[t][0] = (f32x4){0.f, 0.f, 0.f, 0.f};
    acc[t][1] = (f32x4){0.f, 0.f, 0.f, 0.f};
  }
  const unsigned short* Abh = &zs_hi[l15 * 32 + q * 8];
  const unsigned short* Abl = &zs_lo[l15 * 32 + q * 8];

  for (int kk = 0; kk < 8; ++kk) {
    bf16x8 ah0 = *(const bf16x8*)(Abh + kk * 1024);
    bf16x8 ah1 = *(const bf16x8*)(Abh + kk * 1024 + 512);
    bf16x8 al0 = *(const bf16x8*)(Abl + kk * 1024);
    bf16x8 al1 = *(const bf16x8*)(Abl + kk * 1024 + 512);
#pragma unroll
    for (int t = 0; t < 8; ++t) {
      const int code_row = (wave * 8 + t) * 16 + l15;
      const float* src = &cbg[(size_t)code_row * 256 + kk * 32 + q * 8];
      float4 v0 = *(const float4*)src;
      float4 v1 = *(const float4*)(src + 4);
      float f[8] = {v0.x, v0.y, v0.z, v0.w, v1.x, v1.y, v1.z, v1.w};
      union { ushort us[8]; bf16x8 v; } H, L;
#pragma unroll
      for (int e = 0; e < 8; ++e) {
        unsigned short hh = f2bf(f[e]);
        H.us[e] = hh;
        L.us[e] = f2bf(f[e] - bf2f(hh));
      }
      bf16x8 bh = H.v, bl = L.v;
      acc[t][0] = __builtin_amdgcn_mfma_f32_16x16x32_bf16(ah0, bh, acc[t][0], 0, 0, 0);
      acc[t][1] = __builtin_amdgcn_mfma_f32_16x16x32_bf16(ah1, bh, acc[t][1], 0, 0, 0);
      acc[t][0] = __builtin_amdgcn_mfma_f32_16x16x32_bf16(al0, bh, acc[t][0], 0, 0, 0);
      acc[t][1] = __builtin_amdgcn_mfma_f32_16x16x32_bf16(al1, bh, acc[t][1], 0, 0, 0);
      acc[t][0] = __builtin_amdgcn_mfma_f32_16x16x32_bf16(ah0, bl, acc[t][0], 0, 0, 0);
      acc[t][1] = __builtin_amdgcn_mfma_f32_16x16x32_bf16(ah1, bl, acc[t][1], 0, 0, 0);
    }
  }

  float t1[2][4], t2[2][4];
  int   ti[2][4];
#pragma unroll
  for (int i = 0; i < 2; ++i)
#pragma unroll
    for (int rr = 0; rr < 4; ++rr) { t1[i][rr] = 3.0e38f; t2[i][rr] = 3.0e38f; ti[i][rr] = 0; }
#pragma unroll
  for (int t = 0; t < 8; ++t) {
    const int code = (wave * 8 + t) * 16 + l15;
    const float eh = 0.5f * esqs[code];
#pragma unroll
    for (int i = 0; i < 2; ++i)
#pragma unroll
      for (int rr = 0; rr < 4; ++rr) {
        float v = eh - acc[t][i][rr];
        bool  tk = v < t1[i][rr];
        float m2 = fminf(t2[i][rr], v);
        t2[i][rr] = tk ? t1[i][rr] : m2;
        ti[i][rr] = tk ? code : ti[i][rr];
        t1[i][rr] = tk ? v : t1[i][rr];
      }
  }
#pragma unroll
  for (int i = 0; i < 2; ++i)
#pragma unroll
    for (int rr = 0; rr < 4; ++rr) {
      float a1 = t1[i][rr], a2 = t2[i][rr];
      int   ai = ti[i][rr];
#pragma unroll
      for (int m = 1; m < 16; m <<= 1) {
        float o1 = __shfl_xor(a1, m, 64);
        float o2 = __shfl_xor(a2, m, 64);
        int   oi = __shfl_xor(ai, m, 64);
        bool  tk = (o1 < a1) || (o1 == a1 && oi < ai);
        float losr = tk ? a1 : o1;
        a2 = fminf(fminf(a2, o2), losr);
        a1 = tk ? o1 : a1;
        ai = tk ? oi : ai;
      }
      if (l15 == 0) {
        int row = i * 16 + q * 4 + rr;
        wv1[wave][row] = a1; wv2[wave][row] = a2; wi1[wave][row] = ai;
      }
    }
  __syncthreads();

  if (tid < 32) {
    float bv1 = 3.0e38f, bv2 = 3.0e38f;
    int   bi = 0x7fffffff;
#pragma unroll
    for (int w = 0; w < 4; ++w) {
      float a1 = wv1[w][tid], a2 = wv2[w][tid];
      int   ai = wi1[w][tid];
      bool  tk = (a1 < bv1) || (a1 == bv1 && ai < bi);
      if (tk) { bv2 = fminf(bv1, a2); bv1 = a1; bi = ai; }
      else    { bv2 = fminf(bv2, a1); }
    }
    fidxs[tid] = bi;
    carr[tid]  = zsq[tid] + 2.f * bv1;
    if (2.f * (bv2 - bv1) < 0.02f) {
      int pos = atomicAdd(&flagcnt, 1);
      flaglist[pos] = tid;
    }
    int mk;
    if (!(mmode & 1))      mk = maskg[m0 + tid] ? 1 : 0;
    else if (!(mmode & 2)) mk = ((const float*)maskg)[m0 + tid] != 0.f ? 1 : 0;
    else if (!(mmode & 4)) mk = ((const unsigned short*)maskg)[m0 + tid] ? 1 : 0;
    else                   mk = ((const unsigned char*)maskg)[m0 + tid] ? 1 : 0;
    maskb[tid] = mk;
  }
  __syncthreads();

  int nflag = flagcnt;
  for (int f = 0; f < nflag; ++f) {
    int row = flaglist[f];
    double bd = 1e300;
    int    bk = 0;
    for (int k = tid; k < KCB; k += 256) {
      double d2 = 0.0;
      for (int d = 0; d < DD; ++d) {
        double df = (double)zg[(size_t)(m0 + row) * DD + d] - (double)cbg[(size_t)k * DD + d];
        d2 = fma(df, df, d2);
      }
      if (d2 < bd) { bd = d2; bk = k; }
    }
    for (int m = 1; m < 64; m <<= 1) {
      double od = __shfl_xor(bd, m, 64);
      int    ok = __shfl_xor(bk, m, 64);
      if (od < bd || (od == bd && ok < bk)) { bd = od; bk = ok; }
    }
    if (lane == 0) { rbd[wave] = bd; rbi[wave] = bk; }
    __syncthreads();
    if (tid == 0) {
      double xd = rbd[0]; int xk = rbi[0];
      for (int w = 1; w < 4; ++w)
        if (rbd[w] < xd || (rbd[w] == xd && rbi[w] < xk)) { xd = rbd[w]; xk = rbi[w]; }
      fidxs[row] = xk;
      carr[row]  = (float)xd;
    }
    __syncthreads();
  }
  __syncthreads();

  if (tid < 32)
    outidx[m0 + tid] = maskb[tid] ? (float)(fidxs[tid] & (KCB - 1)) : -1.0f;

  if (wave == 0) {
    float c = (lane < 32) ? carr[lane] : 0.f;
    for (int m = 1; m < 64; m <<= 1) c += __shfl_xor(c, m, 64);
    if (lane == 0) atomicAdd(wsum, c);
  }

#pragma unroll
  for (int i = 0; i < 8; ++i) {
    int idx = i * 256 + tid;
    int row = idx >> 6;
    int f4  = idx & 63;
    int k   = fidxs[row] & (KCB - 1);
    float4 val = {0.f, 0.f, 0.f, 0.f};
    if (maskb[row]) val = ((const float4*)cbg)[(size_t)k * 64 + f4];
    ((float4*)outq)[(size_t)(m0 + row) * 64 + f4] = val;
  }
}

__global__ void vq_final(const float* __restrict__ wsum,
                         float* __restrict__ outloss) {
  if (threadIdx.x == 0)
    outloss[0] = 0.25f * (wsum[0] / 16777216.0f);   // mean over B*N*D
}

extern "C" void kernel_launch(void* const* d_in, const int* in_sizes, int n_in,
                              void* d_out, int out_size, void* d_ws, size_t ws_size,
                              hipStream_t stream) {
  // Inputs identified by element count. z/codebook FLOAT32, mask probed.
  const void* pz = d_in[0];
  const void* pm = (n_in > 1) ? d_in[1] : d_in[0];
  const void* pc = (n_in > 2) ? d_in[2] : d_in[0];
  for (int i = 0; i < n_in; ++i) {
    if      (in_sizes[i] == BN * DD)  pz = d_in[i];
    else if (in_sizes[i] == BN)       pm = d_in[i];
    else if (in_sizes[i] == KCB * DD) pc = d_in[i];
  }
  const float* zg  = (const float*)pz;
  const int*   mk  = (const int*)pm;
  const float* cbg = (const float*)pc;

  float* outq   = (float*)d_out;
  float* outidx = outq + (size_t)BN * DD;
  float* outls  = outidx + BN;
  float* wsum   = (float*)d_ws;

  // ws layout: [0] wsum | +512 dcnt | +1024 esq (2KB) | +4096 cbt (512KB)
  //            | +528384 cbT fp32 transposed (512KB)  => total ~1.03 MB
  unsigned int* dcnt = (unsigned int*)((char*)d_ws + 512);
  const size_t ESQ_OFF = 1024;
  const size_t CBT_OFF = 4096;
  const size_t CBF_OFF = CBT_OFF + (size_t)KCB * DD * 2 * 2;      // 528384
  const size_t WS_NEED = CBF_OFF + (size_t)KCB * DD * 4;          // ~1.03 MB

  if (ws_size >= WS_NEED) {
    char*  cbt = (char*)d_ws + CBT_OFF;
    float* cbf = (float*)((char*)d_ws + CBF_OFF);
    float* esw = (float*)((char*)d_ws + ESQ_OFF);
    vq_prep<<<128, 256, 0, stream>>>(cbg, cbt, cbf, esw, wsum, dcnt);
    vq_main<<<NBLK, 512, 0, stream>>>(zg, mk, cbg, cbt, cbf, esw,
                                      outq, outidx, outls, wsum, dcnt);
  } else {
    vq_zero_ws<<<1, 1, 0, stream>>>(wsum);
    vq_main_fb<<<2048, 256, 0, stream>>>(zg, mk, cbg, outq, outidx, wsum);
    vq_final<<<1, 64, 0, stream>>>(wsum, outls);
  }
}

// Round 9
// 220.256 us; speedup vs baseline: 3.2355x; 1.0416x over previous
//
#include <hip/hip_runtime.h>

// Problem constants
#define BN    65536    // B*N rows
#define DD    256      // D
#define KCB   512      // codebook entries
#define MT    256      // rows per block (main kernel)
#define NBLK  256      // BN/MT -> exactly 1 block per CU (proven best)
#define NST   16       // codebook stages of 32 codes (hi+lo staging)

typedef __attribute__((ext_vector_type(8))) short bf16x8;
typedef __attribute__((ext_vector_type(4))) float f32x4;

static __device__ __forceinline__ float bf2f(unsigned short u) {
  return __uint_as_float(((unsigned int)u) << 16);
}
static __device__ __forceinline__ unsigned short f2bf(float f) {
  unsigned int u = __float_as_uint(f);
  return (unsigned short)((u + 0x7fffu + ((u >> 16) & 1u)) >> 16);  // RNE
}
static __device__ __forceinline__ void gll16(const void* g, void* l) {
  __builtin_amdgcn_global_load_lds(
      (const __attribute__((address_space(1))) unsigned int*)g,
      (__attribute__((address_space(3))) unsigned int*)l, 16, 0, 0);
}

__global__ void vq_zero_ws(float* ws) { ws[0] = 0.f; }   // fallback path only

// ---- one-shot prep: codebook fp32 -> bf16 hi/lo, 32-code-stage layout with
// XOR bank-swizzle pre-applied in GLOBAL memory (linear global_load_lds dest
// + inverse-swz source + swz read). Stage s (32 codes, 32 KB) at s*32768:
// [16 KB hi][16 KB lo]; code lc (0..31) byte b at (lc*512+b) ^ ((lc&7)<<4).
// Plus TRANSPOSED fp32 copy cbT[d][k] for the coalesced exact rescan,
// fp64-exact e_sq, and wsum zeroing.
// Numerics: 3-pass MFMA (zh+zl)*eh + zh*el leaves only |z_lo.e_lo| ~3e-4
// -> 0.02 rescan threshold gives ~0.4% flag rate (round-3-verified).
__global__ void vq_prep(const float* __restrict__ cbg,
                        char* __restrict__ cbt,
                        float* __restrict__ cbf,   // (D, K) transposed fp32
                        float* __restrict__ esq,
                        float* __restrict__ wsum) {
  if (blockIdx.x == 0 && threadIdx.x == 0) wsum[0] = 0.f;
  const int tid = threadIdx.x, lane = tid & 63, wave = tid >> 6;
  const int code = blockIdx.x * 4 + wave;
  float4 v = ((const float4*)cbg)[(size_t)code * 64 + lane];
  ushort4 h, l;
  h.x = f2bf(v.x); l.x = f2bf(v.x - bf2f(h.x));
  h.y = f2bf(v.y); l.y = f2bf(v.y - bf2f(h.y));
  h.z = f2bf(v.z); l.z = f2bf(v.z - bf2f(h.z));
  h.w = f2bf(v.w); l.w = f2bf(v.w - bf2f(h.w));
  const int s  = code >> 5;
  const int lc = code & 31;
  unsigned raw = (unsigned)(lc * 512 + lane * 8);     // 8 bytes per lane
  unsigned off = (unsigned)(s * 32768) + (raw ^ ((unsigned)(lc & 7) << 4));
  *(ushort4*)(cbt + off)         = h;
  *(ushort4*)(cbt + off + 16384) = l;
  // transposed fp32 copy: cbT[d][k] (scattered one-shot stores, ~512 KB)
  cbf[(size_t)(lane * 4 + 0) * KCB + code] = v.x;
  cbf[(size_t)(lane * 4 + 1) * KCB + code] = v.y;
  cbf[(size_t)(lane * 4 + 2) * KCB + code] = v.z;
  cbf[(size_t)(lane * 4 + 3) * KCB + code] = v.w;
  double sq = (double)v.x * v.x + (double)v.y * v.y +
              (double)v.z * v.z + (double)v.w * v.w;
#pragma unroll
  for (int m = 1; m < 64; m <<= 1) sq += __shfl_xor(sq, m, 64);
  if (lane == 0) esq[code] = (float)sq;
}

// issue stage S (32 KB) into LDS ring buffer BSEL: 4 x global_load_lds(16B)
// per thread (512 threads); dest = wave-uniform base + lane*16 (HW req).
#define ISSUE(S, BSEL)                                                       \
  do {                                                                       \
    const char* _src = cbt + (size_t)(S) * 32768 + (size_t)tid * 16;         \
    char* _dst = &bufB[BSEL][tid * 16];                                      \
    _Pragma("unroll")                                                        \
    for (int _r = 0; _r < 4; ++_r)                                           \
      gll16(_src + _r * 8192, _dst + _r * 8192);                             \
  } while (0)

#define VMCNT8 asm volatile("s_waitcnt vmcnt(8)" ::: "memory")
#define VMCNT4 asm volatile("s_waitcnt vmcnt(4)" ::: "memory")
#define VMCNT0 asm volatile("s_waitcnt vmcnt(0)" ::: "memory")
#define SBAR   asm volatile("s_barrier" ::: "memory")

__global__ __launch_bounds__(512, 2) void vq_main(
    const float* __restrict__ zg,    // (BN, D) float32
    const int* __restrict__ maskg,   // (BN) mask, dtype probed
    const float* __restrict__ cbg,   // (K, D) float32 (gather)
    const char* __restrict__ cbt,    // stage-major swizzled bf16 hi/lo
    const float* __restrict__ cbf,   // (D, K) transposed fp32 (rescan)
    const float* __restrict__ esqg,  // (K) fp64-acc esq
    float* __restrict__ outq,        // (BN, D) float32
    float* __restrict__ outidx,      // (BN) float32 (-1 pad)
    float* __restrict__ wsum)        // d_ws fp32 accumulator
{
  // ~108 KB LDS; 8 waves (2/SIMD), 1 block/CU. A (z) lives in registers.
  // 3-buffer ring -> 2-deep prefetch: each 32 KB DMA gets 2 stages of
  // compute to land (round-3's 1-deep left the DMA marginally exposed).
  __shared__ __align__(16) char bufB[3][32768];   // ring: 16K hi | 16K lo
  __shared__ float esqs[KCB];
  __shared__ float zsqs[MT];
  __shared__ float v1s[MT], v2s[MT];
  __shared__ int   i1s[MT];
  __shared__ float carr[MT];
  __shared__ int   fidxs[MT], maskb[MT], flaglist[MT];
  __shared__ int   flagcnt, mflags;

  const int tid   = threadIdx.x;
  const int lane  = tid & 63;
  const int wave  = tid >> 6;
  const int q     = lane >> 4;
  const int l15   = lane & 15;
  const int m0    = blockIdx.x * MT;
  const int rbase = wave * 32;           // wave's 32 local rows

  if (tid == 0) { flagcnt = 0; mflags = 0; }

  // ---- mask dtype probe on first 512 bytes (in-bounds under every layout) --
  int wm = 0;
  if (tid < 128) {
    unsigned int W = ((const unsigned int*)maskg)[tid];
    if (W > 1u) wm |= 1;
    if (W != 0u && W != 0x3f800000u) wm |= 2;
    unsigned int lo = W & 0xffffu, hi = W >> 16;
    if ((lo != 0u && lo != 0x3f80u) || (hi != 0u && hi != 0x3f80u)) wm |= 4;
  }
  if (wm) atomicOr(&mflags, wm);

  // ---- esq into LDS (512 threads, 512 entries) ----
  esqs[tid] = esqg[tid];

  // ---- prefetch stages 0,1 before the z prologue (overlap with z loads) ---
  ISSUE(0, 0);
  ISSUE(1, 1);

  // ---- z -> A registers: 32 rows/wave, bf16 hi/lo; fused exact-fp32 z_sq --
  bf16x8 ah[2][8], al[2][8];
  float zacc0 = 0.f, zacc1 = 0.f;
#pragma unroll
  for (int i = 0; i < 2; ++i) {
    const int grow = m0 + rbase + i * 16 + l15;
#pragma unroll
    for (int kk = 0; kk < 8; ++kk) {
      const float* src = &zg[(size_t)grow * DD + kk * 32 + q * 8];
      float4 v0 = *(const float4*)src;
      float4 v1 = *(const float4*)(src + 4);
      float f[8] = {v0.x, v0.y, v0.z, v0.w, v1.x, v1.y, v1.z, v1.w};
      union { ushort us[8]; bf16x8 v; } H, L;
#pragma unroll
      for (int e = 0; e < 8; ++e) {
        unsigned short hh = f2bf(f[e]);
        H.us[e] = hh;
        L.us[e] = f2bf(f[e] - bf2f(hh));
      }
      ah[i][kk] = H.v;
      al[i][kk] = L.v;
      float s = 0.f;
#pragma unroll
      for (int e = 0; e < 8; ++e) s = fmaf(f[e], f[e], s);
      if (i == 0) zacc0 += s; else zacc1 += s;
    }
  }
  {
    float s0 = zacc0, s1 = zacc1;
    s0 += __shfl_xor(s0, 16, 64); s0 += __shfl_xor(s0, 32, 64);
    s1 += __shfl_xor(s1, 16, 64); s1 += __shfl_xor(s1, 32, 64);
    if (q == 0) {
      zsqs[rbase + l15]      = s0;
      zsqs[rbase + 16 + l15] = s1;
    }
  }
  __syncthreads();   // drains z loads + stages 0,1; esqs/zsqs/mflags visible
  const int mmode = mflags;

  // ---- per-thread running top-2 over all 512 codes ----
  float t1[2][4], t2[2][4];
  int   ti[2][4];
#pragma unroll
  for (int i = 0; i < 2; ++i)
#pragma unroll
    for (int rr = 0; rr < 4; ++rr) { t1[i][rr] = 3.0e38f; t2[i][rr] = 3.0e38f; ti[i][rr] = 0; }

  // ---- 16-stage pipeline, 2-deep prefetch; all waves share the B tile ----
  // 3-pass MFMA per code-tile: (ah+al)xbh + ahxbl (z_lo.e_lo dropped ~3e-4,
  // covered by the 0.02 rescan threshold — round-3-verified numerics).
#pragma unroll 1
  for (int s = 0; s < NST; ++s) {
    if (s < NST - 2)      { ISSUE(s + 2, (s + 2) % 3); VMCNT8; }
    else if (s == NST - 2){ VMCNT4; }
    else                  { VMCNT0; }
    SBAR;
    const char* bb = &bufB[s % 3][0];
#pragma unroll
    for (int tt = 0; tt < 2; ++tt) {
      const int lc = tt * 16 + l15;
      const unsigned sw = ((unsigned)(l15 & 7)) << 4;
      f32x4 a0 = (f32x4){0.f, 0.f, 0.f, 0.f};
      f32x4 a1 = (f32x4){0.f, 0.f, 0.f, 0.f};
#pragma unroll
      for (int kk = 0; kk < 8; ++kk) {
        const unsigned off = ((unsigned)(lc * 512 + kk * 64 + q * 16)) ^ sw;
        bf16x8 bh = *(const bf16x8*)(bb + off);
        bf16x8 bl = *(const bf16x8*)(bb + 16384 + off);
        a0 = __builtin_amdgcn_mfma_f32_16x16x32_bf16(ah[0][kk], bh, a0, 0, 0, 0);
        a1 = __builtin_amdgcn_mfma_f32_16x16x32_bf16(ah[1][kk], bh, a1, 0, 0, 0);
        a0 = __builtin_amdgcn_mfma_f32_16x16x32_bf16(al[0][kk], bh, a0, 0, 0, 0);
        a1 = __builtin_amdgcn_mfma_f32_16x16x32_bf16(al[1][kk], bh, a1, 0, 0, 0);
        a0 = __builtin_amdgcn_mfma_f32_16x16x32_bf16(ah[0][kk], bl, a0, 0, 0, 0);
        a1 = __builtin_amdgcn_mfma_f32_16x16x32_bf16(ah[1][kk], bl, a1, 0, 0, 0);
      }
      // fold: half-score v = esq/2 - dot; strict < keeps lowest idx
      const int code = s * 32 + lc;
      const float eh = 0.5f * esqs[code];
#pragma unroll
      for (int rr = 0; rr < 4; ++rr) {
        {
          float v = eh - a0[rr];
          bool  tk = v < t1[0][rr];
          float m2 = fminf(t2[0][rr], v);
          t2[0][rr] = tk ? t1[0][rr] : m2;
          ti[0][rr] = tk ? code : ti[0][rr];
          t1[0][rr] = tk ? v : t1[0][rr];
        }
        {
          float v = eh - a1[rr];
          bool  tk = v < t1[1][rr];
          float m2 = fminf(t2[1][rr], v);
          t2[1][rr] = tk ? t1[1][rr] : m2;
          ti[1][rr] = tk ? code : ti[1][rr];
          t1[1][rr] = tk ? v : t1[1][rr];
        }
      }
    }
    SBAR;            // all waves done reading buf[s%3]; refilled at s+1
  }

  // ---- reduce across the 16 lanes (l15) sharing the same rows; store ------
#pragma unroll
  for (int i = 0; i < 2; ++i)
#pragma unroll
    for (int rr = 0; rr < 4; ++rr) {
      float a1 = t1[i][rr], a2 = t2[i][rr];
      int   ai = ti[i][rr];
#pragma unroll
      for (int m = 1; m < 16; m <<= 1) {
        float o1 = __shfl_xor(a1, m, 64);
        float o2 = __shfl_xor(a2, m, 64);
        int   oi = __shfl_xor(ai, m, 64);
        bool  tk = (o1 < a1) || (o1 == a1 && oi < ai);
        float losr = tk ? a1 : o1;
        a2 = fminf(fminf(a2, o2), losr);
        a1 = tk ? o1 : a1;
        ai = tk ? oi : ai;
      }
      if (l15 == 0) {
        int row = rbase + i * 16 + q * 4 + rr;   // unique owner per row
        v1s[row] = a1; v2s[row] = a2; i1s[row] = ai;
      }
    }
  __syncthreads();

  // ---- per-row finalize (rows disjoint across waves) ----------------------
  if (tid < MT) {
    float bv1 = v1s[tid], bv2 = v2s[tid];
    int   bi = i1s[tid];
    fidxs[tid] = bi;
    carr[tid]  = zsqs[tid] + 2.f * bv1;   // min ||z-e||^2
    if (2.f * (bv2 - bv1) < 0.02f) {      // near-tie -> exact fp64 rescan
      int pos = atomicAdd(&flagcnt, 1);   // (3-pass err ~3e-4 << 0.02)
      flaglist[pos] = tid;
    }
    int mk;
    if (!(mmode & 1))      mk = maskg[m0 + tid] ? 1 : 0;                          // int32
    else if (!(mmode & 2)) mk = ((const float*)maskg)[m0 + tid] != 0.f ? 1 : 0;   // fp32
    else if (!(mmode & 4)) mk = ((const unsigned short*)maskg)[m0 + tid] ? 1 : 0; // bf16
    else                   mk = ((const unsigned char*)maskg)[m0 + tid] ? 1 : 0;  // bool
    maskb[tid] = mk;
  }
  __syncthreads();

  // ---- exact fp64 rescan: WAVE-PARALLEL (8 rows/batch, no inner barriers),
  //      COALESCED via transposed codebook: lane handles codes lane+c*64,
  //      reads cbf[d*512 + lane + c*64] -> lane-stride 4B (4 lines/wave).
  //      Rare at 0.02 threshold (~0.4% of rows).
  int nflag = flagcnt;
  for (int f0 = 0; f0 < nflag; f0 += 8) {
    const int fi = f0 + wave;
    if (fi < nflag) {
      const int row = flaglist[fi];
      const float* zr = &zg[(size_t)(m0 + row) * DD];
      double d2[8] = {0., 0., 0., 0., 0., 0., 0., 0.};
      for (int d = 0; d < DD; ++d) {
        double zd = (double)zr[d];
        const float* cr = &cbf[(size_t)d * KCB + lane];
#pragma unroll
        for (int c = 0; c < 8; ++c) {
          double df = zd - (double)cr[c * 64];
          d2[c] = fma(df, df, d2[c]);
        }
      }
      double bd = d2[0];
      int    bk = lane;
#pragma unroll
      for (int c = 1; c < 8; ++c)           // ascending code order: strict <
        if (d2[c] < bd) { bd = d2[c]; bk = lane + c * 64; }
      for (int m = 1; m < 64; m <<= 1) {
        double od = __shfl_xor(bd, m, 64);
        int    ok = __shfl_xor(bk, m, 64);
        if (od < bd || (od == bd && ok < bk)) { bd = od; bk = ok; }
      }
      if (lane == 0) { fidxs[row] = bk; carr[row] = (float)bd; }
    }
  }
  __syncthreads();

  // ---- index output: float32 values, -1.0 pad ----
  if (tid < MT)
    outidx[m0 + tid] = maskb[tid] ? (float)(fidxs[tid] & (KCB - 1)) : -1.0f;

  // ---- commit partial -> device atomicAdd (waves 0-3, 64 rows each) -------
  if (tid < MT) {
    float c = carr[tid];
    for (int m = 1; m < 64; m <<= 1) c += __shfl_xor(c, m, 64);
    if (lane == 0) atomicAdd(wsum, c);
  }

  // ---- quantized output: float32 codebook gather, masked ----
#pragma unroll
  for (int it = 0; it < 32; ++it) {
    int idx = it * 512 + tid;             // float4 index: 256 rows x 64
    int row = idx >> 6;
    int f4  = idx & 63;
    int k   = fidxs[row] & (KCB - 1);
    float4 val = {0.f, 0.f, 0.f, 0.f};
    if (maskb[row]) val = ((const float4*)cbg)[(size_t)k * 64 + f4];
    ((float4*)outq)[(size_t)(m0 + row) * 64 + f4] = val;
  }
}

// ================= fallback (no workspace): in-register B conversion =======
__global__ __launch_bounds__(256, 3) void vq_main_fb(
    const float* __restrict__ zg, const int* __restrict__ maskg,
    const float* __restrict__ cbg, float* __restrict__ outq,
    float* __restrict__ outidx, float* __restrict__ wsum)
{
  __shared__ unsigned short zs_hi[8 * 32 * 32];
  __shared__ unsigned short zs_lo[8 * 32 * 32];
  __shared__ float esqs[KCB];
  __shared__ float zsq[32];
  __shared__ float wv1[4][32], wv2[4][32];
  __shared__ int   wi1[4][32];
  __shared__ float carr[32];
  __shared__ int   fidxs[32], maskb[32], flaglist[32];
  __shared__ int   flagcnt, mflags;
  __shared__ double rbd[4];
  __shared__ int    rbi[4];

  const int tid  = threadIdx.x;
  const int lane = tid & 63;
  const int wave = tid >> 6;
  const int q    = lane >> 4;
  const int l15  = lane & 15;
  const int m0   = blockIdx.x * 32;

  if (tid == 0) { flagcnt = 0; mflags = 0; }
  int wm = 0;
  if (tid < 128) {
    unsigned int W = ((const unsigned int*)maskg)[tid];
    if (W > 1u) wm |= 1;
    if (W != 0u && W != 0x3f800000u) wm |= 2;
    unsigned int lo = W & 0xffffu, hi = W >> 16;
    if ((lo != 0u && lo != 0x3f80u) || (hi != 0u && hi != 0x3f80u)) wm |= 4;
  }
  if (wm) atomicOr(&mflags, wm);

#pragma unroll
  for (int i = 0; i < 8; ++i) {
    int idx = i * 256 + tid;
    int row = idx >> 6;
    int f4  = idx & 63;
    float4 v = ((const float4*)zg)[(size_t)(m0 + row) * 64 + f4];
    int ch  = f4 >> 3;
    int col = (f4 & 7) * 4;
    int base = (ch * 32 + row) * 32 + col;
    ushort4 h, l;
    h.x = f2bf(v.x); l.x = f2bf(v.x - bf2f(h.x));
    h.y = f2bf(v.y); l.y = f2bf(v.y - bf2f(h.y));
    h.z = f2bf(v.z); l.z = f2bf(v.z - bf2f(h.z));
    h.w = f2bf(v.w); l.w = f2bf(v.w - bf2f(h.w));
    *(ushort4*)&zs_hi[base] = h;
    *(ushort4*)&zs_lo[base] = l;
    float s = v.x * v.x + v.y * v.y + v.z * v.z + v.w * v.w;
#pragma unroll
    for (int m = 1; m < 64; m <<= 1) s += __shfl_xor(s, m, 64);
    if (lane == 0) zsq[row] = s;
  }
  for (int c = tid; c < KCB; c += 256) {
    float s = 0.f;
    for (int f4i = 0; f4i < 64; ++f4i) {
      float4 v = ((const float4*)cbg)[(size_t)c * 64 + f4i];
      s = fmaf(v.x, v.x, s); s = fmaf(v.y, v.y, s);
      s = fmaf(v.z, v.z, s); s = fmaf(v.w, v.w, s);
    }
    esqs[c] = s;
  }
  __syncthreads();
  const int mmode = mflags;

  f32x4 acc[8][2];
#pragma unroll
  for (int t = 0; t < 8; ++t) {
    acc[t][0] = (f32x4){0.f, 0.f, 0.f, 0.f};
    acc[t][1] = (f32x4){0.f, 0.f, 0.f, 0.f};
  }
  const unsigned short* Abh = &zs_hi[l15 * 32 + q * 8];
  const unsigned short* Abl = &zs_lo[l15 * 32 + q * 8];

  for (int kk = 0; kk < 8; ++kk) {
    bf16x8 ah0 = *(const bf16x8*)(Abh + kk * 1024);
    bf16x8 ah1 = *(const bf16x8*)(Abh + kk * 1024 + 512);
    bf16x8 al0 = *(const bf16x8*)(Abl + kk * 1024);
    bf16x8 al1 = *(const bf16x8*)(Abl + kk * 1024 + 512);
#pragma unroll
    for (int t = 0; t < 8; ++t) {
      const int code_row = (wave * 8 + t) * 16 + l15;
      const float* src = &cbg[(size_t)code_row * 256 + kk * 32 + q * 8];
      float4 v0 = *(const float4*)src;
      float4 v1 = *(const float4*)(src + 4);
      float f[8] = {v0.x, v0.y, v0.z, v0.w, v1.x, v1.y, v1.z, v1.w};
      union { ushort us[8]; bf16x8 v; } H, L;
#pragma unroll
      for (int e = 0; e < 8; ++e) {
        unsigned short hh = f2bf(f[e]);
        H.us[e] = hh;
        L.us[e] = f2bf(f[e] - bf2f(hh));
      }
      bf16x8 bh = H.v, bl = L.v;
      acc[t][0] = __builtin_amdgcn_mfma_f32_16x16x32_bf16(ah0, bh, acc[t][0], 0, 0, 0);
      acc[t][1] = __builtin_amdgcn_mfma_f32_16x16x32_bf16(ah1, bh, acc[t][1], 0, 0, 0);
      acc[t][0] = __builtin_amdgcn_mfma_f32_16x16x32_bf16(al0, bh, acc[t][0], 0, 0, 0);
      acc[t][1] = __builtin_amdgcn_mfma_f32_16x16x32_bf16(al1, bh, acc[t][1], 0, 0, 0);
      acc[t][0] = __builtin_amdgcn_mfma_f32_16x16x32_bf16(ah0, bl, acc[t][0], 0, 0, 0);
      acc[t][1] = __builtin_amdgcn_mfma_f32_16x16x32_bf16(ah1, bl, acc[t][1], 0, 0, 0);
    }
  }

  float t1[2][4], t2[2][4];
  int   ti[2][4];
#pragma unroll
  for (int i = 0; i < 2; ++i)
#pragma unroll
    for (int rr = 0; rr < 4; ++rr) { t1[i][rr] = 3.0e38f; t2[i][rr] = 3.0e38f; ti[i][rr] = 0; }
#pragma unroll
  for (int t = 0; t < 8; ++t) {
    const int code = (wave * 8 + t) * 16 + l15;
    const float eh = 0.5f * esqs[code];
#pragma unroll
    for (int i = 0; i < 2; ++i)
#pragma unroll
      for (int rr = 0; rr < 4; ++rr) {
        float v = eh - acc[t][i][rr];
        bool  tk = v < t1[i][rr];
        float m2 = fminf(t2[i][rr], v);
        t2[i][rr] = tk ? t1[i][rr] : m2;
        ti[i][rr] = tk ? code : ti[i][rr];
        t1[i][rr] = tk ? v : t1[i][rr];
      }
  }
#pragma unroll
  for (int i = 0; i < 2; ++i)
#pragma unroll
    for (int rr = 0; rr < 4; ++rr) {
      float a1 = t1[i][rr], a2 = t2[i][rr];
      int   ai = ti[i][rr];
#pragma unroll
      for (int m = 1; m < 16; m <<= 1) {
        float o1 = __shfl_xor(a1, m, 64);
        float o2 = __shfl_xor(a2, m, 64);
        int   oi = __shfl_xor(ai, m, 64);
        bool  tk = (o1 < a1) || (o1 == a1 && oi < ai);
        float losr = tk ? a1 : o1;
        a2 = fminf(fminf(a2, o2), losr);
        a1 = tk ? o1 : a1;
        ai = tk ? oi : ai;
      }
      if (l15 == 0) {
        int row = i * 16 + q * 4 + rr;
        wv1[wave][row] = a1; wv2[wave][row] = a2; wi1[wave][row] = ai;
      }
    }
  __syncthreads();

  if (tid < 32) {
    float bv1 = 3.0e38f, bv2 = 3.0e38f;
    int   bi = 0x7fffffff;
#pragma unroll
    for (int w = 0; w < 4; ++w) {
      float a1 = wv1[w][tid], a2 = wv2[w][tid];
      int   ai = wi1[w][tid];
      bool  tk = (a1 < bv1) || (a1 == bv1 && ai < bi);
      if (tk) { bv2 = fminf(bv1, a2); bv1 = a1; bi = ai; }
      else    { bv2 = fminf(bv2, a1); }
    }
    fidxs[tid] = bi;
    carr[tid]  = zsq[tid] + 2.f * bv1;
    if (2.f * (bv2 - bv1) < 0.02f) {
      int pos = atomicAdd(&flagcnt, 1);
      flaglist[pos] = tid;
    }
    int mk;
    if (!(mmode & 1))      mk = maskg[m0 + tid] ? 1 : 0;
    else if (!(mmode & 2)) mk = ((const float*)maskg)[m0 + tid] != 0.f ? 1 : 0;
    else if (!(mmode & 4)) mk = ((const unsigned short*)maskg)[m0 + tid] ? 1 : 0;
    else                   mk = ((const unsigned char*)maskg)[m0 + tid] ? 1 : 0;
    maskb[tid] = mk;
  }
  __syncthreads();

  int nflag = flagcnt;
  for (int f = 0; f < nflag; ++f) {
    int row = flaglist[f];
    double bd = 1e300;
    int    bk = 0;
    for (int k = tid; k < KCB; k += 256) {
      double d2 = 0.0;
      for (int d = 0; d < DD; ++d) {
        double df = (double)zg[(size_t)(m0 + row) * DD + d] - (double)cbg[(size_t)k * DD + d];
        d2 = fma(df, df, d2);
      }
      if (d2 < bd) { bd = d2; bk = k; }
    }
    for (int m = 1; m < 64; m <<= 1) {
      double od = __shfl_xor(bd, m, 64);
      int    ok = __shfl_xor(bk, m, 64);
      if (od < bd || (od == bd && ok < bk)) { bd = od; bk = ok; }
    }
    if (lane == 0) { rbd[wave] = bd; rbi[wave] = bk; }
    __syncthreads();
    if (tid == 0) {
      double xd = rbd[0]; int xk = rbi[0];
      for (int w = 1; w < 4; ++w)
        if (rbd[w] < xd || (rbd[w] == xd && rbi[w] < xk)) { xd = rbd[w]; xk = rbi[w]; }
      fidxs[row] = xk;
      carr[row]  = (float)xd;
    }
    __syncthreads();
  }
  __syncthreads();

  if (tid < 32)
    outidx[m0 + tid] = maskb[tid] ? (float)(fidxs[tid] & (KCB - 1)) : -1.0f;

  if (wave == 0) {
    float c = (lane < 32) ? carr[lane] : 0.f;
    for (int m = 1; m < 64; m <<= 1) c += __shfl_xor(c, m, 64);
    if (lane == 0) atomicAdd(wsum, c);
  }

#pragma unroll
  for (int i = 0; i < 8; ++i) {
    int idx = i * 256 + tid;
    int row = idx >> 6;
    int f4  = idx & 63;
    int k   = fidxs[row] & (KCB - 1);
    float4 val = {0.f, 0.f, 0.f, 0.f};
    if (maskb[row]) val = ((const float4*)cbg)[(size_t)k * 64 + f4];
    ((float4*)outq)[(size_t)(m0 + row) * 64 + f4] = val;
  }
}

__global__ void vq_final(const float* __restrict__ wsum,
                         float* __restrict__ outloss) {
  if (threadIdx.x == 0)
    outloss[0] = 0.25f * (wsum[0] / 16777216.0f);   // mean over B*N*D
}

extern "C" void kernel_launch(void* const* d_in, const int* in_sizes, int n_in,
                              void* d_out, int out_size, void* d_ws, size_t ws_size,
                              hipStream_t stream) {
  // Inputs identified by element count. z/codebook FLOAT32, mask probed.
  const void* pz = d_in[0];
  const void* pm = (n_in > 1) ? d_in[1] : d_in[0];
  const void* pc = (n_in > 2) ? d_in[2] : d_in[0];
  for (int i = 0; i < n_in; ++i) {
    if      (in_sizes[i] == BN * DD)  pz = d_in[i];
    else if (in_sizes[i] == BN)       pm = d_in[i];
    else if (in_sizes[i] == KCB * DD) pc = d_in[i];
  }
  const float* zg  = (const float*)pz;
  const int*   mk  = (const int*)pm;
  const float* cbg = (const float*)pc;

  float* outq   = (float*)d_out;
  float* outidx = outq + (size_t)BN * DD;
  float* outls  = outidx + BN;
  float* wsum   = (float*)d_ws;

  // ws layout: [0] wsum | +1024 esq (2KB) | +4096 cbt (512KB stage-major)
  //            | +528384 cbT fp32 transposed (512KB)  => total ~1.03 MB
  const size_t ESQ_OFF = 1024;
  const size_t CBT_OFF = 4096;
  const size_t CBF_OFF = CBT_OFF + (size_t)KCB * DD * 2 * 2;      // 528384
  const size_t WS_NEED = CBF_OFF + (size_t)KCB * DD * 4;          // ~1.03 MB

  if (ws_size >= WS_NEED) {
    char*  cbt = (char*)d_ws + CBT_OFF;
    float* cbf = (float*)((char*)d_ws + CBF_OFF);
    float* esw = (float*)((char*)d_ws + ESQ_OFF);
    vq_prep<<<128, 256, 0, stream>>>(cbg, cbt, cbf, esw, wsum);
    vq_main<<<NBLK, 512, 0, stream>>>(zg, mk, cbg, cbt, cbf, esw,
                                      outq, outidx, wsum);
    vq_final<<<1, 64, 0, stream>>>(wsum, outls);
  } else {
    vq_zero_ws<<<1, 1, 0, stream>>>(wsum);
    vq_main_fb<<<2048, 256, 0, stream>>>(zg, mk, cbg, outq, outidx, wsum);
    vq_final<<<1, 64, 0, stream>>>(wsum, outls);
  }
}

// Round 10
// 217.483 us; speedup vs baseline: 3.2767x; 1.0127x over previous
//
#include <hip/hip_runtime.h>

// Problem constants
#define BN    65536    // B*N rows
#define DD    256      // D
#define KCB   512      // codebook entries
#define MT    256      // rows per block (main kernel)
#define NBLK  256      // BN/MT -> exactly 1 block per CU (proven best)
#define NST   16       // codebook stages of 32 codes (hi+lo staging)

typedef __attribute__((ext_vector_type(8))) short bf16x8;
typedef __attribute__((ext_vector_type(4))) float f32x4;

static __device__ __forceinline__ float bf2f(unsigned short u) {
  return __uint_as_float(((unsigned int)u) << 16);
}
static __device__ __forceinline__ unsigned short f2bf(float f) {
  unsigned int u = __float_as_uint(f);
  return (unsigned short)((u + 0x7fffu + ((u >> 16) & 1u)) >> 16);  // RNE
}
static __device__ __forceinline__ void gll16(const void* g, void* l) {
  __builtin_amdgcn_global_load_lds(
      (const __attribute__((address_space(1))) unsigned int*)g,
      (__attribute__((address_space(3))) unsigned int*)l, 16, 0, 0);
}

__global__ void vq_zero_ws(float* ws) { ws[0] = 0.f; }   // fallback path only

// ---- one-shot prep: codebook fp32 -> bf16 hi/lo, 32-code-stage layout with
// XOR bank-swizzle pre-applied in GLOBAL memory (linear global_load_lds dest
// + inverse-swz source + swz read). Stage s (32 codes, 32 KB) at s*32768:
// [16 KB hi][16 KB lo]; code lc (0..31) byte b at (lc*512+b) ^ ((lc&7)<<4).
// Plus TRANSPOSED fp32 copy cbT[d][k] for the coalesced exact rescan,
// fp64-exact e_sq, and wsum zeroing.
// Numerics: 3-pass MFMA (zh+zl)*eh + zh*el leaves only |z_lo.e_lo| ~3e-4
// -> 0.02 rescan threshold gives ~0.4% flag rate (round-3-verified).
__global__ void vq_prep(const float* __restrict__ cbg,
                        char* __restrict__ cbt,
                        float* __restrict__ cbf,   // (D, K) transposed fp32
                        float* __restrict__ esq,
                        float* __restrict__ wsum) {
  if (blockIdx.x == 0 && threadIdx.x == 0) wsum[0] = 0.f;
  const int tid = threadIdx.x, lane = tid & 63, wave = tid >> 6;
  const int code = blockIdx.x * 4 + wave;
  float4 v = ((const float4*)cbg)[(size_t)code * 64 + lane];
  ushort4 h, l;
  h.x = f2bf(v.x); l.x = f2bf(v.x - bf2f(h.x));
  h.y = f2bf(v.y); l.y = f2bf(v.y - bf2f(h.y));
  h.z = f2bf(v.z); l.z = f2bf(v.z - bf2f(h.z));
  h.w = f2bf(v.w); l.w = f2bf(v.w - bf2f(h.w));
  const int s  = code >> 5;
  const int lc = code & 31;
  unsigned raw = (unsigned)(lc * 512 + lane * 8);     // 8 bytes per lane
  unsigned off = (unsigned)(s * 32768) + (raw ^ ((unsigned)(lc & 7) << 4));
  *(ushort4*)(cbt + off)         = h;
  *(ushort4*)(cbt + off + 16384) = l;
  // transposed fp32 copy: cbT[d][k] (scattered one-shot stores, ~512 KB)
  cbf[(size_t)(lane * 4 + 0) * KCB + code] = v.x;
  cbf[(size_t)(lane * 4 + 1) * KCB + code] = v.y;
  cbf[(size_t)(lane * 4 + 2) * KCB + code] = v.z;
  cbf[(size_t)(lane * 4 + 3) * KCB + code] = v.w;
  double sq = (double)v.x * v.x + (double)v.y * v.y +
              (double)v.z * v.z + (double)v.w * v.w;
#pragma unroll
  for (int m = 1; m < 64; m <<= 1) sq += __shfl_xor(sq, m, 64);
  if (lane == 0) esq[code] = (float)sq;
}

// issue stage S (32 KB) into LDS ring buffer BSEL: 4 x global_load_lds(16B)
// per thread (512 threads); dest = wave-uniform base + lane*16 (HW req).
#define ISSUE(S, BSEL)                                                       \
  do {                                                                       \
    const char* _src = cbt + (size_t)(S) * 32768 + (size_t)tid * 16;         \
    char* _dst = &bufB[BSEL][tid * 16];                                      \
    _Pragma("unroll")                                                        \
    for (int _r = 0; _r < 4; ++_r)                                           \
      gll16(_src + _r * 8192, _dst + _r * 8192);                             \
  } while (0)

#define VMCNT4 asm volatile("s_waitcnt vmcnt(4)" ::: "memory")
#define VMCNT0 asm volatile("s_waitcnt vmcnt(0)" ::: "memory")
#define SBAR   asm volatile("s_barrier" ::: "memory")

__global__ __launch_bounds__(512, 2) void vq_main(
    const float* __restrict__ zg,    // (BN, D) float32
    const int* __restrict__ maskg,   // (BN) mask, dtype probed
    const float* __restrict__ cbg,   // (K, D) float32 (gather)
    const char* __restrict__ cbt,    // stage-major swizzled bf16 hi/lo
    const float* __restrict__ cbf,   // (D, K) transposed fp32 (rescan)
    const float* __restrict__ esqg,  // (K) fp64-acc esq
    float* __restrict__ outq,        // (BN, D) float32
    float* __restrict__ outidx,      // (BN) float32 (-1 pad)
    float* __restrict__ wsum)        // d_ws fp32 accumulator
{
  // ~108 KB LDS; 8 waves (2/SIMD), 1 block/CU. A (z) lives in registers.
  // 3-buffer ring + depth-1 prefetch -> ONE barrier per stage is race-free:
  // ISSUE at stage s targets buf[(s+1)%3], last read at stage s-2; every
  // wave passed stage s-1's barrier, which guarantees compute(s-2) finished
  // block-wide. Halves the barrier count vs the 2-barrier double-buffer.
  __shared__ __align__(16) char bufB[3][32768];   // ring: 16K hi | 16K lo
  __shared__ float esqs[KCB];
  __shared__ float zsqs[MT];
  __shared__ float v1s[MT], v2s[MT];
  __shared__ int   i1s[MT];
  __shared__ float carr[MT];
  __shared__ int   fidxs[MT], maskb[MT], flaglist[MT];
  __shared__ int   flagcnt, mflags;

  const int tid   = threadIdx.x;
  const int lane  = tid & 63;
  const int wave  = tid >> 6;
  const int q     = lane >> 4;
  const int l15   = lane & 15;
  const int m0    = blockIdx.x * MT;
  const int rbase = wave * 32;           // wave's 32 local rows

  if (tid == 0) { flagcnt = 0; mflags = 0; }

  // ---- mask dtype probe on first 512 bytes (in-bounds under every layout) --
  int wm = 0;
  if (tid < 128) {
    unsigned int W = ((const unsigned int*)maskg)[tid];
    if (W > 1u) wm |= 1;
    if (W != 0u && W != 0x3f800000u) wm |= 2;
    unsigned int lo = W & 0xffffu, hi = W >> 16;
    if ((lo != 0u && lo != 0x3f80u) || (hi != 0u && hi != 0x3f80u)) wm |= 4;
  }
  if (wm) atomicOr(&mflags, wm);

  // ---- esq into LDS (512 threads, 512 entries) ----
  esqs[tid] = esqg[tid];

  // ---- prefetch stage 0 before the z prologue (overlaps with z loads) ----
  ISSUE(0, 0);

  // ---- z -> A registers: 32 rows/wave, bf16 hi/lo; fused exact-fp32 z_sq --
  bf16x8 ah[2][8], al[2][8];
  float zacc0 = 0.f, zacc1 = 0.f;
#pragma unroll
  for (int i = 0; i < 2; ++i) {
    const int grow = m0 + rbase + i * 16 + l15;
#pragma unroll
    for (int kk = 0; kk < 8; ++kk) {
      const float* src = &zg[(size_t)grow * DD + kk * 32 + q * 8];
      float4 v0 = *(const float4*)src;
      float4 v1 = *(const float4*)(src + 4);
      float f[8] = {v0.x, v0.y, v0.z, v0.w, v1.x, v1.y, v1.z, v1.w};
      union { ushort us[8]; bf16x8 v; } H, L;
#pragma unroll
      for (int e = 0; e < 8; ++e) {
        unsigned short hh = f2bf(f[e]);
        H.us[e] = hh;
        L.us[e] = f2bf(f[e] - bf2f(hh));
      }
      ah[i][kk] = H.v;
      al[i][kk] = L.v;
      float s = 0.f;
#pragma unroll
      for (int e = 0; e < 8; ++e) s = fmaf(f[e], f[e], s);
      if (i == 0) zacc0 += s; else zacc1 += s;
    }
  }
  {
    float s0 = zacc0, s1 = zacc1;
    s0 += __shfl_xor(s0, 16, 64); s0 += __shfl_xor(s0, 32, 64);
    s1 += __shfl_xor(s1, 16, 64); s1 += __shfl_xor(s1, 32, 64);
    if (q == 0) {
      zsqs[rbase + l15]      = s0;
      zsqs[rbase + 16 + l15] = s1;
    }
  }
  __syncthreads();   // drains z loads + stage 0; esqs/zsqs/mflags visible
  const int mmode = mflags;

  // ---- per-thread running top-2 over all 512 codes ----
  float t1[2][4], t2[2][4];
  int   ti[2][4];
#pragma unroll
  for (int i = 0; i < 2; ++i)
#pragma unroll
    for (int rr = 0; rr < 4; ++rr) { t1[i][rr] = 3.0e38f; t2[i][rr] = 3.0e38f; ti[i][rr] = 0; }

  // ---- 16-stage pipeline, depth-1 prefetch, SINGLE barrier per stage ----
  // 3-pass MFMA per code-tile: (ah+al)xbh + ahxbl (z_lo.e_lo dropped ~3e-4,
  // covered by the 0.02 rescan threshold — round-3-verified numerics).
  int rd = 0;                        // ring slot holding stage s
#pragma unroll 1
  for (int s = 0; s < NST; ++s) {
    int wr = rd + 1; if (wr == 3) wr = 0;        // slot for stage s+1
    if (s < NST - 1) { ISSUE(s + 1, wr); VMCNT4; }
    else             { VMCNT0; }
    SBAR;            // all waves done compute(s-1); stage s landed (vmcnt)
    const char* bb = &bufB[rd][0];
#pragma unroll
    for (int tt = 0; tt < 2; ++tt) {
      const int lc = tt * 16 + l15;
      const unsigned sw = ((unsigned)(l15 & 7)) << 4;
      f32x4 a0 = (f32x4){0.f, 0.f, 0.f, 0.f};
      f32x4 a1 = (f32x4){0.f, 0.f, 0.f, 0.f};
#pragma unroll
      for (int kk = 0; kk < 8; ++kk) {
        const unsigned off = ((unsigned)(lc * 512 + kk * 64 + q * 16)) ^ sw;
        bf16x8 bh = *(const bf16x8*)(bb + off);
        bf16x8 bl = *(const bf16x8*)(bb + 16384 + off);
        a0 = __builtin_amdgcn_mfma_f32_16x16x32_bf16(ah[0][kk], bh, a0, 0, 0, 0);
        a1 = __builtin_amdgcn_mfma_f32_16x16x32_bf16(ah[1][kk], bh, a1, 0, 0, 0);
        a0 = __builtin_amdgcn_mfma_f32_16x16x32_bf16(al[0][kk], bh, a0, 0, 0, 0);
        a1 = __builtin_amdgcn_mfma_f32_16x16x32_bf16(al[1][kk], bh, a1, 0, 0, 0);
        a0 = __builtin_amdgcn_mfma_f32_16x16x32_bf16(ah[0][kk], bl, a0, 0, 0, 0);
        a1 = __builtin_amdgcn_mfma_f32_16x16x32_bf16(ah[1][kk], bl, a1, 0, 0, 0);
      }
      // fold: half-score v = esq/2 - dot; strict < keeps lowest idx
      const int code = s * 32 + lc;
      const float eh = 0.5f * esqs[code];
#pragma unroll
      for (int rr = 0; rr < 4; ++rr) {
        {
          float v = eh - a0[rr];
          bool  tk = v < t1[0][rr];
          float m2 = fminf(t2[0][rr], v);
          t2[0][rr] = tk ? t1[0][rr] : m2;
          ti[0][rr] = tk ? code : ti[0][rr];
          t1[0][rr] = tk ? v : t1[0][rr];
        }
        {
          float v = eh - a1[rr];
          bool  tk = v < t1[1][rr];
          float m2 = fminf(t2[1][rr], v);
          t2[1][rr] = tk ? t1[1][rr] : m2;
          ti[1][rr] = tk ? code : ti[1][rr];
          t1[1][rr] = tk ? v : t1[1][rr];
        }
      }
    }
    rd = wr;
  }

  // ---- reduce across the 16 lanes (l15) sharing the same rows; store ------
#pragma unroll
  for (int i = 0; i < 2; ++i)
#pragma unroll
    for (int rr = 0; rr < 4; ++rr) {
      float a1 = t1[i][rr], a2 = t2[i][rr];
      int   ai = ti[i][rr];
#pragma unroll
      for (int m = 1; m < 16; m <<= 1) {
        float o1 = __shfl_xor(a1, m, 64);
        float o2 = __shfl_xor(a2, m, 64);
        int   oi = __shfl_xor(ai, m, 64);
        bool  tk = (o1 < a1) || (o1 == a1 && oi < ai);
        float losr = tk ? a1 : o1;
        a2 = fminf(fminf(a2, o2), losr);
        a1 = tk ? o1 : a1;
        ai = tk ? oi : ai;
      }
      if (l15 == 0) {
        int row = rbase + i * 16 + q * 4 + rr;   // unique owner per row
        v1s[row] = a1; v2s[row] = a2; i1s[row] = ai;
      }
    }
  __syncthreads();

  // ---- per-row finalize (rows disjoint across waves) ----------------------
  if (tid < MT) {
    float bv1 = v1s[tid], bv2 = v2s[tid];
    int   bi = i1s[tid];
    fidxs[tid] = bi;
    carr[tid]  = zsqs[tid] + 2.f * bv1;   // min ||z-e||^2
    if (2.f * (bv2 - bv1) < 0.02f) {      // near-tie -> exact fp64 rescan
      int pos = atomicAdd(&flagcnt, 1);   // (3-pass err ~3e-4 << 0.02)
      flaglist[pos] = tid;
    }
    int mk;
    if (!(mmode & 1))      mk = maskg[m0 + tid] ? 1 : 0;                          // int32
    else if (!(mmode & 2)) mk = ((const float*)maskg)[m0 + tid] != 0.f ? 1 : 0;   // fp32
    else if (!(mmode & 4)) mk = ((const unsigned short*)maskg)[m0 + tid] ? 1 : 0; // bf16
    else                   mk = ((const unsigned char*)maskg)[m0 + tid] ? 1 : 0;  // bool
    maskb[tid] = mk;
  }
  __syncthreads();

  // ---- exact fp64 rescan: WAVE-PARALLEL (8 rows/batch, no inner barriers),
  //      COALESCED via transposed codebook: lane handles codes lane+c*64,
  //      reads cbf[d*512 + lane + c*64] -> lane-stride 4B (4 lines/wave).
  //      Rare at 0.02 threshold (~0.4% of rows).
  int nflag = flagcnt;
  for (int f0 = 0; f0 < nflag; f0 += 8) {
    const int fi = f0 + wave;
    if (fi < nflag) {
      const int row = flaglist[fi];
      const float* zr = &zg[(size_t)(m0 + row) * DD];
      double d2[8] = {0., 0., 0., 0., 0., 0., 0., 0.};
      for (int d = 0; d < DD; ++d) {
        double zd = (double)zr[d];
        const float* cr = &cbf[(size_t)d * KCB + lane];
#pragma unroll
        for (int c = 0; c < 8; ++c) {
          double df = zd - (double)cr[c * 64];
          d2[c] = fma(df, df, d2[c]);
        }
      }
      double bd = d2[0];
      int    bk = lane;
#pragma unroll
      for (int c = 1; c < 8; ++c)           // ascending code order: strict <
        if (d2[c] < bd) { bd = d2[c]; bk = lane + c * 64; }
      for (int m = 1; m < 64; m <<= 1) {
        double od = __shfl_xor(bd, m, 64);
        int    ok = __shfl_xor(bk, m, 64);
        if (od < bd || (od == bd && ok < bk)) { bd = od; bk = ok; }
      }
      if (lane == 0) { fidxs[row] = bk; carr[row] = (float)bd; }
    }
  }
  __syncthreads();

  // ---- index output: float32 values, -1.0 pad ----
  if (tid < MT)
    outidx[m0 + tid] = maskb[tid] ? (float)(fidxs[tid] & (KCB - 1)) : -1.0f;

  // ---- commit partial -> device atomicAdd (waves 0-3, 64 rows each) -------
  if (tid < MT) {
    float c = carr[tid];
    for (int m = 1; m < 64; m <<= 1) c += __shfl_xor(c, m, 64);
    if (lane == 0) atomicAdd(wsum, c);
  }

  // ---- quantized output: float32 codebook gather, masked ----
#pragma unroll
  for (int it = 0; it < 32; ++it) {
    int idx = it * 512 + tid;             // float4 index: 256 rows x 64
    int row = idx >> 6;
    int f4  = idx & 63;
    int k   = fidxs[row] & (KCB - 1);
    float4 val = {0.f, 0.f, 0.f, 0.f};
    if (maskb[row]) val = ((const float4*)cbg)[(size_t)k * 64 + f4];
    ((float4*)outq)[(size_t)(m0 + row) * 64 + f4] = val;
  }
}

// ================= fallback (no workspace): in-register B conversion =======
__global__ __launch_bounds__(256, 3) void vq_main_fb(
    const float* __restrict__ zg, const int* __restrict__ maskg,
    const float* __restrict__ cbg, float* __restrict__ outq,
    float* __restrict__ outidx, float* __restrict__ wsum)
{
  __shared__ unsigned short zs_hi[8 * 32 * 32];
  __shared__ unsigned short zs_lo[8 * 32 * 32];
  __shared__ float esqs[KCB];
  __shared__ float zsq[32];
  __shared__ float wv1[4][32], wv2[4][32];
  __shared__ int   wi1[4][32];
  __shared__ float carr[32];
  __shared__ int   fidxs[32], maskb[32], flaglist[32];
  __shared__ int   flagcnt, mflags;
  __shared__ double rbd[4];
  __shared__ int    rbi[4];

  const int tid  = threadIdx.x;
  const int lane = tid & 63;
  const int wave = tid >> 6;
  const int q    = lane >> 4;
  const int l15  = lane & 15;
  const int m0   = blockIdx.x * 32;

  if (tid == 0) { flagcnt = 0; mflags = 0; }
  int wm = 0;
  if (tid < 128) {
    unsigned int W = ((const unsigned int*)maskg)[tid];
    if (W > 1u) wm |= 1;
    if (W != 0u && W != 0x3f800000u) wm |= 2;
    unsigned int lo = W & 0xffffu, hi = W >> 16;
    if ((lo != 0u && lo != 0x3f80u) || (hi != 0u && hi != 0x3f80u)) wm |= 4;
  }
  if (wm) atomicOr(&mflags, wm);

#pragma unroll
  for (int i = 0; i < 8; ++i) {
    int idx = i * 256 + tid;
    int row = idx >> 6;
    int f4  = idx & 63;
    float4 v = ((const float4*)zg)[(size_t)(m0 + row) * 64 + f4];
    int ch  = f4 >> 3;
    int col = (f4 & 7) * 4;
    int base = (ch * 32 + row) * 32 + col;
    ushort4 h, l;
    h.x = f2bf(v.x); l.x = f2bf(v.x - bf2f(h.x));
    h.y = f2bf(v.y); l.y = f2bf(v.y - bf2f(h.y));
    h.z = f2bf(v.z); l.z = f2bf(v.z - bf2f(h.z));
    h.w = f2bf(v.w); l.w = f2bf(v.w - bf2f(h.w));
    *(ushort4*)&zs_hi[base] = h;
    *(ushort4*)&zs_lo[base] = l;
    float s = v.x * v.x + v.y * v.y + v.z * v.z + v.w * v.w;
#pragma unroll
    for (int m = 1; m < 64; m <<= 1) s += __shfl_xor(s, m, 64);
    if (lane == 0) zsq[row] = s;
  }
  for (int c = tid; c < KCB; c += 256) {
    float s = 0.f;
    for (int f4i = 0; f4i < 64; ++f4i) {
      float4 v = ((const float4*)cbg)[(size_t)c * 64 + f4i];
      s = fmaf(v.x, v.x, s); s = fmaf(v.y, v.y, s);
      s = fmaf(v.z, v.z, s); s = fmaf(v.w, v.w, s);
    }
    esqs[c] = s;
  }
  __syncthreads();
  const int mmode = mflags;

  f32x4 acc[8][2];
#pragma unroll
  for (int t = 0; t < 8; ++t) {
    acc[t][0] = (f32x4){0.f, 0.f, 0.f, 0.f};
    acc[t][1] = (f32x4){0.f, 0.f, 0.f, 0.f};
  }
  const unsigned short* Abh = &zs_hi[l15 * 32 + q * 8];
  const unsigned short* Abl = &zs_lo[l15 * 32 + q * 8];

  for (int kk = 0; kk < 8; ++kk) {
    bf16x8 ah0 = *(const bf16x8*)(Abh + kk * 1024);
    bf16x8 ah1 = *(const bf16x8*)(Abh + kk * 1024 + 512);
    bf16x8 al0 = *(const bf16x8*)(Abl + kk * 1024);
    bf16x8 al1 = *(const bf16x8*)(Abl + kk * 1024 + 512);
#pragma unroll
    for (int t = 0; t < 8; ++t) {
      const int code_row = (wave * 8 + t) * 16 + l15;
      const float* src = &cbg[(size_t)code_row * 256 + kk * 32 + q * 8];
      float4 v0 = *(const float4*)src;
      float4 v1 = *(const float4*)(src + 4);
      float f[8] = {v0.x, v0.y, v0.z, v0.w, v1.x, v1.y, v1.z, v1.w};
      union { ushort us[8]; bf16x8 v; } H, L;
#pragma unroll
      for (int e = 0; e < 8; ++e) {
        unsigned short hh = f2bf(f[e]);
        H.us[e] = hh;
        L.us[e] = f2bf(f[e] - bf2f(hh));
      }
      bf16x8 bh = H.v, bl = L.v;
      acc[t][0] = __builtin_amdgcn_mfma_f32_16x16x32_bf16(ah0, bh, acc[t][0], 0, 0, 0);
      acc[t][1] = __builtin_amdgcn_mfma_f32_16x16x32_bf16(ah1, bh, acc[t][1], 0, 0, 0);
      acc[t][0] = __builtin_amdgcn_mfma_f32_16x16x32_bf16(al0, bh, acc[t][0], 0, 0, 0);
      acc[t][1] = __builtin_amdgcn_mfma_f32_16x16x32_bf16(al1, bh, acc[t][1], 0, 0, 0);
      acc[t][0] = __builtin_amdgcn_mfma_f32_16x16x32_bf16(ah0, bl, acc[t][0], 0, 0, 0);
      acc[t][1] = __builtin_amdgcn_mfma_f32_16x16x32_bf16(ah1, bl, acc[t][1], 0, 0, 0);
    }
  }

  float t1[2][4], t2[2][4];
  int   ti[2][4];
#pragma unroll
  for (int i = 0; i < 2; ++i)
#pragma unroll
    for (int rr = 0; rr < 4; ++rr) { t1[i][rr] = 3.0e38f; t2[i][rr] = 3.0e38f; ti[i][rr] = 0; }
#pragma unroll
  for (int t = 0; t < 8; ++t) {
    const int code = (wave * 8 + t) * 16 + l15;
    const float eh = 0.5f * esqs[code];
#pragma unroll
    for (int i = 0; i < 2; ++i)
#pragma unroll
      for (int rr = 0; rr < 4; ++rr) {
        float v = eh - acc[t][i][rr];
        bool  tk = v < t1[i][rr];
        float m2 = fminf(t2[i][rr], v);
        t2[i][rr] = tk ? t1[i][rr] : m2;
        ti[i][rr] = tk ? code : ti[i][rr];
        t1[i][rr] = tk ? v : t1[i][rr];
      }
  }
#pragma unroll
  for (int i = 0; i < 2; ++i)
#pragma unroll
    for (int rr = 0; rr < 4; ++rr) {
      float a1 = t1[i][rr], a2 = t2[i][rr];
      int   ai = ti[i][rr];
#pragma unroll
      for (int m = 1; m < 16; m <<= 1) {
        float o1 = __shfl_xor(a1, m, 64);
        float o2 = __shfl_xor(a2, m, 64);
        int   oi = __shfl_xor(ai, m, 64);
        bool  tk = (o1 < a1) || (o1 == a1 && oi < ai);
        float losr = tk ? a1 : o1;
        a2 = fminf(fminf(a2, o2), losr);
        a1 = tk ? o1 : a1;
        ai = tk ? oi : ai;
      }
      if (l15 == 0) {
        int row = i * 16 + q * 4 + rr;
        wv1[wave][row] = a1; wv2[wave][row] = a2; wi1[wave][row] = ai;
      }
    }
  __syncthreads();

  if (tid < 32) {
    float bv1 = 3.0e38f, bv2 = 3.0e38f;
    int   bi = 0x7fffffff;
#pragma unroll
    for (int w = 0; w < 4; ++w) {
      float a1 = wv1[w][tid], a2 = wv2[w][tid];
      int   ai = wi1[w][tid];
      bool  tk = (a1 < bv1) || (a1 == bv1 && ai < bi);
      if (tk) { bv2 = fminf(bv1, a2); bv1 = a1; bi = ai; }
      else    { bv2 = fminf(bv2, a1); }
    }
    fidxs[tid] = bi;
    carr[tid]  = zsq[tid] + 2.f * bv1;
    if (2.f * (bv2 - bv1) < 0.02f) {
      int pos = atomicAdd(&flagcnt, 1);
      flaglist[pos] = tid;
    }
    int mk;
    if (!(mmode & 1))      mk = maskg[m0 + tid] ? 1 : 0;
    else if (!(mmode & 2)) mk = ((const float*)maskg)[m0 + tid] != 0.f ? 1 : 0;
    else if (!(mmode & 4)) mk = ((const unsigned short*)maskg)[m0 + tid] ? 1 : 0;
    else                   mk = ((const unsigned char*)maskg)[m0 + tid] ? 1 : 0;
    maskb[tid] = mk;
  }
  __syncthreads();

  int nflag = flagcnt;
  for (int f = 0; f < nflag; ++f) {
    int row = flaglist[f];
    double bd = 1e300;
    int    bk = 0;
    for (int k = tid; k < KCB; k += 256) {
      double d2 = 0.0;
      for (int d = 0; d < DD; ++d) {
        double df = (double)zg[(size_t)(m0 + row) * DD + d] - (double)cbg[(size_t)k * DD + d];
        d2 = fma(df, df, d2);
      }
      if (d2 < bd) { bd = d2; bk = k; }
    }
    for (int m = 1; m < 64; m <<= 1) {
      double od = __shfl_xor(bd, m, 64);
      int    ok = __shfl_xor(bk, m, 64);
      if (od < bd || (od == bd && ok < bk)) { bd = od; bk = ok; }
    }
    if (lane == 0) { rbd[wave] = bd; rbi[wave] = bk; }
    __syncthreads();
    if (tid == 0) {
      double xd = rbd[0]; int xk = rbi[0];
      for (int w = 1; w < 4; ++w)
        if (rbd[w] < xd || (rbd[w] == xd && rbi[w] < xk)) { xd = rbd[w]; xk = rbi[w]; }
      fidxs[row] = xk;
      carr[row]  = (float)xd;
    }
    __syncthreads();
  }
  __syncthreads();

  if (tid < 32)
    outidx[m0 + tid] = maskb[tid] ? (float)(fidxs[tid] & (KCB - 1)) : -1.0f;

  if (wave == 0) {
    float c = (lane < 32) ? carr[lane] : 0.f;
    for (int m = 1; m < 64; m <<= 1) c += __shfl_xor(c, m, 64);
    if (lane == 0) atomicAdd(wsum, c);
  }

#pragma unroll
  for (int i = 0; i < 8; ++i) {
    int idx = i * 256 + tid;
    int row = idx >> 6;
    int f4  = idx & 63;
    int k   = fidxs[row] & (KCB - 1);
    float4 val = {0.f, 0.f, 0.f, 0.f};
    if (maskb[row]) val = ((const float4*)cbg)[(size_t)k * 64 + f4];
    ((float4*)outq)[(size_t)(m0 + row) * 64 + f4] = val;
  }
}

__global__ void vq_final(const float* __restrict__ wsum,
                         float* __restrict__ outloss) {
  if (threadIdx.x == 0)
    outloss[0] = 0.25f * (wsum[0] / 16777216.0f);   // mean over B*N*D
}

extern "C" void kernel_launch(void* const* d_in, const int* in_sizes, int n_in,
                              void* d_out, int out_size, void* d_ws, size_t ws_size,
                              hipStream_t stream) {
  // Inputs identified by element count. z/codebook FLOAT32, mask probed.
  const void* pz = d_in[0];
  const void* pm = (n_in > 1) ? d_in[1] : d_in[0];
  const void* pc = (n_in > 2) ? d_in[2] : d_in[0];
  for (int i = 0; i < n_in; ++i) {
    if      (in_sizes[i] == BN * DD)  pz = d_in[i];
    else if (in_sizes[i] == BN)       pm = d_in[i];
    else if (in_sizes[i] == KCB * DD) pc = d_in[i];
  }
  const float* zg  = (const float*)pz;
  const int*   mk  = (const int*)pm;
  const float* cbg = (const float*)pc;

  float* outq   = (float*)d_out;
  float* outidx = outq + (size_t)BN * DD;
  float* outls  = outidx + BN;
  float* wsum   = (float*)d_ws;

  // ws layout: [0] wsum | +1024 esq (2KB) | +4096 cbt (512KB stage-major)
  //            | +528384 cbT fp32 transposed (512KB)  => total ~1.03 MB
  const size_t ESQ_OFF = 1024;
  const size_t CBT_OFF = 4096;
  const size_t CBF_OFF = CBT_OFF + (size_t)KCB * DD * 2 * 2;      // 528384
  const size_t WS_NEED = CBF_OFF + (size_t)KCB * DD * 4;          // ~1.03 MB

  if (ws_size >= WS_NEED) {
    char*  cbt = (char*)d_ws + CBT_OFF;
    float* cbf = (float*)((char*)d_ws + CBF_OFF);
    float* esw = (float*)((char*)d_ws + ESQ_OFF);
    vq_prep<<<128, 256, 0, stream>>>(cbg, cbt, cbf, esw, wsum);
    vq_main<<<NBLK, 512, 0, stream>>>(zg, mk, cbg, cbt, cbf, esw,
                                      outq, outidx, wsum);
    vq_final<<<1, 64, 0, stream>>>(wsum, outls);
  } else {
    vq_zero_ws<<<1, 1, 0, stream>>>(wsum);
    vq_main_fb<<<2048, 256, 0, stream>>>(zg, mk, cbg, outq, outidx, wsum);
    vq_final<<<1, 64, 0, stream>>>(wsum, outls);
  }
}

// Round 11
// 207.758 us; speedup vs baseline: 3.4301x; 1.0468x over previous
//
#include <hip/hip_runtime.h>

// Problem constants
#define BN    65536    // B*N rows
#define DD    256      // D
#define KCB   512      // codebook entries
#define MT    256      // rows per block (main kernel)
#define NBLK  256      // BN/MT  -> exactly 1 block per CU
#define NST   16       // codebook stages of 32 codes

typedef __attribute__((ext_vector_type(8))) short bf16x8;
typedef __attribute__((ext_vector_type(4))) float f32x4;

static __device__ __forceinline__ float bf2f(unsigned short u) {
  return __uint_as_float(((unsigned int)u) << 16);
}
static __device__ __forceinline__ unsigned short f2bf(float f) {
  unsigned int u = __float_as_uint(f);
  return (unsigned short)((u + 0x7fffu + ((u >> 16) & 1u)) >> 16);  // RNE
}
static __device__ __forceinline__ void gll16(const void* g, void* l) {
  __builtin_amdgcn_global_load_lds(
      (const __attribute__((address_space(1))) unsigned int*)g,
      (__attribute__((address_space(3))) unsigned int*)l, 16, 0, 0);
}

__global__ void vq_zero_ws(float* ws) { ws[0] = 0.f; }

// ---- one-shot prep: codebook fp32 -> bf16 hi/lo, stage-major layout with
// XOR bank-swizzle pre-applied in GLOBAL memory so the linear
// global_load_lds staging lands a swizzled LDS image (linear dest +
// inverse-swz source + swz read). Stage s (32 codes) = 32 KB at s*32768:
// [16 KB hi][16 KB lo]; within half, code lc byte b at
// (lc*512 + b) ^ ((lc&7)<<4). Also fp64-exact e_sq.
// NOTE (rounds 8-10 post-mortem): 64-code stages, 3-buffer rings (2-deep or
// single-barrier), and fused loss finalize all measured 132-142 us vs this
// structure's 120 us. This exact schedule is the verified optimum.
__global__ void vq_prep(const float* __restrict__ cbg,
                        char* __restrict__ cbt,
                        float* __restrict__ esq) {
  const int tid = threadIdx.x, lane = tid & 63, wave = tid >> 6;
  const int code = blockIdx.x * 4 + wave;
  float4 v = ((const float4*)cbg)[(size_t)code * 64 + lane];
  ushort4 h, l;
  h.x = f2bf(v.x); l.x = f2bf(v.x - bf2f(h.x));
  h.y = f2bf(v.y); l.y = f2bf(v.y - bf2f(h.y));
  h.z = f2bf(v.z); l.z = f2bf(v.z - bf2f(h.z));
  h.w = f2bf(v.w); l.w = f2bf(v.w - bf2f(h.w));
  const int s  = code >> 5;
  const int lc = code & 31;
  unsigned raw = (unsigned)(lc * 512 + lane * 8);     // 8 bytes per lane
  unsigned off = (unsigned)(s * 32768) + (raw ^ ((unsigned)(lc & 7) << 4));
  *(ushort4*)(cbt + off)         = h;
  *(ushort4*)(cbt + off + 16384) = l;
  double sq = (double)v.x * v.x + (double)v.y * v.y +
              (double)v.z * v.z + (double)v.w * v.w;
#pragma unroll
  for (int m = 1; m < 64; m <<= 1) sq += __shfl_xor(sq, m, 64);
  if (lane == 0) esq[code] = (float)sq;
}

// issue stage S (32 KB) into LDS buffer BSEL: 4 x global_load_lds(16B) per
// thread; dest = wave-uniform base + lane*16 (required by HW).
#define ISSUE(S, BSEL)                                                       \
  do {                                                                       \
    const char* _src = cbt + (size_t)(S) * 32768 + (size_t)tid * 16;         \
    char* _dst = &bufB[BSEL][tid * 16];                                      \
    _Pragma("unroll")                                                        \
    for (int _r = 0; _r < 4; ++_r)                                           \
      gll16(_src + _r * 8192, _dst + _r * 8192);                             \
  } while (0)

#define VMCNT4 asm volatile("s_waitcnt vmcnt(4)" ::: "memory")
#define VMCNT0 asm volatile("s_waitcnt vmcnt(0)" ::: "memory")
#define SBAR   asm volatile("s_barrier" ::: "memory")

__global__ __launch_bounds__(512, 2) void vq_main(
    const float* __restrict__ zg,    // (BN, D) float32
    const int* __restrict__ maskg,   // (BN) mask, dtype probed
    const float* __restrict__ cbg,   // (K, D) float32 (rescan + gather)
    const char* __restrict__ cbt,    // stage-major swizzled bf16 hi/lo
    const float* __restrict__ esqg,  // (K) fp64-acc esq
    float* __restrict__ outq,        // (BN, D) float32
    float* __restrict__ outidx,      // (BN) float32 (-1 pad)
    float* __restrict__ wsum)        // d_ws fp32 accumulator
{
  // ~76 KB LDS; 8 waves (2/SIMD). A (z) lives in registers, not LDS.
  __shared__ __align__(16) char bufB[2][32768];   // B dbuf: 16K hi | 16K lo
  __shared__ float esqs[KCB];
  __shared__ float zsqs[MT];
  __shared__ float v1s[MT], v2s[MT];
  __shared__ int   i1s[MT];
  __shared__ float carr[MT];
  __shared__ int   fidxs[MT], maskb[MT], flaglist[MT];
  __shared__ int   flagcnt, mflags;
  __shared__ double rbd[8];
  __shared__ int    rbi[8];

  const int tid   = threadIdx.x;
  const int lane  = tid & 63;
  const int wave  = tid >> 6;
  const int q     = lane >> 4;
  const int l15   = lane & 15;
  const int m0    = blockIdx.x * MT;
  const int rbase = wave * 32;           // wave's 32 local rows

  if (tid == 0) { flagcnt = 0; mflags = 0; }

  // ---- mask dtype probe on first 512 bytes (in-bounds under every layout) --
  int wm = 0;
  if (tid < 128) {
    unsigned int W = ((const unsigned int*)maskg)[tid];
    if (W > 1u) wm |= 1;
    if (W != 0u && W != 0x3f800000u) wm |= 2;
    unsigned int lo = W & 0xffffu, hi = W >> 16;
    if ((lo != 0u && lo != 0x3f80u) || (hi != 0u && hi != 0x3f80u)) wm |= 4;
  }
  if (wm) atomicOr(&mflags, wm);

  // ---- esq into LDS (512 threads, 512 entries) ----
  esqs[tid] = esqg[tid];

  // ---- prefetch stage 0 before the z prologue (overlaps with z loads) ----
  ISSUE(0, 0);

  // ---- z -> A registers: 32 rows/wave, bf16 hi/lo; fused exact-fp32 z_sq --
  bf16x8 ah[2][8], al[2][8];
  float zacc0 = 0.f, zacc1 = 0.f;
#pragma unroll
  for (int i = 0; i < 2; ++i) {
    const int grow = m0 + rbase + i * 16 + l15;
#pragma unroll
    for (int kk = 0; kk < 8; ++kk) {
      const float* src = &zg[(size_t)grow * DD + kk * 32 + q * 8];
      float4 v0 = *(const float4*)src;
      float4 v1 = *(const float4*)(src + 4);
      float f[8] = {v0.x, v0.y, v0.z, v0.w, v1.x, v1.y, v1.z, v1.w};
      union { ushort us[8]; bf16x8 v; } H, L;
#pragma unroll
      for (int e = 0; e < 8; ++e) {
        unsigned short hh = f2bf(f[e]);
        H.us[e] = hh;
        L.us[e] = f2bf(f[e] - bf2f(hh));
      }
      ah[i][kk] = H.v;
      al[i][kk] = L.v;
      float s = 0.f;
#pragma unroll
      for (int e = 0; e < 8; ++e) s = fmaf(f[e], f[e], s);
      if (i == 0) zacc0 += s; else zacc1 += s;
    }
  }
  // reduce z_sq across the 4 q-lanes holding the same row
  {
    float s0 = zacc0, s1 = zacc1;
    s0 += __shfl_xor(s0, 16, 64); s0 += __shfl_xor(s0, 32, 64);
    s1 += __shfl_xor(s1, 16, 64); s1 += __shfl_xor(s1, 32, 64);
    if (q == 0) {
      zsqs[rbase + l15]      = s0;
      zsqs[rbase + 16 + l15] = s1;
    }
  }
  __syncthreads();   // drains z loads + stage 0; esqs/zsqs/mflags visible
  const int mmode = mflags;

  // ---- per-thread running top-2 over all 512 codes ----
  float t1[2][4], t2[2][4];
  int   ti[2][4];
#pragma unroll
  for (int i = 0; i < 2; ++i)
#pragma unroll
    for (int rr = 0; rr < 4; ++rr) { t1[i][rr] = 3.0e38f; t2[i][rr] = 3.0e38f; ti[i][rr] = 0; }

  // ---- 16-stage pipeline over codes; all waves consume the same B tile ----
#pragma unroll 1
  for (int s = 0; s < NST; ++s) {
    if (s < NST - 1) { ISSUE(s + 1, (s + 1) & 1); VMCNT4; }
    else             { VMCNT0; }
    SBAR;
    const char* bb = &bufB[s & 1][0];
#pragma unroll
    for (int tt = 0; tt < 2; ++tt) {
      const int lc = tt * 16 + l15;
      const unsigned sw = ((unsigned)(lc & 7)) << 4;
      f32x4 a0 = (f32x4){0.f, 0.f, 0.f, 0.f};
      f32x4 a1 = (f32x4){0.f, 0.f, 0.f, 0.f};
#pragma unroll
      for (int kk = 0; kk < 8; ++kk) {
        const unsigned off = ((unsigned)(lc * 512 + kk * 64 + q * 16)) ^ sw;
        bf16x8 bh = *(const bf16x8*)(bb + off);
        bf16x8 bl = *(const bf16x8*)(bb + 16384 + off);
        a0 = __builtin_amdgcn_mfma_f32_16x16x32_bf16(ah[0][kk], bh, a0, 0, 0, 0);
        a1 = __builtin_amdgcn_mfma_f32_16x16x32_bf16(ah[1][kk], bh, a1, 0, 0, 0);
        a0 = __builtin_amdgcn_mfma_f32_16x16x32_bf16(al[0][kk], bh, a0, 0, 0, 0);
        a1 = __builtin_amdgcn_mfma_f32_16x16x32_bf16(al[1][kk], bh, a1, 0, 0, 0);
        a0 = __builtin_amdgcn_mfma_f32_16x16x32_bf16(ah[0][kk], bl, a0, 0, 0, 0);
        a1 = __builtin_amdgcn_mfma_f32_16x16x32_bf16(ah[1][kk], bl, a1, 0, 0, 0);
      }
      // fold: half-score v = esq/2 - dot; strict < keeps lowest idx
      const int code = s * 32 + lc;
      const float eh = 0.5f * esqs[code];
#pragma unroll
      for (int rr = 0; rr < 4; ++rr) {
        {
          float v = eh - a0[rr];
          bool  tk = v < t1[0][rr];
          float m2 = fminf(t2[0][rr], v);
          t2[0][rr] = tk ? t1[0][rr] : m2;
          ti[0][rr] = tk ? code : ti[0][rr];
          t1[0][rr] = tk ? v : t1[0][rr];
        }
        {
          float v = eh - a1[rr];
          bool  tk = v < t1[1][rr];
          float m2 = fminf(t2[1][rr], v);
          t2[1][rr] = tk ? t1[1][rr] : m2;
          ti[1][rr] = tk ? code : ti[1][rr];
          t1[1][rr] = tk ? v : t1[1][rr];
        }
      }
    }
    SBAR;            // all waves done reading this buffer -> safe to refill
  }

  // ---- reduce across the 16 lanes (l15) sharing the same rows; store ------
#pragma unroll
  for (int i = 0; i < 2; ++i)
#pragma unroll
    for (int rr = 0; rr < 4; ++rr) {
      float a1 = t1[i][rr], a2 = t2[i][rr];
      int   ai = ti[i][rr];
#pragma unroll
      for (int m = 1; m < 16; m <<= 1) {
        float o1 = __shfl_xor(a1, m, 64);
        float o2 = __shfl_xor(a2, m, 64);
        int   oi = __shfl_xor(ai, m, 64);
        bool  tk = (o1 < a1) || (o1 == a1 && oi < ai);
        float losr = tk ? a1 : o1;
        a2 = fminf(fminf(a2, o2), losr);
        a1 = tk ? o1 : a1;
        ai = tk ? oi : ai;
      }
      if (l15 == 0) {
        int row = rbase + i * 16 + q * 4 + rr;   // unique owner per row
        v1s[row] = a1; v2s[row] = a2; i1s[row] = ai;
      }
    }
  __syncthreads();

  // ---- per-row finalize (no cross-wave merge needed: rows disjoint) -------
  if (tid < MT) {
    float bv1 = v1s[tid], bv2 = v2s[tid];
    int   bi = i1s[tid];
    fidxs[tid] = bi;
    carr[tid]  = zsqs[tid] + 2.f * bv1;   // min ||z-e||^2
    if (2.f * (bv2 - bv1) < 0.02f) {      // near-tie -> exact fp64 rescan
      int pos = atomicAdd(&flagcnt, 1);
      flaglist[pos] = tid;
    }
    int mk;
    if (!(mmode & 1))      mk = maskg[m0 + tid] ? 1 : 0;                          // int32
    else if (!(mmode & 2)) mk = ((const float*)maskg)[m0 + tid] != 0.f ? 1 : 0;   // fp32
    else if (!(mmode & 4)) mk = ((const unsigned short*)maskg)[m0 + tid] ? 1 : 0; // bf16
    else                   mk = ((const unsigned char*)maskg)[m0 + tid] ? 1 : 0;  // bool
    maskb[tid] = mk;
  }
  __syncthreads();

  // ---- exact fp64 rescan of near-tie rows (rare; 1 code per thread) -------
  int nflag = flagcnt;
  for (int f = 0; f < nflag; ++f) {
    int row = flaglist[f];
    int k   = tid;                         // 512 threads, 512 codes
    double d2 = 0.0;
    for (int d = 0; d < DD; ++d) {
      double df = (double)zg[(size_t)(m0 + row) * DD + d] - (double)cbg[(size_t)k * DD + d];
      d2 = fma(df, df, d2);
    }
    double bd = d2;
    int    bk = k;
    for (int m = 1; m < 64; m <<= 1) {
      double od = __shfl_xor(bd, m, 64);
      int    ok = __shfl_xor(bk, m, 64);
      if (od < bd || (od == bd && ok < bk)) { bd = od; bk = ok; }
    }
    if (lane == 0) { rbd[wave] = bd; rbi[wave] = bk; }
    __syncthreads();
    if (tid == 0) {
      double xd = rbd[0]; int xk = rbi[0];
      for (int w = 1; w < 8; ++w)
        if (rbd[w] < xd || (rbd[w] == xd && rbi[w] < xk)) { xd = rbd[w]; xk = rbi[w]; }
      fidxs[row] = xk;
      carr[row]  = (float)xd;
    }
    __syncthreads();
  }
  __syncthreads();

  // ---- index output: float32 values, -1.0 pad ----
  if (tid < MT)
    outidx[m0 + tid] = maskb[tid] ? (float)(fidxs[tid] & (KCB - 1)) : -1.0f;

  // ---- commit partial -> device atomicAdd (waves 0-3, 64 rows each) -------
  if (tid < MT) {
    float c = carr[tid];
    for (int m = 1; m < 64; m <<= 1) c += __shfl_xor(c, m, 64);
    if (lane == 0) atomicAdd(wsum, c);
  }

  // ---- quantized output: float32 codebook gather, masked ----
#pragma unroll
  for (int it = 0; it < 32; ++it) {
    int idx = it * 512 + tid;             // float4 index: 256 rows x 64
    int row = idx >> 6;
    int f4  = idx & 63;
    int k   = fidxs[row] & (KCB - 1);
    float4 val = {0.f, 0.f, 0.f, 0.f};
    if (maskb[row]) val = ((const float4*)cbg)[(size_t)k * 64 + f4];
    ((float4*)outq)[(size_t)(m0 + row) * 64 + f4] = val;
  }
}

// ================= fallback (no workspace): in-register B conversion =======
__global__ __launch_bounds__(256, 3) void vq_main_fb(
    const float* __restrict__ zg, const int* __restrict__ maskg,
    const float* __restrict__ cbg, float* __restrict__ outq,
    float* __restrict__ outidx, float* __restrict__ wsum)
{
  __shared__ unsigned short zs_hi[8 * 32 * 32];
  __shared__ unsigned short zs_lo[8 * 32 * 32];
  __shared__ float esqs[KCB];
  __shared__ float zsq[32];
  __shared__ float wv1[4][32], wv2[4][32];
  __shared__ int   wi1[4][32];
  __shared__ float carr[32];
  __shared__ int   fidxs[32], maskb[32], flaglist[32];
  __shared__ int   flagcnt, mflags;
  __shared__ double rbd[4];
  __shared__ int    rbi[4];

  const int tid  = threadIdx.x;
  const int lane = tid & 63;
  const int wave = tid >> 6;
  const int q    = lane >> 4;
  const int l15  = lane & 15;
  const int m0   = blockIdx.x * 32;

  if (tid == 0) { flagcnt = 0; mflags = 0; }
  int wm = 0;
  if (tid < 128) {
    unsigned int W = ((const unsigned int*)maskg)[tid];
    if (W > 1u) wm |= 1;
    if (W != 0u && W != 0x3f800000u) wm |= 2;
    unsigned int lo = W & 0xffffu, hi = W >> 16;
    if ((lo != 0u && lo != 0x3f80u) || (hi != 0u && hi != 0x3f80u)) wm |= 4;
  }
  if (wm) atomicOr(&mflags, wm);

#pragma unroll
  for (int i = 0; i < 8; ++i) {
    int idx = i * 256 + tid;
    int row = idx >> 6;
    int f4  = idx & 63;
    float4 v = ((const float4*)zg)[(size_t)(m0 + row) * 64 + f4];
    int ch  = f4 >> 3;
    int col = (f4 & 7) * 4;
    int base = (ch * 32 + row) * 32 + col;
    ushort4 h, l;
    h.x = f2bf(v.x); l.x = f2bf(v.x - bf2f(h.x));
    h.y = f2bf(v.y); l.y = f2bf(v.y - bf2f(h.y));
    h.z = f2bf(v.z); l.z = f2bf(v.z - bf2f(h.z));
    h.w = f2bf(v.w); l.w = f2bf(v.w - bf2f(h.w));
    *(ushort4*)&zs_hi[base] = h;
    *(ushort4*)&zs_lo[base] = l;
    float s = v.x * v.x + v.y * v.y + v.z * v.z + v.w * v.w;
#pragma unroll
    for (int m = 1; m < 64; m <<= 1) s += __shfl_xor(s, m, 64);
    if (lane == 0) zsq[row] = s;
  }
  for (int c = tid; c < KCB; c += 256) {
    float s = 0.f;
    for (int f4i = 0; f4i < 64; ++f4i) {
      float4 v = ((const float4*)cbg)[(size_t)c * 64 + f4i];
      s = fmaf(v.x, v.x, s); s = fmaf(v.y, v.y, s);
      s = fmaf(v.z, v.z, s); s = fmaf(v.w, v.w, s);
    }
    esqs[c] = s;
  }
  __syncthreads();
  const int mmode = mflags;

  f32x4 acc[8][2];
#pragma unroll
  for (int t = 0; t < 8; ++t) {
    acc[t][0] = (f32x4){0.f, 0.f, 0.f, 0.f};
    acc[t][1] = (f32x4){0.f, 0.f, 0.f, 0.f};
  }
  const unsigned short* Abh = &zs_hi[l15 * 32 + q * 8];
  const unsigned short* Abl = &zs_lo[l15 * 32 + q * 8];

  for (int kk = 0; kk < 8; ++kk) {
    bf16x8 ah0 = *(const bf16x8*)(Abh + kk * 1024);
    bf16x8 ah1 = *(const bf16x8*)(Abh + kk * 1024 + 512);
    bf16x8 al0 = *(const bf16x8*)(Abl + kk * 1024);
    bf16x8 al1 = *(const bf16x8*)(Abl + kk * 1024 + 512);
#pragma unroll
    for (int t = 0; t < 8; ++t) {
      const int code_row = (wave * 8 + t) * 16 + l15;
      const float* src = &cbg[(size_t)code_row * 256 + kk * 32 + q * 8];
      float4 v0 = *(const float4*)src;
      float4 v1 = *(const float4*)(src + 4);
      float f[8] = {v0.x, v0.y, v0.z, v0.w, v1.x, v1.y, v1.z, v1.w};
      union { ushort us[8]; bf16x8 v; } H, L;
#pragma unroll
      for (int e = 0; e < 8; ++e) {
        unsigned short hh = f2bf(f[e]);
        H.us[e] = hh;
        L.us[e] = f2bf(f[e] - bf2f(hh));
      }
      bf16x8 bh = H.v, bl = L.v;
      acc[t][0] = __builtin_amdgcn_mfma_f32_16x16x32_bf16(ah0, bh, acc[t][0], 0, 0, 0);
      acc[t][1] = __builtin_amdgcn_mfma_f32_16x16x32_bf16(ah1, bh, acc[t][1], 0, 0, 0);
      acc[t][0] = __builtin_amdgcn_mfma_f32_16x16x32_bf16(al0, bh, acc[t][0], 0, 0, 0);
      acc[t][1] = __builtin_amdgcn_mfma_f32_16x16x32_bf16(al1, bh, acc[t][1], 0, 0, 0);
      acc[t][0] = __builtin_amdgcn_mfma_f32_16x16x32_bf16(ah0, bl, acc[t][0], 0, 0, 0);
      acc[t][1] = __builtin_amdgcn_mfma_f32_16x16x32_bf16(ah1, bl, acc[t][1], 0, 0, 0);
    }
  }

  float t1[2][4], t2[2][4];
  int   ti[2][4];
#pragma unroll
  for (int i = 0; i < 2; ++i)
#pragma unroll
    for (int rr = 0; rr < 4; ++rr) { t1[i][rr] = 3.0e38f; t2[i][rr] = 3.0e38f; ti[i][rr] = 0; }
#pragma unroll
  for (int t = 0; t < 8; ++t) {
    const int code = (wave * 8 + t) * 16 + l15;
    const float eh = 0.5f * esqs[code];
#pragma unroll
    for (int i = 0; i < 2; ++i)
#pragma unroll
      for (int rr = 0; rr < 4; ++rr) {
        float v = eh - acc[t][i][rr];
        bool  tk = v < t1[i][rr];
        float m2 = fminf(t2[i][rr], v);
        t2[i][rr] = tk ? t1[i][rr] : m2;
        ti[i][rr] = tk ? code : ti[i][rr];
        t1[i][rr] = tk ? v : t1[i][rr];
      }
  }
#pragma unroll
  for (int i = 0; i < 2; ++i)
#pragma unroll
    for (int rr = 0; rr < 4; ++rr) {
      float a1 = t1[i][rr], a2 = t2[i][rr];
      int   ai = ti[i][rr];
#pragma unroll
      for (int m = 1; m < 16; m <<= 1) {
        float o1 = __shfl_xor(a1, m, 64);
        float o2 = __shfl_xor(a2, m, 64);
        int   oi = __shfl_xor(ai, m, 64);
        bool  tk = (o1 < a1) || (o1 == a1 && oi < ai);
        float losr = tk ? a1 : o1;
        a2 = fminf(fminf(a2, o2), losr);
        a1 = tk ? o1 : a1;
        ai = tk ? oi : ai;
      }
      if (l15 == 0) {
        int row = i * 16 + q * 4 + rr;
        wv1[wave][row] = a1; wv2[wave][row] = a2; wi1[wave][row] = ai;
      }
    }
  __syncthreads();

  if (tid < 32) {
    float bv1 = 3.0e38f, bv2 = 3.0e38f;
    int   bi = 0x7fffffff;
#pragma unroll
    for (int w = 0; w < 4; ++w) {
      float a1 = wv1[w][tid], a2 = wv2[w][tid];
      int   ai = wi1[w][tid];
      bool  tk = (a1 < bv1) || (a1 == bv1 && ai < bi);
      if (tk) { bv2 = fminf(bv1, a2); bv1 = a1; bi = ai; }
      else    { bv2 = fminf(bv2, a1); }
    }
    fidxs[tid] = bi;
    carr[tid]  = zsq[tid] + 2.f * bv1;
    if (2.f * (bv2 - bv1) < 0.02f) {
      int pos = atomicAdd(&flagcnt, 1);
      flaglist[pos] = tid;
    }
    int mk;
    if (!(mmode & 1))      mk = maskg[m0 + tid] ? 1 : 0;
    else if (!(mmode & 2)) mk = ((const float*)maskg)[m0 + tid] != 0.f ? 1 : 0;
    else if (!(mmode & 4)) mk = ((const unsigned short*)maskg)[m0 + tid] ? 1 : 0;
    else                   mk = ((const unsigned char*)maskg)[m0 + tid] ? 1 : 0;
    maskb[tid] = mk;
  }
  __syncthreads();

  int nflag = flagcnt;
  for (int f = 0; f < nflag; ++f) {
    int row = flaglist[f];
    double bd = 1e300;
    int    bk = 0;
    for (int k = tid; k < KCB; k += 256) {
      double d2 = 0.0;
      for (int d = 0; d < DD; ++d) {
        double df = (double)zg[(size_t)(m0 + row) * DD + d] - (double)cbg[(size_t)k * DD + d];
        d2 = fma(df, df, d2);
      }
      if (d2 < bd) { bd = d2; bk = k; }
    }
    for (int m = 1; m < 64; m <<= 1) {
      double od = __shfl_xor(bd, m, 64);
      int    ok = __shfl_xor(bk, m, 64);
      if (od < bd || (od == bd && ok < bk)) { bd = od; bk = ok; }
    }
    if (lane == 0) { rbd[wave] = bd; rbi[wave] = bk; }
    __syncthreads();
    if (tid == 0) {
      double xd = rbd[0]; int xk = rbi[0];
      for (int w = 1; w < 4; ++w)
        if (rbd[w] < xd || (rbd[w] == xd && rbi[w] < xk)) { xd = rbd[w]; xk = rbi[w]; }
      fidxs[row] = xk;
      carr[row]  = (float)xd;
    }
    __syncthreads();
  }
  __syncthreads();

  if (tid < 32)
    outidx[m0 + tid] = maskb[tid] ? (float)(fidxs[tid] & (KCB - 1)) : -1.0f;

  if (wave == 0) {
    float c = (lane < 32) ? carr[lane] : 0.f;
    for (int m = 1; m < 64; m <<= 1) c += __shfl_xor(c, m, 64);
    if (lane == 0) atomicAdd(wsum, c);
  }

#pragma unroll
  for (int i = 0; i < 8; ++i) {
    int idx = i * 256 + tid;
    int row = idx >> 6;
    int f4  = idx & 63;
    int k   = fidxs[row] & (KCB - 1);
    float4 val = {0.f, 0.f, 0.f, 0.f};
    if (maskb[row]) val = ((const float4*)cbg)[(size_t)k * 64 + f4];
    ((float4*)outq)[(size_t)(m0 + row) * 64 + f4] = val;
  }
}

__global__ void vq_final(const float* __restrict__ wsum,
                         float* __restrict__ outloss) {
  if (threadIdx.x == 0)
    outloss[0] = 0.25f * (wsum[0] / 16777216.0f);   // mean over B*N*D
}

extern "C" void kernel_launch(void* const* d_in, const int* in_sizes, int n_in,
                              void* d_out, int out_size, void* d_ws, size_t ws_size,
                              hipStream_t stream) {
  // Inputs identified by element count. z/codebook FLOAT32, mask probed.
  const void* pz = d_in[0];
  const void* pm = (n_in > 1) ? d_in[1] : d_in[0];
  const void* pc = (n_in > 2) ? d_in[2] : d_in[0];
  for (int i = 0; i < n_in; ++i) {
    if      (in_sizes[i] == BN * DD)  pz = d_in[i];
    else if (in_sizes[i] == BN)       pm = d_in[i];
    else if (in_sizes[i] == KCB * DD) pc = d_in[i];
  }
  const float* zg  = (const float*)pz;
  const int*   mk  = (const int*)pm;
  const float* cbg = (const float*)pc;

  float* outq   = (float*)d_out;
  float* outidx = outq + (size_t)BN * DD;
  float* outls  = outidx + BN;
  float* wsum   = (float*)d_ws;

  // ws layout: [0] wsum | +1024 esq (2KB) | +4096 cbt (512KB stage-major)
  const size_t ESQ_OFF = 1024;
  const size_t CBT_OFF = 4096;
  const size_t WS_NEED = CBT_OFF + (size_t)KCB * DD * 2 * 2;   // 528 KB

  vq_zero_ws<<<1, 1, 0, stream>>>(wsum);
  if (ws_size >= WS_NEED) {
    char*  cbt = (char*)d_ws + CBT_OFF;
    float* esw = (float*)((char*)d_ws + ESQ_OFF);
    vq_prep<<<128, 256, 0, stream>>>(cbg, cbt, esw);
    vq_main<<<NBLK, 512, 0, stream>>>(zg, mk, cbg, cbt, esw,
                                      outq, outidx, wsum);
  } else {
    vq_main_fb<<<2048, 256, 0, stream>>>(zg, mk, cbg, outq, outidx, wsum);
  }
  vq_final<<<1, 64, 0, stream>>>(wsum, outls);
}

// Round 13
// 205.863 us; speedup vs baseline: 3.4617x; 1.0092x over previous
//
#include <hip/hip_runtime.h>

// Problem constants
#define BN    65536    // B*N rows
#define DD    256      // D
#define KCB   512      // codebook entries
#define MT    256      // rows per block (main kernel)
#define NBLK  256      // BN/MT  -> exactly 1 block per CU
#define NST   16       // codebook stages of 32 codes

typedef __attribute__((ext_vector_type(8))) short bf16x8;
typedef __attribute__((ext_vector_type(4))) float f32x4;

static __device__ __forceinline__ float bf2f(unsigned short u) {
  return __uint_as_float(((unsigned int)u) << 16);
}
static __device__ __forceinline__ unsigned short f2bf(float f) {
  unsigned int u = __float_as_uint(f);
  return (unsigned short)((u + 0x7fffu + ((u >> 16) & 1u)) >> 16);  // RNE
}
static __device__ __forceinline__ void gll16(const void* g, void* l) {
  __builtin_amdgcn_global_load_lds(
      (const __attribute__((address_space(1))) unsigned int*)g,
      (__attribute__((address_space(3))) unsigned int*)l, 16, 0, 0);
}

__global__ void vq_zero_ws(float* ws) { ws[0] = 0.f; }   // fallback path only

// ---- one-shot prep: codebook fp32 -> bf16 hi/lo, stage-major layout with
// XOR bank-swizzle pre-applied in GLOBAL memory so the linear
// global_load_lds staging lands a swizzled LDS image (linear dest +
// inverse-swz source + swz read). Stage s (32 codes) = 32 KB at s*32768:
// [16 KB hi][16 KB lo]; within half, code lc byte b at
// (lc*512 + b) ^ ((lc&7)<<4). Also fp64-exact e_sq, and wsum zeroing
// (fused here to save one dispatch; cross-dispatch stream order makes the
// zero visible to vq_main's atomics).
// NOTE (rounds 8-10 post-mortem): 64-code stages, 3-buffer rings (2-deep or
// single-barrier), and in-main fused loss finalize all measured worse than
// this structure. This exact schedule is the verified optimum.
__global__ void vq_prep(const float* __restrict__ cbg,
                        char* __restrict__ cbt,
                        float* __restrict__ esq,
                        float* __restrict__ wsum) {
  if (blockIdx.x == 0 && threadIdx.x == 0) wsum[0] = 0.f;
  const int tid = threadIdx.x, lane = tid & 63, wave = tid >> 6;
  const int code = blockIdx.x * 4 + wave;
  float4 v = ((const float4*)cbg)[(size_t)code * 64 + lane];
  ushort4 h, l;
  h.x = f2bf(v.x); l.x = f2bf(v.x - bf2f(h.x));
  h.y = f2bf(v.y); l.y = f2bf(v.y - bf2f(h.y));
  h.z = f2bf(v.z); l.z = f2bf(v.z - bf2f(h.z));
  h.w = f2bf(v.w); l.w = f2bf(v.w - bf2f(h.w));
  const int s  = code >> 5;
  const int lc = code & 31;
  unsigned raw = (unsigned)(lc * 512 + lane * 8);     // 8 bytes per lane
  unsigned off = (unsigned)(s * 32768) + (raw ^ ((unsigned)(lc & 7) << 4));
  *(ushort4*)(cbt + off)         = h;
  *(ushort4*)(cbt + off + 16384) = l;
  double sq = (double)v.x * v.x + (double)v.y * v.y +
              (double)v.z * v.z + (double)v.w * v.w;
#pragma unroll
  for (int m = 1; m < 64; m <<= 1) sq += __shfl_xor(sq, m, 64);
  if (lane == 0) esq[code] = (float)sq;
}

// issue stage S (32 KB) into LDS buffer BSEL: 4 x global_load_lds(16B) per
// thread; dest = wave-uniform base + lane*16 (required by HW).
#define ISSUE(S, BSEL)                                                       \
  do {                                                                       \
    const char* _src = cbt + (size_t)(S) * 32768 + (size_t)tid * 16;         \
    char* _dst = &bufB[BSEL][tid * 16];                                      \
    _Pragma("unroll")                                                        \
    for (int _r = 0; _r < 4; ++_r)                                           \
      gll16(_src + _r * 8192, _dst + _r * 8192);                             \
  } while (0)

#define VMCNT4 asm volatile("s_waitcnt vmcnt(4)" ::: "memory")
#define VMCNT0 asm volatile("s_waitcnt vmcnt(0)" ::: "memory")
#define SBAR   asm volatile("s_barrier" ::: "memory")

__global__ __launch_bounds__(512, 2) void vq_main(
    const float* __restrict__ zg,    // (BN, D) float32
    const int* __restrict__ maskg,   // (BN) mask, dtype probed
    const float* __restrict__ cbg,   // (K, D) float32 (rescan + gather)
    const char* __restrict__ cbt,    // stage-major swizzled bf16 hi/lo
    const float* __restrict__ esqg,  // (K) fp64-acc esq
    float* __restrict__ outq,        // (BN, D) float32
    float* __restrict__ outidx,      // (BN) float32 (-1 pad)
    float* __restrict__ wsum)        // d_ws fp32 accumulator
{
  // ~76 KB LDS; 8 waves (2/SIMD). A (z) lives in registers, not LDS.
  __shared__ __align__(16) char bufB[2][32768];   // B dbuf: 16K hi | 16K lo
  __shared__ float esqs[KCB];
  __shared__ float zsqs[MT];
  __shared__ float v1s[MT], v2s[MT];
  __shared__ int   i1s[MT];
  __shared__ float carr[MT];
  __shared__ int   fidxs[MT], maskb[MT], flaglist[MT];
  __shared__ int   flagcnt, mflags;
  __shared__ double rbd[8];
  __shared__ int    rbi[8];

  const int tid   = threadIdx.x;
  const int lane  = tid & 63;
  const int wave  = tid >> 6;
  const int q     = lane >> 4;
  const int l15   = lane & 15;
  const int m0    = blockIdx.x * MT;
  const int rbase = wave * 32;           // wave's 32 local rows

  if (tid == 0) { flagcnt = 0; mflags = 0; }

  // ---- mask dtype probe on first 512 bytes (in-bounds under every layout) --
  int wm = 0;
  if (tid < 128) {
    unsigned int W = ((const unsigned int*)maskg)[tid];
    if (W > 1u) wm |= 1;
    if (W != 0u && W != 0x3f800000u) wm |= 2;
    unsigned int lo = W & 0xffffu, hi = W >> 16;
    if ((lo != 0u && lo != 0x3f80u) || (hi != 0u && hi != 0x3f80u)) wm |= 4;
  }
  if (wm) atomicOr(&mflags, wm);

  // ---- esq into LDS (512 threads, 512 entries) ----
  esqs[tid] = esqg[tid];

  // ---- prefetch stage 0 before the z prologue (overlaps with z loads) ----
  ISSUE(0, 0);

  // ---- z -> A registers: 32 rows/wave, bf16 hi/lo; fused exact-fp32 z_sq --
  bf16x8 ah[2][8], al[2][8];
  float zacc0 = 0.f, zacc1 = 0.f;
#pragma unroll
  for (int i = 0; i < 2; ++i) {
    const int grow = m0 + rbase + i * 16 + l15;
#pragma unroll
    for (int kk = 0; kk < 8; ++kk) {
      const float* src = &zg[(size_t)grow * DD + kk * 32 + q * 8];
      float4 v0 = *(const float4*)src;
      float4 v1 = *(const float4*)(src + 4);
      float f[8] = {v0.x, v0.y, v0.z, v0.w, v1.x, v1.y, v1.z, v1.w};
      union { ushort us[8]; bf16x8 v; } H, L;
#pragma unroll
      for (int e = 0; e < 8; ++e) {
        unsigned short hh = f2bf(f[e]);
        H.us[e] = hh;
        L.us[e] = f2bf(f[e] - bf2f(hh));
      }
      ah[i][kk] = H.v;
      al[i][kk] = L.v;
      float s = 0.f;
#pragma unroll
      for (int e = 0; e < 8; ++e) s = fmaf(f[e], f[e], s);
      if (i == 0) zacc0 += s; else zacc1 += s;
    }
  }
  // reduce z_sq across the 4 q-lanes holding the same row
  {
    float s0 = zacc0, s1 = zacc1;
    s0 += __shfl_xor(s0, 16, 64); s0 += __shfl_xor(s0, 32, 64);
    s1 += __shfl_xor(s1, 16, 64); s1 += __shfl_xor(s1, 32, 64);
    if (q == 0) {
      zsqs[rbase + l15]      = s0;
      zsqs[rbase + 16 + l15] = s1;
    }
  }
  __syncthreads();   // drains z loads + stage 0; esqs/zsqs/mflags visible
  const int mmode = mflags;

  // ---- per-thread running top-2 over all 512 codes ----
  float t1[2][4], t2[2][4];
  int   ti[2][4];
#pragma unroll
  for (int i = 0; i < 2; ++i)
#pragma unroll
    for (int rr = 0; rr < 4; ++rr) { t1[i][rr] = 3.0e38f; t2[i][rr] = 3.0e38f; ti[i][rr] = 0; }

  // ---- 16-stage pipeline over codes; all waves consume the same B tile ----
#pragma unroll 1
  for (int s = 0; s < NST; ++s) {
    if (s < NST - 1) { ISSUE(s + 1, (s + 1) & 1); VMCNT4; }
    else             { VMCNT0; }
    SBAR;
    const char* bb = &bufB[s & 1][0];
#pragma unroll
    for (int tt = 0; tt < 2; ++tt) {
      const int lc = tt * 16 + l15;
      const unsigned sw = ((unsigned)(lc & 7)) << 4;
      f32x4 a0 = (f32x4){0.f, 0.f, 0.f, 0.f};
      f32x4 a1 = (f32x4){0.f, 0.f, 0.f, 0.f};
#pragma unroll
      for (int kk = 0; kk < 8; ++kk) {
        const unsigned off = ((unsigned)(lc * 512 + kk * 64 + q * 16)) ^ sw;
        bf16x8 bh = *(const bf16x8*)(bb + off);
        bf16x8 bl = *(const bf16x8*)(bb + 16384 + off);
        a0 = __builtin_amdgcn_mfma_f32_16x16x32_bf16(ah[0][kk], bh, a0, 0, 0, 0);
        a1 = __builtin_amdgcn_mfma_f32_16x16x32_bf16(ah[1][kk], bh, a1, 0, 0, 0);
        a0 = __builtin_amdgcn_mfma_f32_16x16x32_bf16(al[0][kk], bh, a0, 0, 0, 0);
        a1 = __builtin_amdgcn_mfma_f32_16x16x32_bf16(al[1][kk], bh, a1, 0, 0, 0);
        a0 = __builtin_amdgcn_mfma_f32_16x16x32_bf16(ah[0][kk], bl, a0, 0, 0, 0);
        a1 = __builtin_amdgcn_mfma_f32_16x16x32_bf16(ah[1][kk], bl, a1, 0, 0, 0);
      }
      // fold: half-score v = esq/2 - dot; strict < keeps lowest idx
      const int code = s * 32 + lc;
      const float eh = 0.5f * esqs[code];
#pragma unroll
      for (int rr = 0; rr < 4; ++rr) {
        {
          float v = eh - a0[rr];
          bool  tk = v < t1[0][rr];
          float m2 = fminf(t2[0][rr], v);
          t2[0][rr] = tk ? t1[0][rr] : m2;
          ti[0][rr] = tk ? code : ti[0][rr];
          t1[0][rr] = tk ? v : t1[0][rr];
        }
        {
          float v = eh - a1[rr];
          bool  tk = v < t1[1][rr];
          float m2 = fminf(t2[1][rr], v);
          t2[1][rr] = tk ? t1[1][rr] : m2;
          ti[1][rr] = tk ? code : ti[1][rr];
          t1[1][rr] = tk ? v : t1[1][rr];
        }
      }
    }
    SBAR;            // all waves done reading this buffer -> safe to refill
  }

  // ---- reduce across the 16 lanes (l15) sharing the same rows; store ------
#pragma unroll
  for (int i = 0; i < 2; ++i)
#pragma unroll
    for (int rr = 0; rr < 4; ++rr) {
      float a1 = t1[i][rr], a2 = t2[i][rr];
      int   ai = ti[i][rr];
#pragma unroll
      for (int m = 1; m < 16; m <<= 1) {
        float o1 = __shfl_xor(a1, m, 64);
        float o2 = __shfl_xor(a2, m, 64);
        int   oi = __shfl_xor(ai, m, 64);
        bool  tk = (o1 < a1) || (o1 == a1 && oi < ai);
        float losr = tk ? a1 : o1;
        a2 = fminf(fminf(a2, o2), losr);
        a1 = tk ? o1 : a1;
        ai = tk ? oi : ai;
      }
      if (l15 == 0) {
        int row = rbase + i * 16 + q * 4 + rr;   // unique owner per row
        v1s[row] = a1; v2s[row] = a2; i1s[row] = ai;
      }
    }
  __syncthreads();

  // ---- per-row finalize (no cross-wave merge needed: rows disjoint) -------
  if (tid < MT) {
    float bv1 = v1s[tid], bv2 = v2s[tid];
    int   bi = i1s[tid];
    fidxs[tid] = bi;
    carr[tid]  = zsqs[tid] + 2.f * bv1;   // min ||z-e||^2
    if (2.f * (bv2 - bv1) < 0.02f) {      // near-tie -> exact fp64 rescan
      int pos = atomicAdd(&flagcnt, 1);
      flaglist[pos] = tid;
    }
    int mk;
    if (!(mmode & 1))      mk = maskg[m0 + tid] ? 1 : 0;                          // int32
    else if (!(mmode & 2)) mk = ((const float*)maskg)[m0 + tid] != 0.f ? 1 : 0;   // fp32
    else if (!(mmode & 4)) mk = ((const unsigned short*)maskg)[m0 + tid] ? 1 : 0; // bf16
    else                   mk = ((const unsigned char*)maskg)[m0 + tid] ? 1 : 0;  // bool
    maskb[tid] = mk;
  }
  __syncthreads();

  // ---- exact fp64 rescan of near-tie rows (rare; 1 code per thread) -------
  int nflag = flagcnt;
  for (int f = 0; f < nflag; ++f) {
    int row = flaglist[f];
    int k   = tid;                         // 512 threads, 512 codes
    double d2 = 0.0;
    for (int d = 0; d < DD; ++d) {
      double df = (double)zg[(size_t)(m0 + row) * DD + d] - (double)cbg[(size_t)k * DD + d];
      d2 = fma(df, df, d2);
    }
    double bd = d2;
    int    bk = k;
    for (int m = 1; m < 64; m <<= 1) {
      double od = __shfl_xor(bd, m, 64);
      int    ok = __shfl_xor(bk, m, 64);
      if (od < bd || (od == bd && ok < bk)) { bd = od; bk = ok; }
    }
    if (lane == 0) { rbd[wave] = bd; rbi[wave] = bk; }
    __syncthreads();
    if (tid == 0) {
      double xd = rbd[0]; int xk = rbi[0];
      for (int w = 1; w < 8; ++w)
        if (rbd[w] < xd || (rbd[w] == xd && rbi[w] < xk)) { xd = rbd[w]; xk = rbi[w]; }
      fidxs[row] = xk;
      carr[row]  = (float)xd;
    }
    __syncthreads();
  }
  __syncthreads();

  // ---- index output: float32 values, -1.0 pad ----
  if (tid < MT)
    outidx[m0 + tid] = maskb[tid] ? (float)(fidxs[tid] & (KCB - 1)) : -1.0f;

  // ---- commit partial -> device atomicAdd (waves 0-3, 64 rows each) -------
  if (tid < MT) {
    float c = carr[tid];
    for (int m = 1; m < 64; m <<= 1) c += __shfl_xor(c, m, 64);
    if (lane == 0) atomicAdd(wsum, c);
  }

  // ---- quantized output: float32 codebook gather, masked ----
#pragma unroll
  for (int it = 0; it < 32; ++it) {
    int idx = it * 512 + tid;             // float4 index: 256 rows x 64
    int row = idx >> 6;
    int f4  = idx & 63;
    int k   = fidxs[row] & (KCB - 1);
    float4 val = {0.f, 0.f, 0.f, 0.f};
    if (maskb[row]) val = ((const float4*)cbg)[(size_t)k * 64 + f4];
    ((float4*)outq)[(size_t)(m0 + row) * 64 + f4] = val;
  }
}

// ================= fallback (no workspace): in-register B conversion =======
__global__ __launch_bounds__(256, 3) void vq_main_fb(
    const float* __restrict__ zg, const int* __restrict__ maskg,
    const float* __restrict__ cbg, float* __restrict__ outq,
    float* __restrict__ outidx, float* __restrict__ wsum)
{
  __shared__ unsigned short zs_hi[8 * 32 * 32];
  __shared__ unsigned short zs_lo[8 * 32 * 32];
  __shared__ float esqs[KCB];
  __shared__ float zsq[32];
  __shared__ float wv1[4][32], wv2[4][32];
  __shared__ int   wi1[4][32];
  __shared__ float carr[32];
  __shared__ int   fidxs[32], maskb[32], flaglist[32];
  __shared__ int   flagcnt, mflags;
  __shared__ double rbd[4];
  __shared__ int    rbi[4];

  const int tid  = threadIdx.x;
  const int lane = tid & 63;
  const int wave = tid >> 6;
  const int q    = lane >> 4;
  const int l15  = lane & 15;
  const int m0   = blockIdx.x * 32;

  if (tid == 0) { flagcnt = 0; mflags = 0; }
  int wm = 0;
  if (tid < 128) {
    unsigned int W = ((const unsigned int*)maskg)[tid];
    if (W > 1u) wm |= 1;
    if (W != 0u && W != 0x3f800000u) wm |= 2;
    unsigned int lo = W & 0xffffu, hi = W >> 16;
    if ((lo != 0u && lo != 0x3f80u) || (hi != 0u && hi != 0x3f80u)) wm |= 4;
  }
  if (wm) atomicOr(&mflags, wm);

#pragma unroll
  for (int i = 0; i < 8; ++i) {
    int idx = i * 256 + tid;
    int row = idx >> 6;
    int f4  = idx & 63;
    float4 v = ((const float4*)zg)[(size_t)(m0 + row) * 64 + f4];
    int ch  = f4 >> 3;
    int col = (f4 & 7) * 4;
    int base = (ch * 32 + row) * 32 + col;
    ushort4 h, l;
    h.x = f2bf(v.x); l.x = f2bf(v.x - bf2f(h.x));
    h.y = f2bf(v.y); l.y = f2bf(v.y - bf2f(h.y));
    h.z = f2bf(v.z); l.z = f2bf(v.z - bf2f(h.z));
    h.w = f2bf(v.w); l.w = f2bf(v.w - bf2f(h.w));
    *(ushort4*)&zs_hi[base] = h;
    *(ushort4*)&zs_lo[base] = l;
    float s = v.x * v.x + v.y * v.y + v.z * v.z + v.w * v.w;
#pragma unroll
    for (int m = 1; m < 64; m <<= 1) s += __shfl_xor(s, m, 64);
    if (lane == 0) zsq[row] = s;
  }
  for (int c = tid; c < KCB; c += 256) {
    float s = 0.f;
    for (int f4i = 0; f4i < 64; ++f4i) {
      float4 v = ((const float4*)cbg)[(size_t)c * 64 + f4i];
      s = fmaf(v.x, v.x, s); s = fmaf(v.y, v.y, s);
      s = fmaf(v.z, v.z, s); s = fmaf(v.w, v.w, s);
    }
    esqs[c] = s;
  }
  __syncthreads();
  const int mmode = mflags;

  f32x4 acc[8][2];
#pragma unroll
  for (int t = 0; t < 8; ++t) {
    acc[t][0] = (f32x4){0.f, 0.f, 0.f, 0.f};
    acc[t][1] = (f32x4){0.f, 0.f, 0.f, 0.f};
  }
  const unsigned short* Abh = &zs_hi[l15 * 32 + q * 8];
  const unsigned short* Abl = &zs_lo[l15 * 32 + q * 8];

  for (int kk = 0; kk < 8; ++kk) {
    bf16x8 ah0 = *(const bf16x8*)(Abh + kk * 1024);
    bf16x8 ah1 = *(const bf16x8*)(Abh + kk * 1024 + 512);
    bf16x8 al0 = *(const bf16x8*)(Abl + kk * 1024);
    bf16x8 al1 = *(const bf16x8*)(Abl + kk * 1024 + 512);
#pragma unroll
    for (int t = 0; t < 8; ++t) {
      const int code_row = (wave * 8 + t) * 16 + l15;
      const float* src = &cbg[(size_t)code_row * 256 + kk * 32 + q * 8];
      float4 v0 = *(const float4*)src;
      float4 v1 = *(const float4*)(src + 4);
      float f[8] = {v0.x, v0.y, v0.z, v0.w, v1.x, v1.y, v1.z, v1.w};
      union { ushort us[8]; bf16x8 v; } H, L;
#pragma unroll
      for (int e = 0; e < 8; ++e) {
        unsigned short hh = f2bf(f[e]);
        H.us[e] = hh;
        L.us[e] = f2bf(f[e] - bf2f(hh));
      }
      bf16x8 bh = H.v, bl = L.v;
      acc[t][0] = __builtin_amdgcn_mfma_f32_16x16x32_bf16(ah0, bh, acc[t][0], 0, 0, 0);
      acc[t][1] = __builtin_amdgcn_mfma_f32_16x16x32_bf16(ah1, bh, acc[t][1], 0, 0, 0);
      acc[t][0] = __builtin_amdgcn_mfma_f32_16x16x32_bf16(al0, bh, acc[t][0], 0, 0, 0);
      acc[t][1] = __builtin_amdgcn_mfma_f32_16x16x32_bf16(al1, bh, acc[t][1], 0, 0, 0);
      acc[t][0] = __builtin_amdgcn_mfma_f32_16x16x32_bf16(ah0, bl, acc[t][0], 0, 0, 0);
      acc[t][1] = __builtin_amdgcn_mfma_f32_16x16x32_bf16(ah1, bl, acc[t][1], 0, 0, 0);
    }
  }

  float t1[2][4], t2[2][4];
  int   ti[2][4];
#pragma unroll
  for (int i = 0; i < 2; ++i)
#pragma unroll
    for (int rr = 0; rr < 4; ++rr) { t1[i][rr] = 3.0e38f; t2[i][rr] = 3.0e38f; ti[i][rr] = 0; }
#pragma unroll
  for (int t = 0; t < 8; ++t) {
    const int code = (wave * 8 + t) * 16 + l15;
    const float eh = 0.5f * esqs[code];
#pragma unroll
    for (int i = 0; i < 2; ++i)
#pragma unroll
      for (int rr = 0; rr < 4; ++rr) {
        float v = eh - acc[t][i][rr];
        bool  tk = v < t1[i][rr];
        float m2 = fminf(t2[i][rr], v);
        t2[i][rr] = tk ? t1[i][rr] : m2;
        ti[i][rr] = tk ? code : ti[i][rr];
        t1[i][rr] = tk ? v : t1[i][rr];
      }
  }
#pragma unroll
  for (int i = 0; i < 2; ++i)
#pragma unroll
    for (int rr = 0; rr < 4; ++rr) {
      float a1 = t1[i][rr], a2 = t2[i][rr];
      int   ai = ti[i][rr];
#pragma unroll
      for (int m = 1; m < 16; m <<= 1) {
        float o1 = __shfl_xor(a1, m, 64);
        float o2 = __shfl_xor(a2, m, 64);
        int   oi = __shfl_xor(ai, m, 64);
        bool  tk = (o1 < a1) || (o1 == a1 && oi < ai);
        float losr = tk ? a1 : o1;
        a2 = fminf(fminf(a2, o2), losr);
        a1 = tk ? o1 : a1;
        ai = tk ? oi : ai;
      }
      if (l15 == 0) {
        int row = i * 16 + q * 4 + rr;
        wv1[wave][row] = a1; wv2[wave][row] = a2; wi1[wave][row] = ai;
      }
    }
  __syncthreads();

  if (tid < 32) {
    float bv1 = 3.0e38f, bv2 = 3.0e38f;
    int   bi = 0x7fffffff;
#pragma unroll
    for (int w = 0; w < 4; ++w) {
      float a1 = wv1[w][tid], a2 = wv2[w][tid];
      int   ai = wi1[w][tid];
      bool  tk = (a1 < bv1) || (a1 == bv1 && ai < bi);
      if (tk) { bv2 = fminf(bv1, a2); bv1 = a1; bi = ai; }
      else    { bv2 = fminf(bv2, a1); }
    }
    fidxs[tid] = bi;
    carr[tid]  = zsq[tid] + 2.f * bv1;
    if (2.f * (bv2 - bv1) < 0.02f) {
      int pos = atomicAdd(&flagcnt, 1);
      flaglist[pos] = tid;
    }
    int mk;
    if (!(mmode & 1))      mk = maskg[m0 + tid] ? 1 : 0;
    else if (!(mmode & 2)) mk = ((const float*)maskg)[m0 + tid] != 0.f ? 1 : 0;
    else if (!(mmode & 4)) mk = ((const unsigned short*)maskg)[m0 + tid] ? 1 : 0;
    else                   mk = ((const unsigned char*)maskg)[m0 + tid] ? 1 : 0;
    maskb[tid] = mk;
  }
  __syncthreads();

  int nflag = flagcnt;
  for (int f = 0; f < nflag; ++f) {
    int row = flaglist[f];
    double bd = 1e300;
    int    bk = 0;
    for (int k = tid; k < KCB; k += 256) {
      double d2 = 0.0;
      for (int d = 0; d < DD; ++d) {
        double df = (double)zg[(size_t)(m0 + row) * DD + d] - (double)cbg[(size_t)k * DD + d];
        d2 = fma(df, df, d2);
      }
      if (d2 < bd) { bd = d2; bk = k; }
    }
    for (int m = 1; m < 64; m <<= 1) {
      double od = __shfl_xor(bd, m, 64);
      int    ok = __shfl_xor(bk, m, 64);
      if (od < bd || (od == bd && ok < bk)) { bd = od; bk = ok; }
    }
    if (lane == 0) { rbd[wave] = bd; rbi[wave] = bk; }
    __syncthreads();
    if (tid == 0) {
      double xd = rbd[0]; int xk = rbi[0];
      for (int w = 1; w < 4; ++w)
        if (rbd[w] < xd || (rbd[w] == xd && rbi[w] < xk)) { xd = rbd[w]; xk = rbi[w]; }
      fidxs[row] = xk;
      carr[row]  = (float)xd;
    }
    __syncthreads();
  }
  __syncthreads();

  if (tid < 32)
    outidx[m0 + tid] = maskb[tid] ? (float)(fidxs[tid] & (KCB - 1)) : -1.0f;

  if (wave == 0) {
    float c = (lane < 32) ? carr[lane] : 0.f;
    for (int m = 1; m < 64; m <<= 1) c += __shfl_xor(c, m, 64);
    if (lane == 0) atomicAdd(wsum, c);
  }

#pragma unroll
  for (int i = 0; i < 8; ++i) {
    int idx = i * 256 + tid;
    int row = idx >> 6;
    int f4  = idx & 63;
    int k   = fidxs[row] & (KCB - 1);
    float4 val = {0.f, 0.f, 0.f, 0.f};
    if (maskb[row]) val = ((const float4*)cbg)[(size_t)k * 64 + f4];
    ((float4*)outq)[(size_t)(m0 + row) * 64 + f4] = val;
  }
}

__global__ void vq_final(const float* __restrict__ wsum,
                         float* __restrict__ outloss) {
  if (threadIdx.x == 0)
    outloss[0] = 0.25f * (wsum[0] / 16777216.0f);   // mean over B*N*D
}

extern "C" void kernel_launch(void* const* d_in, const int* in_sizes, int n_in,
                              void* d_out, int out_size, void* d_ws, size_t ws_size,
                              hipStream_t stream) {
  // Inputs identified by element count. z/codebook FLOAT32, mask probed.
  const void* pz = d_in[0];
  const void* pm = (n_in > 1) ? d_in[1] : d_in[0];
  const void* pc = (n_in > 2) ? d_in[2] : d_in[0];
  for (int i = 0; i < n_in; ++i) {
    if      (in_sizes[i] == BN * DD)  pz = d_in[i];
    else if (in_sizes[i] == BN)       pm = d_in[i];
    else if (in_sizes[i] == KCB * DD) pc = d_in[i];
  }
  const float* zg  = (const float*)pz;
  const int*   mk  = (const int*)pm;
  const float* cbg = (const float*)pc;

  float* outq   = (float*)d_out;
  float* outidx = outq + (size_t)BN * DD;
  float* outls  = outidx + BN;
  float* wsum   = (float*)d_ws;

  // ws layout: [0] wsum | +1024 esq (2KB) | +4096 cbt (512KB stage-major)
  const size_t ESQ_OFF = 1024;
  const size_t CBT_OFF = 4096;
  const size_t WS_NEED = CBT_OFF + (size_t)KCB * DD * 2 * 2;   // 528 KB

  if (ws_size >= WS_NEED) {
    char*  cbt = (char*)d_ws + CBT_OFF;
    float* esw = (float*)((char*)d_ws + ESQ_OFF);
    vq_prep<<<128, 256, 0, stream>>>(cbg, cbt, esw, wsum);   // zeroes wsum too
    vq_main<<<NBLK, 512, 0, stream>>>(zg, mk, cbg, cbt, esw,
                                      outq, outidx, wsum);
  } else {
    vq_zero_ws<<<1, 1, 0, stream>>>(wsum);
    vq_main_fb<<<2048, 256, 0, stream>>>(zg, mk, cbg, outq, outidx, wsum);
  }
  vq_final<<<1, 64, 0, stream>>>(wsum, outls);
}